// Round 7
// baseline (659.545 us; speedup 1.0000x reference)
//
#include <hip/hip_runtime.h>
#include <hip/hip_fp8.h>
#include <stdint.h>

#define AS1 __attribute__((address_space(1)))
#define AS3 __attribute__((address_space(3)))

typedef __bf16 bf16;
typedef __bf16 bf16x2 __attribute__((ext_vector_type(2)));
typedef __bf16 bf16x4v __attribute__((ext_vector_type(4)));
typedef __bf16 bf16x8 __attribute__((ext_vector_type(8)));
typedef float f32x4 __attribute__((ext_vector_type(4)));
typedef float f32x2 __attribute__((ext_vector_type(2)));
typedef __hip_fp8_e4m3 fp8;

#define BN_EPS 1e-5f
#define BKT_SHIFT 8              // 256 nodes per bucket
#define BKT_NODES 256
#define TILE_E 2048              // edges per binning block
#define NCOPY 16                 // striped stats copies (atomic de-contention)

// ---- fused setup: weight cvt+transpose, x fp32 -> bf16 + fp8, bucket count ----
__global__ void k_setup(const float* __restrict__ x, bf16* __restrict__ x_bf,
                        unsigned char* __restrict__ x8, int n4,
                        const int* __restrict__ ei, int* __restrict__ btot, int E, int nbkt,
                        const float* __restrict__ Wl0, const float* __restrict__ Wr0,
                        const float* __restrict__ Wl1, const float* __restrict__ Wr1,
                        const float* __restrict__ Wl2, const float* __restrict__ Wr2,
                        bf16* __restrict__ Bt0, bf16* __restrict__ Bt1, bf16* __restrict__ Bt2) {
    __shared__ int hist[512];
    const int tid = threadIdx.x;
    int g = blockIdx.x * 256 + tid;
    if (g < n4) {
        float4 v = ((const float4*)x)[g];
        bf16x4v o; o[0] = (bf16)v.x; o[1] = (bf16)v.y; o[2] = (bf16)v.z; o[3] = (bf16)v.w;
        ((bf16x4v*)x_bf)[g] = o;
        uchar4 o8;
        o8.x = fp8(v.x).__x; o8.y = fp8(v.y).__x; o8.z = fp8(v.z).__x; o8.w = fp8(v.w).__x;
        ((uchar4*)x8)[g] = o8;
    }
    if (blockIdx.x < 128) {
        int idx = g;                 // 32768 threads: c in [0,128), k in [0,256)
        int c = idx >> 8, k = idx & 255;
        float v0 = (k < 128) ? Wl0[k * 128 + c] : Wr0[(k - 128) * 128 + c];
        Bt0[c * 256 + k] = (bf16)v0;
        float v1 = (k < 128) ? Wl1[k * 128 + c] : Wr1[(k - 128) * 128 + c];
        Bt1[c * 256 + k] = (bf16)v1;
        if (k < 128) {
            float v2 = 0.f;
            if (c < 47)      v2 = Wl2[k * 47 + c];
            else if (c < 94) v2 = Wr2[k * 47 + (c - 47)];
            Bt2[c * 128 + k] = (bf16)v2;
        }
    }
    // bucket histogram for blocks [0, ceil(E/4096))
    int nbinb = (E + 4095) / 4096;
    if (blockIdx.x < nbinb) {
        hist[tid] = 0; hist[tid + 256] = 0;
        __syncthreads();
        const int e0 = blockIdx.x * 4096;
        #pragma unroll
        for (int k = 0; k < 4; ++k) {
            int i4 = (e0 >> 2) + k * 256 + tid;
            if (i4 * 4 + 3 < E) {
                int4 d4 = ((const int4*)(ei + E))[i4];
                atomicAdd(&hist[d4.x >> BKT_SHIFT], 1);
                atomicAdd(&hist[d4.y >> BKT_SHIFT], 1);
                atomicAdd(&hist[d4.z >> BKT_SHIFT], 1);
                atomicAdd(&hist[d4.w >> BKT_SHIFT], 1);
            } else {
                for (int e = i4 * 4; e < min(E, i4 * 4 + 4); ++e)
                    atomicAdd(&hist[ei[E + e] >> BKT_SHIFT], 1);
            }
        }
        __syncthreads();
        for (int b = tid; b < nbkt; b += 256)
            if (hist[b]) atomicAdd(&btot[b], hist[b]);
    }
}

// In-block exclusive scan of btot[0..512) into sb[0..512], sb[512]=total.
__device__ __forceinline__ void scan_btot(const int* __restrict__ btot, int nbkt,
                                          int* sb, int* wsum) {
    const int tid = threadIdx.x, lane = tid & 63, wid = tid >> 6;
    int a = (tid < nbkt) ? btot[tid] : 0;
    int b2 = (tid + 256 < nbkt) ? btot[tid + 256] : 0;
    int ia = a, ib = b2;
    #pragma unroll
    for (int d = 1; d < 64; d <<= 1) {
        int t1 = __shfl_up(ia, d, 64);
        int t2 = __shfl_up(ib, d, 64);
        if (lane >= d) { ia += t1; ib += t2; }
    }
    if (lane == 63) { wsum[wid] = ia; wsum[4 + wid] = ib; }
    __syncthreads();
    if (tid == 0) {
        int c = 0;
        #pragma unroll
        for (int i = 0; i < 8; ++i) { int t = wsum[i]; wsum[i] = c; c += t; }
    }
    __syncthreads();
    sb[tid] = ia - a + wsum[wid];
    sb[tid + 256] = ib - b2 + wsum[4 + wid];
    if (tid == 255) sb[512] = ib + wsum[7];
    __syncthreads();
}

// ---- binning pass: in-block bbase scan -> histogram -> claim -> ranked write ----
__global__ __launch_bounds__(256) void k_bin(const int* __restrict__ ei,
                                             const int* __restrict__ btot,
                                             int* __restrict__ bfill,
                                             uint32_t* __restrict__ pair_buf,
                                             int E, int nbkt) {
    __shared__ int hist[512], gbase[512], hcur[512];
    __shared__ int sb[513], wsum[8];
    const int tid = threadIdx.x;
    const int e0 = blockIdx.x * TILE_E;
    hist[tid] = 0; hist[tid + 256] = 0;
    scan_btot(btot, nbkt, sb, wsum);   // includes syncs; hist zeroed before first sync

    int dreg[TILE_E / 256];
    #pragma unroll
    for (int k = 0; k < TILE_E / 256; ++k) {
        int e = e0 + k * 256 + tid;
        int d = (e < E) ? ei[E + e] : -1;
        dreg[k] = d;
        if (d >= 0) atomicAdd(&hist[d >> BKT_SHIFT], 1);
    }
    __syncthreads();

    for (int b = tid; b < nbkt; b += 256) {
        int h = hist[b];
        int g = (h > 0) ? atomicAdd(&bfill[b], h) : 0;
        gbase[b] = sb[b] + g;
        hcur[b] = 0;
    }
    __syncthreads();

    #pragma unroll
    for (int k = 0; k < TILE_E / 256; ++k) {
        int d = dreg[k];
        if (d >= 0) {
            int e = e0 + k * 256 + tid;
            int s = ei[e];
            int b = d >> BKT_SHIFT;
            int r = atomicAdd(&hcur[b], 1);
            pair_buf[(size_t)gbase[b] + r] =
                ((uint32_t)s << BKT_SHIFT) | (uint32_t)(d & (BKT_NODES - 1));
        }
    }
}

// ---- fill: one block per bucket ----
__global__ __launch_bounds__(256) void k_fill2(const uint32_t* __restrict__ pair_buf,
                                               const int* __restrict__ btot,
                                               int* __restrict__ row_ptr,
                                               float* __restrict__ inv_deg,
                                               int* __restrict__ col_idx,
                                               int n, int E, int nbkt) {
    __shared__ int hist[256], excl[256], hcur[256], wsum4[4];
    __shared__ int sb[513], wsum[8];
    const int b = blockIdx.x;
    const int tid = threadIdx.x, lane = tid & 63, wid = tid >> 6;
    const int n0 = b << BKT_SHIFT;
    hist[tid] = 0; hcur[tid] = 0;
    scan_btot(btot, nbkt, sb, wsum);
    const int s = sb[b], e = sb[b + 1];
    for (int i = s + tid; i < e; i += 256)
        atomicAdd(&hist[pair_buf[i] & (BKT_NODES - 1)], 1);
    __syncthreads();
    int v = hist[tid];
    int incl = v;
    #pragma unroll
    for (int d = 1; d < 64; d <<= 1) {
        int t = __shfl_up(incl, d, 64);
        if (lane >= d) incl += t;
    }
    if (lane == 63) wsum4[wid] = incl;
    __syncthreads();
    if (tid == 0) {
        int c = 0;
        #pragma unroll
        for (int i = 0; i < 4; ++i) { int t = wsum4[i]; wsum4[i] = c; c += t; }
    }
    __syncthreads();
    int ex = incl - v + wsum4[wid];
    excl[tid] = ex;
    int node = n0 + tid;
    if (node < n) {
        row_ptr[node] = s + ex;
        inv_deg[node] = 1.0f / (float)(v > 1 ? v : 1);
    }
    if (b == (int)gridDim.x - 1 && tid == 0) row_ptr[n] = E;
    __syncthreads();
    for (int i = s + tid; i < e; i += 256) {
        uint32_t pk = pair_buf[i];
        int dl = pk & (BKT_NODES - 1);
        int r = atomicAdd(&hcur[dl], 1);
        col_idx[s + excl[dl] + r] = (int)(pk >> BKT_SHIFT);
    }
}

// ---- mean-aggregate from fp8 table (128 B/row): wave per node, lane = 2 feats.
//      32-bit offsets (v_lshl_add_u32 + SADDR loads) — no 64-bit addr chains. ----
__global__ void k_aggregate(const unsigned char* __restrict__ src8, bf16* __restrict__ dst,
                            const int* __restrict__ row_ptr, const int* __restrict__ col_idx,
                            const float* __restrict__ inv_deg, int n) {
    int node = blockIdx.x * 4 + (threadIdx.x >> 6);
    int lane = threadIdx.x & 63;
    if (node >= n) return;
    int e0 = row_ptr[node], e1 = row_ptr[node + 1];
    float inv = inv_deg[node];
    const uint32_t l2 = (uint32_t)(lane << 1);
    float f0 = 0.f, f1 = 0.f;
    int e = e0;
    // align to 4
    for (; e < e1 && (e & 3); ++e) {
        uint32_t u = *(const uint16_t*)(src8 + (((uint32_t)col_idx[e] << 7) + l2));
        f32x2 p = __builtin_amdgcn_cvt_pk_f32_fp8(u, false);
        f0 += p[0]; f1 += p[1];
    }
    for (; e + 7 < e1; e += 8) {
        int4 i0 = *(const int4*)(col_idx + e);
        int4 i1 = *(const int4*)(col_idx + e + 4);
        uint32_t u0 = *(const uint16_t*)(src8 + (((uint32_t)i0.x << 7) + l2));
        uint32_t u1 = *(const uint16_t*)(src8 + (((uint32_t)i0.y << 7) + l2));
        uint32_t u2 = *(const uint16_t*)(src8 + (((uint32_t)i0.z << 7) + l2));
        uint32_t u3 = *(const uint16_t*)(src8 + (((uint32_t)i0.w << 7) + l2));
        uint32_t u4 = *(const uint16_t*)(src8 + (((uint32_t)i1.x << 7) + l2));
        uint32_t u5 = *(const uint16_t*)(src8 + (((uint32_t)i1.y << 7) + l2));
        uint32_t u6 = *(const uint16_t*)(src8 + (((uint32_t)i1.z << 7) + l2));
        uint32_t u7 = *(const uint16_t*)(src8 + (((uint32_t)i1.w << 7) + l2));
        f32x2 p0 = __builtin_amdgcn_cvt_pk_f32_fp8(u0, false);
        f32x2 p1 = __builtin_amdgcn_cvt_pk_f32_fp8(u1, false);
        f32x2 p2 = __builtin_amdgcn_cvt_pk_f32_fp8(u2, false);
        f32x2 p3 = __builtin_amdgcn_cvt_pk_f32_fp8(u3, false);
        f32x2 p4 = __builtin_amdgcn_cvt_pk_f32_fp8(u4, false);
        f32x2 p5 = __builtin_amdgcn_cvt_pk_f32_fp8(u5, false);
        f32x2 p6 = __builtin_amdgcn_cvt_pk_f32_fp8(u6, false);
        f32x2 p7 = __builtin_amdgcn_cvt_pk_f32_fp8(u7, false);
        f0 += ((p0[0] + p1[0]) + (p2[0] + p3[0])) + ((p4[0] + p5[0]) + (p6[0] + p7[0]));
        f1 += ((p0[1] + p1[1]) + (p2[1] + p3[1])) + ((p4[1] + p5[1]) + (p6[1] + p7[1]));
    }
    if (e + 3 < e1) {
        int4 i0 = *(const int4*)(col_idx + e);
        uint32_t u0 = *(const uint16_t*)(src8 + (((uint32_t)i0.x << 7) + l2));
        uint32_t u1 = *(const uint16_t*)(src8 + (((uint32_t)i0.y << 7) + l2));
        uint32_t u2 = *(const uint16_t*)(src8 + (((uint32_t)i0.z << 7) + l2));
        uint32_t u3 = *(const uint16_t*)(src8 + (((uint32_t)i0.w << 7) + l2));
        f32x2 p0 = __builtin_amdgcn_cvt_pk_f32_fp8(u0, false);
        f32x2 p1 = __builtin_amdgcn_cvt_pk_f32_fp8(u1, false);
        f32x2 p2 = __builtin_amdgcn_cvt_pk_f32_fp8(u2, false);
        f32x2 p3 = __builtin_amdgcn_cvt_pk_f32_fp8(u3, false);
        f0 += (p0[0] + p1[0]) + (p2[0] + p3[0]);
        f1 += (p0[1] + p1[1]) + (p2[1] + p3[1]);
        e += 4;
    }
    for (; e < e1; ++e) {
        uint32_t u = *(const uint16_t*)(src8 + (((uint32_t)col_idx[e] << 7) + l2));
        f32x2 p = __builtin_amdgcn_cvt_pk_f32_fp8(u, false);
        f0 += p[0]; f1 += p[1];
    }
    bf16x2 o; o[0] = (bf16)(f0 * inv); o[1] = (bf16)(f1 * inv);
    *(bf16x2*)(dst + (size_t)node * 128 + (lane << 1)) = o;
}

// ---- MFMA GEMM, 2-phase pipeline (round-5 proven structure) with
//      (a) bf16 h output (halves write traffic + bn_apply read traffic),
//      (b) 16-way striped stats copies (cuts global-atomic serialization 16x). ----
template<int CH, bool STATS>
__global__ __launch_bounds__(256) void k_gemm6(
    const bf16* __restrict__ A1, const bf16* __restrict__ A2, const bf16* __restrict__ Bt,
    const float* __restrict__ bias, bf16* __restrict__ outH,
    fp8* __restrict__ yl8, bf16* __restrict__ yrbf, float* __restrict__ stats, int M) {
    __shared__ __attribute__((aligned(16))) bf16 sA[2][4096];
    __shared__ __attribute__((aligned(16))) bf16 sB[2][4096];
    __shared__ float scol[128], scol2[128];
    constexpr int LDB = CH * 32;             // Bt leading dim (elements)
    const int tid = threadIdx.x;
    const int w = tid >> 6, l = tid & 63;
    const int q = l >> 4, r = l & 15;
    const int r0 = blockIdx.x * 128;
    if (STATS && tid < 128) { scol[tid] = 0.f; scol2[tid] = 0.f; }

    auto stage = [&](int buf, int c) {
        const bf16* As = (c < 4) ? A1 : A2;
        const int ka = (c & 3) * 32;
        #pragma unroll
        for (int i = 0; i < 2; ++i) {
            const int T = w * 2 + i;
            const bf16* ga = As + (size_t)(r0 + T * 16 + r) * 128 + ka + q * 8;
            const bf16* gb = Bt + (T * 16 + r) * LDB + c * 32 + q * 8;
            __builtin_amdgcn_global_load_lds((AS1 uint32_t*)(uintptr_t)ga,
                (AS3 uint32_t*)(uint32_t)(uintptr_t)(&sA[buf][T * 512]), 16, 0, 0);
            __builtin_amdgcn_global_load_lds((AS1 uint32_t*)(uintptr_t)gb,
                (AS3 uint32_t*)(uint32_t)(uintptr_t)(&sB[buf][T * 512]), 16, 0, 0);
        }
    };

    f32x4 acc[2][8];
    #pragma unroll
    for (int i = 0; i < 2; ++i)
        #pragma unroll
        for (int j = 0; j < 8; ++j) { acc[i][j][0] = 0.f; acc[i][j][1] = 0.f; acc[i][j][2] = 0.f; acc[i][j][3] = 0.f; }

    stage(0, 0);
    __syncthreads();                 // drains vmcnt(0): buf0 fully landed

    #pragma unroll
    for (int c = 0; c < CH; ++c) {
        const int cur = c & 1;
        if (c + 1 < CH) stage(cur ^ 1, c + 1);   // issue next loads; fly under compute
        bf16x8 af0 = *(const bf16x8*)&sA[cur][(w * 2 + 0) * 512 + q * 128 + r * 8];
        bf16x8 af1 = *(const bf16x8*)&sA[cur][(w * 2 + 1) * 512 + q * 128 + r * 8];
        #pragma unroll
        for (int ct = 0; ct < 8; ++ct) {
            bf16x8 bv = *(const bf16x8*)&sB[cur][ct * 512 + q * 128 + r * 8];
            acc[0][ct] = __builtin_amdgcn_mfma_f32_16x16x32_bf16(af0, bv, acc[0][ct], 0, 0, 0);
            acc[1][ct] = __builtin_amdgcn_mfma_f32_16x16x32_bf16(af1, bv, acc[1][ct], 0, 0, 0);
        }
        __syncthreads();             // drain: next buf landed; all reads of cur done
    }

    if (STATS) {
        #pragma unroll
        for (int ct = 0; ct < 8; ++ct) {
            int col = ct * 16 + r;
            float bv = bias ? bias[col] : 0.f;
            float s_c = 0.f, q_c = 0.f;
            #pragma unroll
            for (int rt = 0; rt < 2; ++rt) {
                #pragma unroll
                for (int j = 0; j < 4; ++j) {
                    int row = r0 + w * 32 + rt * 16 + q * 4 + j;
                    if (row < M) {
                        float v = acc[rt][ct][j] + bv;
                        outH[(size_t)row * 128 + col] = (bf16)v;
                        s_c += v; q_c += v * v;
                    }
                }
            }
            atomicAdd(&scol[col], s_c);
            atomicAdd(&scol2[col], q_c);
        }
        __syncthreads();
        float* sbase = stats + ((blockIdx.x & (NCOPY - 1)) << 8);
        if (tid < 128) {
            atomicAdd(&sbase[tid], scol[tid]);
            atomicAdd(&sbase[128 + tid], scol2[tid]);
        }
    } else {
        #pragma unroll
        for (int rt = 0; rt < 2; ++rt) {
            #pragma unroll
            for (int ct = 0; ct < 8; ++ct) {
                int col = ct * 16 + r;
                #pragma unroll
                for (int j = 0; j < 4; ++j) {
                    int row = r0 + w * 32 + rt * 16 + q * 4 + j;
                    if (row >= M) continue;
                    if (col < 47)      yl8[(size_t)row * 64 + col] = fp8(acc[rt][ct][j]);
                    else if (col < 94) yrbf[(size_t)row * 48 + (col - 47)] = (bf16)acc[rt][ct][j];
                }
            }
        }
    }
}

// ---- BN apply + ReLU (bf16 h input, 16 striped stats copies) ----
__global__ void k_bn_apply(const bf16* __restrict__ h, const float* __restrict__ sums,
                           const float* __restrict__ gma, const float* __restrict__ bta,
                           bf16* __restrict__ out, unsigned char* __restrict__ out8, int n) {
    int g = blockIdx.x * blockDim.x + threadIdx.x;
    int row = g >> 6, c2 = g & 63;
    if (row >= n) return;
    int col = c2 << 1;
    float s0 = 0.f, s1 = 0.f, q0 = 0.f, q1 = 0.f;
    #pragma unroll
    for (int cpy = 0; cpy < NCOPY; ++cpy) {
        const float* S = sums + (cpy << 8);
        s0 += S[col];       s1 += S[col + 1];
        q0 += S[128 + col]; q1 += S[128 + col + 1];
    }
    float invn = 1.0f / (float)n;
    float mu0 = s0 * invn, mu1 = s1 * invn;
    float v0 = q0 * invn - mu0 * mu0;
    float v1 = q1 * invn - mu1 * mu1;
    float sc0 = gma[col] * rsqrtf(v0 + BN_EPS);
    float sc1 = gma[col + 1] * rsqrtf(v1 + BN_EPS);
    float sh0 = bta[col] - mu0 * sc0;
    float sh1 = bta[col + 1] - mu1 * sc1;
    bf16x2 hv = *(const bf16x2*)(h + (size_t)row * 128 + col);
    float r0 = fmaxf((float)hv[0] * sc0 + sh0, 0.f);
    float r1 = fmaxf((float)hv[1] * sc1 + sh1, 0.f);
    bf16x2 o; o[0] = (bf16)r0; o[1] = (bf16)r1;
    *(bf16x2*)(out + (size_t)row * 128 + col) = o;
    uchar2 o8; o8.x = fp8(r0).__x; o8.y = fp8(r1).__x;
    *(uchar2*)(out8 + (size_t)row * 128 + col) = o8;
}

// ---- final: gather-mean of yl (fp8, 64B line/edge) + yr + bl2, log_softmax.
//      Latency-MLP version: 16 edges per batch -> 4 masked idx loads + 4
//      independent dword gathers (16 distinct lines) in flight per wave. ----
__global__ void k_final(const unsigned char* __restrict__ yl, const bf16* __restrict__ yr,
                        const int* __restrict__ row_ptr, const int* __restrict__ col_idx,
                        const float* __restrict__ inv_deg, const float* __restrict__ bl2,
                        float* __restrict__ out, int n) {
    int node = blockIdx.x * 4 + (threadIdx.x >> 6);
    int lane = threadIdx.x & 63;
    if (node >= n) return;
    int e0 = row_ptr[node], e1 = row_ptr[node + 1];
    float inv = inv_deg[node];
    const int sub = lane >> 4;               // edge slot within group of 4
    const int c4 = lane & 15;                // feature group: feats 4*c4 .. 4*c4+3
    const uint32_t loff = (uint32_t)(c4 << 2);
    float a0 = 0.f, a1 = 0.f, a2 = 0.f, a3 = 0.f;
    for (int base = e0; base < e1; base += 16) {
        int ee0 = base + sub;
        int ee1 = base + 4 + sub;
        int ee2 = base + 8 + sub;
        int ee3 = base + 12 + sub;
        bool k0 = ee0 < e1, k1 = ee1 < e1, k2 = ee2 < e1, k3 = ee3 < e1;
        int i0 = col_idx[k0 ? ee0 : e0];
        int i1 = col_idx[k1 ? ee1 : e0];
        int i2 = col_idx[k2 ? ee2 : e0];
        int i3 = col_idx[k3 ? ee3 : e0];
        uint32_t u0 = *(const uint32_t*)(yl + (((uint32_t)i0 << 6) + loff));
        uint32_t u1 = *(const uint32_t*)(yl + (((uint32_t)i1 << 6) + loff));
        uint32_t u2 = *(const uint32_t*)(yl + (((uint32_t)i2 << 6) + loff));
        uint32_t u3 = *(const uint32_t*)(yl + (((uint32_t)i3 << 6) + loff));
        u0 = k0 ? u0 : 0u;
        u1 = k1 ? u1 : 0u;
        u2 = k2 ? u2 : 0u;
        u3 = k3 ? u3 : 0u;
        f32x2 p0l = __builtin_amdgcn_cvt_pk_f32_fp8(u0, false);
        f32x2 p0h = __builtin_amdgcn_cvt_pk_f32_fp8(u0, true);
        f32x2 p1l = __builtin_amdgcn_cvt_pk_f32_fp8(u1, false);
        f32x2 p1h = __builtin_amdgcn_cvt_pk_f32_fp8(u1, true);
        f32x2 p2l = __builtin_amdgcn_cvt_pk_f32_fp8(u2, false);
        f32x2 p2h = __builtin_amdgcn_cvt_pk_f32_fp8(u2, true);
        f32x2 p3l = __builtin_amdgcn_cvt_pk_f32_fp8(u3, false);
        f32x2 p3h = __builtin_amdgcn_cvt_pk_f32_fp8(u3, true);
        a0 += (p0l[0] + p1l[0]) + (p2l[0] + p3l[0]);
        a1 += (p0l[1] + p1l[1]) + (p2l[1] + p3l[1]);
        a2 += (p0h[0] + p1h[0]) + (p2h[0] + p3h[0]);
        a3 += (p0h[1] + p1h[1]) + (p2h[1] + p3h[1]);
    }
    // sum the 4 edge subgroups (lanes differing in bits 4,5 share c4)
    a0 += __shfl_xor(a0, 16, 64); a1 += __shfl_xor(a1, 16, 64);
    a2 += __shfl_xor(a2, 16, 64); a3 += __shfl_xor(a3, 16, 64);
    a0 += __shfl_xor(a0, 32, 64); a1 += __shfl_xor(a1, 32, 64);
    a2 += __shfl_xor(a2, 32, 64); a3 += __shfl_xor(a3, 32, 64);
    const int f0 = c4 << 2;
    const bf16* yrp = yr + (size_t)node * 48;
    float v0 = (f0 + 0 < 47) ? a0 * inv + (float)yrp[f0 + 0] + bl2[f0 + 0] : -__builtin_inff();
    float v1 = (f0 + 1 < 47) ? a1 * inv + (float)yrp[f0 + 1] + bl2[f0 + 1] : -__builtin_inff();
    float v2 = (f0 + 2 < 47) ? a2 * inv + (float)yrp[f0 + 2] + bl2[f0 + 2] : -__builtin_inff();
    float v3 = (f0 + 3 < 47) ? a3 * inv + (float)yrp[f0 + 3] + bl2[f0 + 3] : -__builtin_inff();
    float m = fmaxf(fmaxf(v0, v1), fmaxf(v2, v3));
    #pragma unroll
    for (int o = 1; o < 16; o <<= 1) m = fmaxf(m, __shfl_xor(m, o, 64));
    float ex0 = (f0 + 0 < 47) ? __expf(v0 - m) : 0.f;
    float ex1 = (f0 + 1 < 47) ? __expf(v1 - m) : 0.f;
    float ex2 = (f0 + 2 < 47) ? __expf(v2 - m) : 0.f;
    float ex3 = (f0 + 3 < 47) ? __expf(v3 - m) : 0.f;
    float s = (ex0 + ex1) + (ex2 + ex3);
    #pragma unroll
    for (int o = 1; o < 16; o <<= 1) s += __shfl_xor(s, o, 64);
    float ls = __logf(s);
    if (lane < 16) {
        float* op = out + (size_t)node * 47 + f0;
        if (f0 + 0 < 47) op[0] = v0 - m - ls;
        if (f0 + 1 < 47) op[1] = v1 - m - ls;
        if (f0 + 2 < 47) op[2] = v2 - m - ls;
        if (f0 + 3 < 47) op[3] = v3 - m - ls;
    }
}

extern "C" void kernel_launch(void* const* d_in, const int* in_sizes, int n_in,
                              void* d_out, int out_size, void* d_ws, size_t ws_size,
                              hipStream_t stream) {
    const float* x   = (const float*)d_in[0];
    const int*   ei  = (const int*)d_in[1];
    const float* Wl0 = (const float*)d_in[2];
    const float* bl0 = (const float*)d_in[3];
    const float* Wr0 = (const float*)d_in[4];
    const float* g0  = (const float*)d_in[5];
    const float* be0 = (const float*)d_in[6];
    const float* Wl1 = (const float*)d_in[7];
    const float* bl1 = (const float*)d_in[8];
    const float* Wr1 = (const float*)d_in[9];
    const float* g1  = (const float*)d_in[10];
    const float* be1 = (const float*)d_in[11];
    const float* Wl2 = (const float*)d_in[12];
    const float* bl2 = (const float*)d_in[13];
    const float* Wr2 = (const float*)d_in[14];
    float* out = (float*)d_out;

    const int N  = in_sizes[0] / 128;
    const int E  = in_sizes[1] / 2;
    const int NP = ((N + 127) / 128) * 128;
    const int NBKT = (N + BKT_NODES - 1) / BKT_NODES;

    char* p = (char*)d_ws;
    size_t off = 0;
    auto alloc = [&](size_t b) { char* r = p + off; off += (b + 255) & ~(size_t)255; return r; };
    // zero-init region (one memset): bfill, bnsum (2 layers x NCOPY x 256), btot
    int*   bfill   = (int*)alloc(1024 * 4);
    float* bnsum   = (float*)alloc(2 * NCOPY * 256 * 4);
    int*   btot    = (int*)alloc(512 * 4);
    size_t zero_span = off;
    int*   row_ptr = (int*)alloc((size_t)(N + 1) * 4);
    float* invd    = (float*)alloc((size_t)N * 4);
    int*   col_idx = (int*)alloc((size_t)E * 4);
    uint32_t* pair_buf = (uint32_t*)alloc((size_t)E * 4);
    bf16*  x_bf    = (bf16*)alloc((size_t)NP * 128 * 2);
    bf16*  aggbf   = (bf16*)alloc((size_t)NP * 128 * 2);
    bf16*  hbf     = (bf16*)alloc((size_t)NP * 128 * 2);
    unsigned char* h8 = (unsigned char*)alloc((size_t)NP * 128);
    float* bufF    = (float*)alloc((size_t)NP * 128 * 4 + 256);
    bf16*  Bt0     = (bf16*)alloc(128 * 256 * 2);
    bf16*  Bt1     = (bf16*)alloc(128 * 256 * 2);
    bf16*  Bt2     = (bf16*)alloc(128 * 128 * 2);
    // aliases into bufF (sequentially dead/live): x8 (pre-GEMM0), hraw (bf16 h,
    // GEMM->bn_apply), yl8/yrbf (post-BN1)
    unsigned char* x8 = (unsigned char*)bufF;
    bf16*  hraw = (bf16*)bufF;
    fp8*   yl8  = (fp8*)bufF;
    bf16*  yrbf = (bf16*)((char*)bufF + (size_t)NP * 64);

    hipMemsetAsync(bfill, 0, zero_span, stream);

    int n4 = N * 128 / 4;
    k_setup<<<(n4 + 255) / 256, 256, 0, stream>>>(x, x_bf, x8, n4, ei, btot, E, NBKT,
                                                  Wl0, Wr0, Wl1, Wr1, Wl2, Wr2, Bt0, Bt1, Bt2);
    k_bin<<<(E + TILE_E - 1) / TILE_E, 256, 0, stream>>>(ei, btot, bfill, pair_buf, E, NBKT);
    k_fill2<<<NBKT, 256, 0, stream>>>(pair_buf, btot, row_ptr, invd, col_idx, N, E, NBKT);

    int aggBlocks  = (N + 3) / 4;
    int gemmBlocks = NP / 128;

    // Layer 0
    k_aggregate<<<aggBlocks, 256, 0, stream>>>(x8, aggbf, row_ptr, col_idx, invd, N);
    k_gemm6<8, true><<<gemmBlocks, 256, 0, stream>>>(aggbf, x_bf, Bt0, bl0, hraw, nullptr, nullptr, bnsum, N);
    k_bn_apply<<<(N * 64 + 255) / 256, 256, 0, stream>>>(hraw, bnsum, g0, be0, hbf, h8, N);
    // Layer 1
    k_aggregate<<<aggBlocks, 256, 0, stream>>>(h8, aggbf, row_ptr, col_idx, invd, N);
    k_gemm6<8, true><<<gemmBlocks, 256, 0, stream>>>(aggbf, hbf, Bt1, bl1, hraw, nullptr, nullptr, bnsum + NCOPY * 256, N);
    k_bn_apply<<<(N * 64 + 255) / 256, 256, 0, stream>>>(hraw, bnsum + NCOPY * 256, g1, be1, hbf, h8, N);
    // Layer 2: project to yl (fp8, stride 64) / yr (bf16), then gather + log_softmax
    k_gemm6<4, false><<<gemmBlocks, 256, 0, stream>>>(hbf, hbf, Bt2, nullptr, nullptr, yl8, yrbf, nullptr, N);
    k_final<<<aggBlocks, 256, 0, stream>>>((const unsigned char*)yl8, yrbf, row_ptr, col_idx, invd, bl2, out, N);
}

// Round 8
// 503.654 us; speedup vs baseline: 1.3095x; 1.3095x over previous
//
#include <hip/hip_runtime.h>
#include <hip/hip_fp8.h>
#include <stdint.h>

#define AS1 __attribute__((address_space(1)))
#define AS3 __attribute__((address_space(3)))

typedef __bf16 bf16;
typedef __bf16 bf16x2 __attribute__((ext_vector_type(2)));
typedef __bf16 bf16x4v __attribute__((ext_vector_type(4)));
typedef __bf16 bf16x8 __attribute__((ext_vector_type(8)));
typedef float f32x4 __attribute__((ext_vector_type(4)));
typedef float f32x2 __attribute__((ext_vector_type(2)));
typedef __hip_fp8_e4m3 fp8;

#define BN_EPS 1e-5f
#define BKT_SHIFT 8              // 256 nodes per bucket
#define BKT_NODES 256
#define TILE_E 2048              // edges per binning block
#define NCOPY 16                 // striped stats copies (atomic de-contention)

// ---- fused setup: weight cvt+transpose, x fp32 -> bf16 + fp8, bucket count ----
__global__ void k_setup(const float* __restrict__ x, bf16* __restrict__ x_bf,
                        unsigned char* __restrict__ x8, int n4,
                        const int* __restrict__ ei, int* __restrict__ btot, int E, int nbkt,
                        const float* __restrict__ Wl0, const float* __restrict__ Wr0,
                        const float* __restrict__ Wl1, const float* __restrict__ Wr1,
                        const float* __restrict__ Wl2, const float* __restrict__ Wr2,
                        bf16* __restrict__ Bt0, bf16* __restrict__ Bt1, bf16* __restrict__ Bt2) {
    __shared__ int hist[512];
    const int tid = threadIdx.x;
    int g = blockIdx.x * 256 + tid;
    if (g < n4) {
        float4 v = ((const float4*)x)[g];
        bf16x4v o; o[0] = (bf16)v.x; o[1] = (bf16)v.y; o[2] = (bf16)v.z; o[3] = (bf16)v.w;
        ((bf16x4v*)x_bf)[g] = o;
        uchar4 o8;
        o8.x = fp8(v.x).__x; o8.y = fp8(v.y).__x; o8.z = fp8(v.z).__x; o8.w = fp8(v.w).__x;
        ((uchar4*)x8)[g] = o8;
    }
    if (blockIdx.x < 128) {
        int idx = g;                 // 32768 threads: c in [0,128), k in [0,256)
        int c = idx >> 8, k = idx & 255;
        float v0 = (k < 128) ? Wl0[k * 128 + c] : Wr0[(k - 128) * 128 + c];
        Bt0[c * 256 + k] = (bf16)v0;
        float v1 = (k < 128) ? Wl1[k * 128 + c] : Wr1[(k - 128) * 128 + c];
        Bt1[c * 256 + k] = (bf16)v1;
        if (k < 128) {
            float v2 = 0.f;
            if (c < 47)      v2 = Wl2[k * 47 + c];
            else if (c < 94) v2 = Wr2[k * 47 + (c - 47)];
            Bt2[c * 128 + k] = (bf16)v2;
        }
    }
    // bucket histogram for blocks [0, ceil(E/4096))
    int nbinb = (E + 4095) / 4096;
    if (blockIdx.x < nbinb) {
        hist[tid] = 0; hist[tid + 256] = 0;
        __syncthreads();
        const int e0 = blockIdx.x * 4096;
        #pragma unroll
        for (int k = 0; k < 4; ++k) {
            int i4 = (e0 >> 2) + k * 256 + tid;
            if (i4 * 4 + 3 < E) {
                int4 d4 = ((const int4*)(ei + E))[i4];
                atomicAdd(&hist[d4.x >> BKT_SHIFT], 1);
                atomicAdd(&hist[d4.y >> BKT_SHIFT], 1);
                atomicAdd(&hist[d4.z >> BKT_SHIFT], 1);
                atomicAdd(&hist[d4.w >> BKT_SHIFT], 1);
            } else {
                for (int e = i4 * 4; e < min(E, i4 * 4 + 4); ++e)
                    atomicAdd(&hist[ei[E + e] >> BKT_SHIFT], 1);
            }
        }
        __syncthreads();
        for (int b = tid; b < nbkt; b += 256)
            if (hist[b]) atomicAdd(&btot[b], hist[b]);
    }
}

// In-block exclusive scan of btot[0..512) into sb[0..512], sb[512]=total.
__device__ __forceinline__ void scan_btot(const int* __restrict__ btot, int nbkt,
                                          int* sb, int* wsum) {
    const int tid = threadIdx.x, lane = tid & 63, wid = tid >> 6;
    int a = (tid < nbkt) ? btot[tid] : 0;
    int b2 = (tid + 256 < nbkt) ? btot[tid + 256] : 0;
    int ia = a, ib = b2;
    #pragma unroll
    for (int d = 1; d < 64; d <<= 1) {
        int t1 = __shfl_up(ia, d, 64);
        int t2 = __shfl_up(ib, d, 64);
        if (lane >= d) { ia += t1; ib += t2; }
    }
    if (lane == 63) { wsum[wid] = ia; wsum[4 + wid] = ib; }
    __syncthreads();
    if (tid == 0) {
        int c = 0;
        #pragma unroll
        for (int i = 0; i < 8; ++i) { int t = wsum[i]; wsum[i] = c; c += t; }
    }
    __syncthreads();
    sb[tid] = ia - a + wsum[wid];
    sb[tid + 256] = ib - b2 + wsum[4 + wid];
    if (tid == 255) sb[512] = ib + wsum[7];
    __syncthreads();
}

// ---- binning pass: in-block bbase scan -> histogram -> claim -> ranked write ----
__global__ __launch_bounds__(256) void k_bin(const int* __restrict__ ei,
                                             const int* __restrict__ btot,
                                             int* __restrict__ bfill,
                                             uint32_t* __restrict__ pair_buf,
                                             int E, int nbkt) {
    __shared__ int hist[512], gbase[512], hcur[512];
    __shared__ int sb[513], wsum[8];
    const int tid = threadIdx.x;
    const int e0 = blockIdx.x * TILE_E;
    hist[tid] = 0; hist[tid + 256] = 0;
    scan_btot(btot, nbkt, sb, wsum);   // includes syncs; hist zeroed before first sync

    int dreg[TILE_E / 256];
    #pragma unroll
    for (int k = 0; k < TILE_E / 256; ++k) {
        int e = e0 + k * 256 + tid;
        int d = (e < E) ? ei[E + e] : -1;
        dreg[k] = d;
        if (d >= 0) atomicAdd(&hist[d >> BKT_SHIFT], 1);
    }
    __syncthreads();

    for (int b = tid; b < nbkt; b += 256) {
        int h = hist[b];
        int g = (h > 0) ? atomicAdd(&bfill[b], h) : 0;
        gbase[b] = sb[b] + g;
        hcur[b] = 0;
    }
    __syncthreads();

    #pragma unroll
    for (int k = 0; k < TILE_E / 256; ++k) {
        int d = dreg[k];
        if (d >= 0) {
            int e = e0 + k * 256 + tid;
            int s = ei[e];
            int b = d >> BKT_SHIFT;
            int r = atomicAdd(&hcur[b], 1);
            pair_buf[(size_t)gbase[b] + r] =
                ((uint32_t)s << BKT_SHIFT) | (uint32_t)(d & (BKT_NODES - 1));
        }
    }
}

// ---- fill: one block per bucket ----
__global__ __launch_bounds__(256) void k_fill2(const uint32_t* __restrict__ pair_buf,
                                               const int* __restrict__ btot,
                                               int* __restrict__ row_ptr,
                                               float* __restrict__ inv_deg,
                                               int* __restrict__ col_idx,
                                               int n, int E, int nbkt) {
    __shared__ int hist[256], excl[256], hcur[256], wsum4[4];
    __shared__ int sb[513], wsum[8];
    const int b = blockIdx.x;
    const int tid = threadIdx.x, lane = tid & 63, wid = tid >> 6;
    const int n0 = b << BKT_SHIFT;
    hist[tid] = 0; hcur[tid] = 0;
    scan_btot(btot, nbkt, sb, wsum);
    const int s = sb[b], e = sb[b + 1];
    for (int i = s + tid; i < e; i += 256)
        atomicAdd(&hist[pair_buf[i] & (BKT_NODES - 1)], 1);
    __syncthreads();
    int v = hist[tid];
    int incl = v;
    #pragma unroll
    for (int d = 1; d < 64; d <<= 1) {
        int t = __shfl_up(incl, d, 64);
        if (lane >= d) incl += t;
    }
    if (lane == 63) wsum4[wid] = incl;
    __syncthreads();
    if (tid == 0) {
        int c = 0;
        #pragma unroll
        for (int i = 0; i < 4; ++i) { int t = wsum4[i]; wsum4[i] = c; c += t; }
    }
    __syncthreads();
    int ex = incl - v + wsum4[wid];
    excl[tid] = ex;
    int node = n0 + tid;
    if (node < n) {
        row_ptr[node] = s + ex;
        inv_deg[node] = 1.0f / (float)(v > 1 ? v : 1);
    }
    if (b == (int)gridDim.x - 1 && tid == 0) row_ptr[n] = E;
    __syncthreads();
    for (int i = s + tid; i < e; i += 256) {
        uint32_t pk = pair_buf[i];
        int dl = pk & (BKT_NODES - 1);
        int r = atomicAdd(&hcur[dl], 1);
        col_idx[s + excl[dl] + r] = (int)(pk >> BKT_SHIFT);
    }
}

// ---- mean-aggregate from fp8 table (128 B/row): wave per node, lane = 2 feats.
//      32-bit offsets (v_lshl_add_u32 + SADDR loads) — no 64-bit addr chains. ----
__global__ void k_aggregate(const unsigned char* __restrict__ src8, bf16* __restrict__ dst,
                            const int* __restrict__ row_ptr, const int* __restrict__ col_idx,
                            const float* __restrict__ inv_deg, int n) {
    int node = blockIdx.x * 4 + (threadIdx.x >> 6);
    int lane = threadIdx.x & 63;
    if (node >= n) return;
    int e0 = row_ptr[node], e1 = row_ptr[node + 1];
    float inv = inv_deg[node];
    const uint32_t l2 = (uint32_t)(lane << 1);
    float f0 = 0.f, f1 = 0.f;
    int e = e0;
    // align to 4
    for (; e < e1 && (e & 3); ++e) {
        uint32_t u = *(const uint16_t*)(src8 + (((uint32_t)col_idx[e] << 7) + l2));
        f32x2 p = __builtin_amdgcn_cvt_pk_f32_fp8(u, false);
        f0 += p[0]; f1 += p[1];
    }
    for (; e + 7 < e1; e += 8) {
        int4 i0 = *(const int4*)(col_idx + e);
        int4 i1 = *(const int4*)(col_idx + e + 4);
        uint32_t u0 = *(const uint16_t*)(src8 + (((uint32_t)i0.x << 7) + l2));
        uint32_t u1 = *(const uint16_t*)(src8 + (((uint32_t)i0.y << 7) + l2));
        uint32_t u2 = *(const uint16_t*)(src8 + (((uint32_t)i0.z << 7) + l2));
        uint32_t u3 = *(const uint16_t*)(src8 + (((uint32_t)i0.w << 7) + l2));
        uint32_t u4 = *(const uint16_t*)(src8 + (((uint32_t)i1.x << 7) + l2));
        uint32_t u5 = *(const uint16_t*)(src8 + (((uint32_t)i1.y << 7) + l2));
        uint32_t u6 = *(const uint16_t*)(src8 + (((uint32_t)i1.z << 7) + l2));
        uint32_t u7 = *(const uint16_t*)(src8 + (((uint32_t)i1.w << 7) + l2));
        f32x2 p0 = __builtin_amdgcn_cvt_pk_f32_fp8(u0, false);
        f32x2 p1 = __builtin_amdgcn_cvt_pk_f32_fp8(u1, false);
        f32x2 p2 = __builtin_amdgcn_cvt_pk_f32_fp8(u2, false);
        f32x2 p3 = __builtin_amdgcn_cvt_pk_f32_fp8(u3, false);
        f32x2 p4 = __builtin_amdgcn_cvt_pk_f32_fp8(u4, false);
        f32x2 p5 = __builtin_amdgcn_cvt_pk_f32_fp8(u5, false);
        f32x2 p6 = __builtin_amdgcn_cvt_pk_f32_fp8(u6, false);
        f32x2 p7 = __builtin_amdgcn_cvt_pk_f32_fp8(u7, false);
        f0 += ((p0[0] + p1[0]) + (p2[0] + p3[0])) + ((p4[0] + p5[0]) + (p6[0] + p7[0]));
        f1 += ((p0[1] + p1[1]) + (p2[1] + p3[1])) + ((p4[1] + p5[1]) + (p6[1] + p7[1]));
    }
    if (e + 3 < e1) {
        int4 i0 = *(const int4*)(col_idx + e);
        uint32_t u0 = *(const uint16_t*)(src8 + (((uint32_t)i0.x << 7) + l2));
        uint32_t u1 = *(const uint16_t*)(src8 + (((uint32_t)i0.y << 7) + l2));
        uint32_t u2 = *(const uint16_t*)(src8 + (((uint32_t)i0.z << 7) + l2));
        uint32_t u3 = *(const uint16_t*)(src8 + (((uint32_t)i0.w << 7) + l2));
        f32x2 p0 = __builtin_amdgcn_cvt_pk_f32_fp8(u0, false);
        f32x2 p1 = __builtin_amdgcn_cvt_pk_f32_fp8(u1, false);
        f32x2 p2 = __builtin_amdgcn_cvt_pk_f32_fp8(u2, false);
        f32x2 p3 = __builtin_amdgcn_cvt_pk_f32_fp8(u3, false);
        f0 += (p0[0] + p1[0]) + (p2[0] + p3[0]);
        f1 += (p0[1] + p1[1]) + (p2[1] + p3[1]);
        e += 4;
    }
    for (; e < e1; ++e) {
        uint32_t u = *(const uint16_t*)(src8 + (((uint32_t)col_idx[e] << 7) + l2));
        f32x2 p = __builtin_amdgcn_cvt_pk_f32_fp8(u, false);
        f0 += p[0]; f1 += p[1];
    }
    bf16x2 o; o[0] = (bf16)(f0 * inv); o[1] = (bf16)(f1 * inv);
    *(bf16x2*)(dst + (size_t)node * 128 + (lane << 1)) = o;
}

// ---- MFMA GEMM, 2-phase pipeline with bf16 h output + striped stats ----
template<int CH, bool STATS>
__global__ __launch_bounds__(256) void k_gemm6(
    const bf16* __restrict__ A1, const bf16* __restrict__ A2, const bf16* __restrict__ Bt,
    const float* __restrict__ bias, bf16* __restrict__ outH,
    fp8* __restrict__ yl8, bf16* __restrict__ yrbf, float* __restrict__ stats, int M) {
    __shared__ __attribute__((aligned(16))) bf16 sA[2][4096];
    __shared__ __attribute__((aligned(16))) bf16 sB[2][4096];
    __shared__ float scol[128], scol2[128];
    constexpr int LDB = CH * 32;             // Bt leading dim (elements)
    const int tid = threadIdx.x;
    const int w = tid >> 6, l = tid & 63;
    const int q = l >> 4, r = l & 15;
    const int r0 = blockIdx.x * 128;
    if (STATS && tid < 128) { scol[tid] = 0.f; scol2[tid] = 0.f; }

    auto stage = [&](int buf, int c) {
        const bf16* As = (c < 4) ? A1 : A2;
        const int ka = (c & 3) * 32;
        #pragma unroll
        for (int i = 0; i < 2; ++i) {
            const int T = w * 2 + i;
            const bf16* ga = As + (size_t)(r0 + T * 16 + r) * 128 + ka + q * 8;
            const bf16* gb = Bt + (T * 16 + r) * LDB + c * 32 + q * 8;
            __builtin_amdgcn_global_load_lds((AS1 uint32_t*)(uintptr_t)ga,
                (AS3 uint32_t*)(uint32_t)(uintptr_t)(&sA[buf][T * 512]), 16, 0, 0);
            __builtin_amdgcn_global_load_lds((AS1 uint32_t*)(uintptr_t)gb,
                (AS3 uint32_t*)(uint32_t)(uintptr_t)(&sB[buf][T * 512]), 16, 0, 0);
        }
    };

    f32x4 acc[2][8];
    #pragma unroll
    for (int i = 0; i < 2; ++i)
        #pragma unroll
        for (int j = 0; j < 8; ++j) { acc[i][j][0] = 0.f; acc[i][j][1] = 0.f; acc[i][j][2] = 0.f; acc[i][j][3] = 0.f; }

    stage(0, 0);
    __syncthreads();                 // drains vmcnt(0): buf0 fully landed

    #pragma unroll
    for (int c = 0; c < CH; ++c) {
        const int cur = c & 1;
        if (c + 1 < CH) stage(cur ^ 1, c + 1);   // issue next loads; fly under compute
        bf16x8 af0 = *(const bf16x8*)&sA[cur][(w * 2 + 0) * 512 + q * 128 + r * 8];
        bf16x8 af1 = *(const bf16x8*)&sA[cur][(w * 2 + 1) * 512 + q * 128 + r * 8];
        #pragma unroll
        for (int ct = 0; ct < 8; ++ct) {
            bf16x8 bv = *(const bf16x8*)&sB[cur][ct * 512 + q * 128 + r * 8];
            acc[0][ct] = __builtin_amdgcn_mfma_f32_16x16x32_bf16(af0, bv, acc[0][ct], 0, 0, 0);
            acc[1][ct] = __builtin_amdgcn_mfma_f32_16x16x32_bf16(af1, bv, acc[1][ct], 0, 0, 0);
        }
        __syncthreads();             // drain: next buf landed; all reads of cur done
    }

    if (STATS) {
        #pragma unroll
        for (int ct = 0; ct < 8; ++ct) {
            int col = ct * 16 + r;
            float bv = bias ? bias[col] : 0.f;
            float s_c = 0.f, q_c = 0.f;
            #pragma unroll
            for (int rt = 0; rt < 2; ++rt) {
                #pragma unroll
                for (int j = 0; j < 4; ++j) {
                    int row = r0 + w * 32 + rt * 16 + q * 4 + j;
                    if (row < M) {
                        float v = acc[rt][ct][j] + bv;
                        outH[(size_t)row * 128 + col] = (bf16)v;
                        s_c += v; q_c += v * v;
                    }
                }
            }
            atomicAdd(&scol[col], s_c);
            atomicAdd(&scol2[col], q_c);
        }
        __syncthreads();
        float* sbase = stats + ((blockIdx.x & (NCOPY - 1)) << 8);
        if (tid < 128) {
            atomicAdd(&sbase[tid], scol[tid]);
            atomicAdd(&sbase[128 + tid], scol2[tid]);
        }
    } else {
        #pragma unroll
        for (int rt = 0; rt < 2; ++rt) {
            #pragma unroll
            for (int ct = 0; ct < 8; ++ct) {
                int col = ct * 16 + r;
                #pragma unroll
                for (int j = 0; j < 4; ++j) {
                    int row = r0 + w * 32 + rt * 16 + q * 4 + j;
                    if (row >= M) continue;
                    if (col < 47)      yl8[(size_t)row * 64 + col] = fp8(acc[rt][ct][j]);
                    else if (col < 94) yrbf[(size_t)row * 48 + (col - 47)] = (bf16)acc[rt][ct][j];
                }
            }
        }
    }
}

// ---- tiny BN prep: collapse NCOPY striped stats, compute scale/shift per col.
//      1 block x 128 threads; 1 KB output scsh[0..128)=scale, [128..256)=shift. ----
__global__ void k_bn_prep(const float* __restrict__ sums, const float* __restrict__ gma,
                          const float* __restrict__ bta, float* __restrict__ scsh, int n) {
    int col = threadIdx.x;               // 128 threads
    float s = 0.f, q = 0.f;
    #pragma unroll
    for (int cpy = 0; cpy < NCOPY; ++cpy) {
        s += sums[(cpy << 8) + col];
        q += sums[(cpy << 8) + 128 + col];
    }
    float invn = 1.0f / (float)n;
    float mu = s * invn;
    float var = q * invn - mu * mu;
    float sc = gma[col] * rsqrtf(var + BN_EPS);
    scsh[col] = sc;
    scsh[128 + col] = bta[col] - mu * sc;
}

// ---- BN apply + ReLU (bf16 h input, precomputed scale/shift table) ----
__global__ void k_bn_apply(const bf16* __restrict__ h, const float* __restrict__ scsh,
                           bf16* __restrict__ out, unsigned char* __restrict__ out8, int n) {
    int g = blockIdx.x * blockDim.x + threadIdx.x;
    int row = g >> 6, c2 = g & 63;
    if (row >= n) return;
    int col = c2 << 1;
    float2 sc = *(const float2*)(scsh + col);
    float2 sh = *(const float2*)(scsh + 128 + col);
    bf16x2 hv = *(const bf16x2*)(h + (size_t)row * 128 + col);
    float r0 = fmaxf((float)hv[0] * sc.x + sh.x, 0.f);
    float r1 = fmaxf((float)hv[1] * sc.y + sh.y, 0.f);
    bf16x2 o; o[0] = (bf16)r0; o[1] = (bf16)r1;
    *(bf16x2*)(out + (size_t)row * 128 + col) = o;
    uchar2 o8; o8.x = fp8(r0).__x; o8.y = fp8(r1).__x;
    *(uchar2*)(out8 + (size_t)row * 128 + col) = o8;
}

// ---- final: gather-mean of yl (fp8, 64B line/edge) + yr + bl2, log_softmax. ----
__global__ void k_final(const unsigned char* __restrict__ yl, const bf16* __restrict__ yr,
                        const int* __restrict__ row_ptr, const int* __restrict__ col_idx,
                        const float* __restrict__ inv_deg, const float* __restrict__ bl2,
                        float* __restrict__ out, int n) {
    int node = blockIdx.x * 4 + (threadIdx.x >> 6);
    int lane = threadIdx.x & 63;
    if (node >= n) return;
    int e0 = row_ptr[node], e1 = row_ptr[node + 1];
    float inv = inv_deg[node];
    const int sub = lane >> 4;               // edge slot within group of 4
    const int c4 = lane & 15;                // feature group: feats 4*c4 .. 4*c4+3
    const uint32_t loff = (uint32_t)(c4 << 2);
    float a0 = 0.f, a1 = 0.f, a2 = 0.f, a3 = 0.f;
    for (int base = e0; base < e1; base += 16) {
        int ee0 = base + sub;
        int ee1 = base + 4 + sub;
        int ee2 = base + 8 + sub;
        int ee3 = base + 12 + sub;
        bool k0 = ee0 < e1, k1 = ee1 < e1, k2 = ee2 < e1, k3 = ee3 < e1;
        int i0 = col_idx[k0 ? ee0 : e0];
        int i1 = col_idx[k1 ? ee1 : e0];
        int i2 = col_idx[k2 ? ee2 : e0];
        int i3 = col_idx[k3 ? ee3 : e0];
        uint32_t u0 = *(const uint32_t*)(yl + (((uint32_t)i0 << 6) + loff));
        uint32_t u1 = *(const uint32_t*)(yl + (((uint32_t)i1 << 6) + loff));
        uint32_t u2 = *(const uint32_t*)(yl + (((uint32_t)i2 << 6) + loff));
        uint32_t u3 = *(const uint32_t*)(yl + (((uint32_t)i3 << 6) + loff));
        u0 = k0 ? u0 : 0u;
        u1 = k1 ? u1 : 0u;
        u2 = k2 ? u2 : 0u;
        u3 = k3 ? u3 : 0u;
        f32x2 p0l = __builtin_amdgcn_cvt_pk_f32_fp8(u0, false);
        f32x2 p0h = __builtin_amdgcn_cvt_pk_f32_fp8(u0, true);
        f32x2 p1l = __builtin_amdgcn_cvt_pk_f32_fp8(u1, false);
        f32x2 p1h = __builtin_amdgcn_cvt_pk_f32_fp8(u1, true);
        f32x2 p2l = __builtin_amdgcn_cvt_pk_f32_fp8(u2, false);
        f32x2 p2h = __builtin_amdgcn_cvt_pk_f32_fp8(u2, true);
        f32x2 p3l = __builtin_amdgcn_cvt_pk_f32_fp8(u3, false);
        f32x2 p3h = __builtin_amdgcn_cvt_pk_f32_fp8(u3, true);
        a0 += (p0l[0] + p1l[0]) + (p2l[0] + p3l[0]);
        a1 += (p0l[1] + p1l[1]) + (p2l[1] + p3l[1]);
        a2 += (p0h[0] + p1h[0]) + (p2h[0] + p3h[0]);
        a3 += (p0h[1] + p1h[1]) + (p2h[1] + p3h[1]);
    }
    // sum the 4 edge subgroups (lanes differing in bits 4,5 share c4)
    a0 += __shfl_xor(a0, 16, 64); a1 += __shfl_xor(a1, 16, 64);
    a2 += __shfl_xor(a2, 16, 64); a3 += __shfl_xor(a3, 16, 64);
    a0 += __shfl_xor(a0, 32, 64); a1 += __shfl_xor(a1, 32, 64);
    a2 += __shfl_xor(a2, 32, 64); a3 += __shfl_xor(a3, 32, 64);
    const int f0 = c4 << 2;
    const bf16* yrp = yr + (size_t)node * 48;
    float v0 = (f0 + 0 < 47) ? a0 * inv + (float)yrp[f0 + 0] + bl2[f0 + 0] : -__builtin_inff();
    float v1 = (f0 + 1 < 47) ? a1 * inv + (float)yrp[f0 + 1] + bl2[f0 + 1] : -__builtin_inff();
    float v2 = (f0 + 2 < 47) ? a2 * inv + (float)yrp[f0 + 2] + bl2[f0 + 2] : -__builtin_inff();
    float v3 = (f0 + 3 < 47) ? a3 * inv + (float)yrp[f0 + 3] + bl2[f0 + 3] : -__builtin_inff();
    float m = fmaxf(fmaxf(v0, v1), fmaxf(v2, v3));
    #pragma unroll
    for (int o = 1; o < 16; o <<= 1) m = fmaxf(m, __shfl_xor(m, o, 64));
    float ex0 = (f0 + 0 < 47) ? __expf(v0 - m) : 0.f;
    float ex1 = (f0 + 1 < 47) ? __expf(v1 - m) : 0.f;
    float ex2 = (f0 + 2 < 47) ? __expf(v2 - m) : 0.f;
    float ex3 = (f0 + 3 < 47) ? __expf(v3 - m) : 0.f;
    float s = (ex0 + ex1) + (ex2 + ex3);
    #pragma unroll
    for (int o = 1; o < 16; o <<= 1) s += __shfl_xor(s, o, 64);
    float ls = __logf(s);
    if (lane < 16) {
        float* op = out + (size_t)node * 47 + f0;
        if (f0 + 0 < 47) op[0] = v0 - m - ls;
        if (f0 + 1 < 47) op[1] = v1 - m - ls;
        if (f0 + 2 < 47) op[2] = v2 - m - ls;
        if (f0 + 3 < 47) op[3] = v3 - m - ls;
    }
}

extern "C" void kernel_launch(void* const* d_in, const int* in_sizes, int n_in,
                              void* d_out, int out_size, void* d_ws, size_t ws_size,
                              hipStream_t stream) {
    const float* x   = (const float*)d_in[0];
    const int*   ei  = (const int*)d_in[1];
    const float* Wl0 = (const float*)d_in[2];
    const float* bl0 = (const float*)d_in[3];
    const float* Wr0 = (const float*)d_in[4];
    const float* g0  = (const float*)d_in[5];
    const float* be0 = (const float*)d_in[6];
    const float* Wl1 = (const float*)d_in[7];
    const float* bl1 = (const float*)d_in[8];
    const float* Wr1 = (const float*)d_in[9];
    const float* g1  = (const float*)d_in[10];
    const float* be1 = (const float*)d_in[11];
    const float* Wl2 = (const float*)d_in[12];
    const float* bl2 = (const float*)d_in[13];
    const float* Wr2 = (const float*)d_in[14];
    float* out = (float*)d_out;

    const int N  = in_sizes[0] / 128;
    const int E  = in_sizes[1] / 2;
    const int NP = ((N + 127) / 128) * 128;
    const int NBKT = (N + BKT_NODES - 1) / BKT_NODES;

    char* p = (char*)d_ws;
    size_t off = 0;
    auto alloc = [&](size_t b) { char* r = p + off; off += (b + 255) & ~(size_t)255; return r; };
    // zero-init region (one memset): bfill, bnsum (2 layers x NCOPY x 256), btot
    int*   bfill   = (int*)alloc(1024 * 4);
    float* bnsum   = (float*)alloc(2 * NCOPY * 256 * 4);
    int*   btot    = (int*)alloc(512 * 4);
    size_t zero_span = off;
    float* scsh    = (float*)alloc(2 * 256 * 4);   // per-layer scale/shift tables
    int*   row_ptr = (int*)alloc((size_t)(N + 1) * 4);
    float* invd    = (float*)alloc((size_t)N * 4);
    int*   col_idx = (int*)alloc((size_t)E * 4);
    uint32_t* pair_buf = (uint32_t*)alloc((size_t)E * 4);
    bf16*  x_bf    = (bf16*)alloc((size_t)NP * 128 * 2);
    bf16*  aggbf   = (bf16*)alloc((size_t)NP * 128 * 2);
    bf16*  hbf     = (bf16*)alloc((size_t)NP * 128 * 2);
    unsigned char* h8 = (unsigned char*)alloc((size_t)NP * 128);
    float* bufF    = (float*)alloc((size_t)NP * 128 * 4 + 256);
    bf16*  Bt0     = (bf16*)alloc(128 * 256 * 2);
    bf16*  Bt1     = (bf16*)alloc(128 * 256 * 2);
    bf16*  Bt2     = (bf16*)alloc(128 * 128 * 2);
    // aliases into bufF (sequentially dead/live): x8 (pre-GEMM0), hraw (bf16 h,
    // GEMM->bn_apply), yl8/yrbf (post-BN1)
    unsigned char* x8 = (unsigned char*)bufF;
    bf16*  hraw = (bf16*)bufF;
    fp8*   yl8  = (fp8*)bufF;
    bf16*  yrbf = (bf16*)((char*)bufF + (size_t)NP * 64);

    hipMemsetAsync(bfill, 0, zero_span, stream);

    int n4 = N * 128 / 4;
    k_setup<<<(n4 + 255) / 256, 256, 0, stream>>>(x, x_bf, x8, n4, ei, btot, E, NBKT,
                                                  Wl0, Wr0, Wl1, Wr1, Wl2, Wr2, Bt0, Bt1, Bt2);
    k_bin<<<(E + TILE_E - 1) / TILE_E, 256, 0, stream>>>(ei, btot, bfill, pair_buf, E, NBKT);
    k_fill2<<<NBKT, 256, 0, stream>>>(pair_buf, btot, row_ptr, invd, col_idx, N, E, NBKT);

    int aggBlocks  = (N + 3) / 4;
    int gemmBlocks = NP / 128;
    int bnBlocks   = (N * 64 + 255) / 256;

    // Layer 0
    k_aggregate<<<aggBlocks, 256, 0, stream>>>(x8, aggbf, row_ptr, col_idx, invd, N);
    k_gemm6<8, true><<<gemmBlocks, 256, 0, stream>>>(aggbf, x_bf, Bt0, bl0, hraw, nullptr, nullptr, bnsum, N);
    k_bn_prep<<<1, 128, 0, stream>>>(bnsum, g0, be0, scsh, N);
    k_bn_apply<<<bnBlocks, 256, 0, stream>>>(hraw, scsh, hbf, h8, N);
    // Layer 1
    k_aggregate<<<aggBlocks, 256, 0, stream>>>(h8, aggbf, row_ptr, col_idx, invd, N);
    k_gemm6<8, true><<<gemmBlocks, 256, 0, stream>>>(aggbf, hbf, Bt1, bl1, hraw, nullptr, nullptr, bnsum + NCOPY * 256, N);
    k_bn_prep<<<1, 128, 0, stream>>>(bnsum + NCOPY * 256, g1, be1, scsh + 256, N);
    k_bn_apply<<<bnBlocks, 256, 0, stream>>>(hraw, scsh + 256, hbf, h8, N);
    // Layer 2: project to yl (fp8, stride 64) / yr (bf16), then gather + log_softmax
    k_gemm6<4, false><<<gemmBlocks, 256, 0, stream>>>(hbf, hbf, Bt2, nullptr, nullptr, yl8, yrbf, nullptr, N);
    k_final<<<aggBlocks, 256, 0, stream>>>((const unsigned char*)yl8, yrbf, row_ptr, col_idx, invd, bl2, out, N);
}

// Round 9
// 492.907 us; speedup vs baseline: 1.3381x; 1.0218x over previous
//
#include <hip/hip_runtime.h>
#include <hip/hip_fp8.h>
#include <stdint.h>

#define AS1 __attribute__((address_space(1)))
#define AS3 __attribute__((address_space(3)))

typedef __bf16 bf16;
typedef __bf16 bf16x2 __attribute__((ext_vector_type(2)));
typedef __bf16 bf16x4v __attribute__((ext_vector_type(4)));
typedef __bf16 bf16x8 __attribute__((ext_vector_type(8)));
typedef float f32x4 __attribute__((ext_vector_type(4)));
typedef float f32x2 __attribute__((ext_vector_type(2)));
typedef __hip_fp8_e4m3 fp8;

#define BN_EPS 1e-5f
#define BKT_SHIFT 8              // 256 nodes per bucket
#define BKT_NODES 256
#define TILE_E 2048              // edges per binning block
#define NCOPY 16                 // striped stats copies (atomic de-contention)

// ---- fused setup: weight cvt+transpose, x fp32 -> bf16 + fp8, bucket count ----
__global__ void k_setup(const float* __restrict__ x, bf16* __restrict__ x_bf,
                        unsigned char* __restrict__ x8, int n4,
                        const int* __restrict__ ei, int* __restrict__ btot, int E, int nbkt,
                        const float* __restrict__ Wl0, const float* __restrict__ Wr0,
                        const float* __restrict__ Wl1, const float* __restrict__ Wr1,
                        const float* __restrict__ Wl2, const float* __restrict__ Wr2,
                        bf16* __restrict__ Bt0, bf16* __restrict__ Bt1, bf16* __restrict__ Bt2) {
    __shared__ int hist[512];
    const int tid = threadIdx.x;
    int g = blockIdx.x * 256 + tid;
    if (g < n4) {
        float4 v = ((const float4*)x)[g];
        bf16x4v o; o[0] = (bf16)v.x; o[1] = (bf16)v.y; o[2] = (bf16)v.z; o[3] = (bf16)v.w;
        ((bf16x4v*)x_bf)[g] = o;
        uchar4 o8;
        o8.x = fp8(v.x).__x; o8.y = fp8(v.y).__x; o8.z = fp8(v.z).__x; o8.w = fp8(v.w).__x;
        ((uchar4*)x8)[g] = o8;
    }
    if (blockIdx.x < 128) {
        int idx = g;                 // 32768 threads: c in [0,128), k in [0,256)
        int c = idx >> 8, k = idx & 255;
        float v0 = (k < 128) ? Wl0[k * 128 + c] : Wr0[(k - 128) * 128 + c];
        Bt0[c * 256 + k] = (bf16)v0;
        float v1 = (k < 128) ? Wl1[k * 128 + c] : Wr1[(k - 128) * 128 + c];
        Bt1[c * 256 + k] = (bf16)v1;
        if (k < 128) {
            float v2 = 0.f;
            if (c < 47)      v2 = Wl2[k * 47 + c];
            else if (c < 94) v2 = Wr2[k * 47 + (c - 47)];
            Bt2[c * 128 + k] = (bf16)v2;
        }
    }
    // bucket histogram for blocks [0, ceil(E/4096))
    int nbinb = (E + 4095) / 4096;
    if (blockIdx.x < nbinb) {
        hist[tid] = 0; hist[tid + 256] = 0;
        __syncthreads();
        const int e0 = blockIdx.x * 4096;
        #pragma unroll
        for (int k = 0; k < 4; ++k) {
            int i4 = (e0 >> 2) + k * 256 + tid;
            if (i4 * 4 + 3 < E) {
                int4 d4 = ((const int4*)(ei + E))[i4];
                atomicAdd(&hist[d4.x >> BKT_SHIFT], 1);
                atomicAdd(&hist[d4.y >> BKT_SHIFT], 1);
                atomicAdd(&hist[d4.z >> BKT_SHIFT], 1);
                atomicAdd(&hist[d4.w >> BKT_SHIFT], 1);
            } else {
                for (int e = i4 * 4; e < min(E, i4 * 4 + 4); ++e)
                    atomicAdd(&hist[ei[E + e] >> BKT_SHIFT], 1);
            }
        }
        __syncthreads();
        for (int b = tid; b < nbkt; b += 256)
            if (hist[b]) atomicAdd(&btot[b], hist[b]);
    }
}

// In-block exclusive scan of btot[0..512) into sb[0..512], sb[512]=total.
__device__ __forceinline__ void scan_btot(const int* __restrict__ btot, int nbkt,
                                          int* sb, int* wsum) {
    const int tid = threadIdx.x, lane = tid & 63, wid = tid >> 6;
    int a = (tid < nbkt) ? btot[tid] : 0;
    int b2 = (tid + 256 < nbkt) ? btot[tid + 256] : 0;
    int ia = a, ib = b2;
    #pragma unroll
    for (int d = 1; d < 64; d <<= 1) {
        int t1 = __shfl_up(ia, d, 64);
        int t2 = __shfl_up(ib, d, 64);
        if (lane >= d) { ia += t1; ib += t2; }
    }
    if (lane == 63) { wsum[wid] = ia; wsum[4 + wid] = ib; }
    __syncthreads();
    if (tid == 0) {
        int c = 0;
        #pragma unroll
        for (int i = 0; i < 8; ++i) { int t = wsum[i]; wsum[i] = c; c += t; }
    }
    __syncthreads();
    sb[tid] = ia - a + wsum[wid];
    sb[tid + 256] = ib - b2 + wsum[4 + wid];
    if (tid == 255) sb[512] = ib + wsum[7];
    __syncthreads();
}

// ---- binning pass: in-block bbase scan -> histogram -> claim -> ranked write ----
__global__ __launch_bounds__(256) void k_bin(const int* __restrict__ ei,
                                             const int* __restrict__ btot,
                                             int* __restrict__ bfill,
                                             uint32_t* __restrict__ pair_buf,
                                             int E, int nbkt) {
    __shared__ int hist[512], gbase[512], hcur[512];
    __shared__ int sb[513], wsum[8];
    const int tid = threadIdx.x;
    const int e0 = blockIdx.x * TILE_E;
    hist[tid] = 0; hist[tid + 256] = 0;
    scan_btot(btot, nbkt, sb, wsum);   // includes syncs; hist zeroed before first sync

    int dreg[TILE_E / 256];
    #pragma unroll
    for (int k = 0; k < TILE_E / 256; ++k) {
        int e = e0 + k * 256 + tid;
        int d = (e < E) ? ei[E + e] : -1;
        dreg[k] = d;
        if (d >= 0) atomicAdd(&hist[d >> BKT_SHIFT], 1);
    }
    __syncthreads();

    for (int b = tid; b < nbkt; b += 256) {
        int h = hist[b];
        int g = (h > 0) ? atomicAdd(&bfill[b], h) : 0;
        gbase[b] = sb[b] + g;
        hcur[b] = 0;
    }
    __syncthreads();

    #pragma unroll
    for (int k = 0; k < TILE_E / 256; ++k) {
        int d = dreg[k];
        if (d >= 0) {
            int e = e0 + k * 256 + tid;
            int s = ei[e];
            int b = d >> BKT_SHIFT;
            int r = atomicAdd(&hcur[b], 1);
            pair_buf[(size_t)gbase[b] + r] =
                ((uint32_t)s << BKT_SHIFT) | (uint32_t)(d & (BKT_NODES - 1));
        }
    }
}

// ---- fill: one block per bucket ----
__global__ __launch_bounds__(256) void k_fill2(const uint32_t* __restrict__ pair_buf,
                                               const int* __restrict__ btot,
                                               int* __restrict__ row_ptr,
                                               float* __restrict__ inv_deg,
                                               int* __restrict__ col_idx,
                                               int n, int E, int nbkt) {
    __shared__ int hist[256], excl[256], hcur[256], wsum4[4];
    __shared__ int sb[513], wsum[8];
    const int b = blockIdx.x;
    const int tid = threadIdx.x, lane = tid & 63, wid = tid >> 6;
    const int n0 = b << BKT_SHIFT;
    hist[tid] = 0; hcur[tid] = 0;
    scan_btot(btot, nbkt, sb, wsum);
    const int s = sb[b], e = sb[b + 1];
    for (int i = s + tid; i < e; i += 256)
        atomicAdd(&hist[pair_buf[i] & (BKT_NODES - 1)], 1);
    __syncthreads();
    int v = hist[tid];
    int incl = v;
    #pragma unroll
    for (int d = 1; d < 64; d <<= 1) {
        int t = __shfl_up(incl, d, 64);
        if (lane >= d) incl += t;
    }
    if (lane == 63) wsum4[wid] = incl;
    __syncthreads();
    if (tid == 0) {
        int c = 0;
        #pragma unroll
        for (int i = 0; i < 4; ++i) { int t = wsum4[i]; wsum4[i] = c; c += t; }
    }
    __syncthreads();
    int ex = incl - v + wsum4[wid];
    excl[tid] = ex;
    int node = n0 + tid;
    if (node < n) {
        row_ptr[node] = s + ex;
        inv_deg[node] = 1.0f / (float)(v > 1 ? v : 1);
    }
    if (b == (int)gridDim.x - 1 && tid == 0) row_ptr[n] = E;
    __syncthreads();
    for (int i = s + tid; i < e; i += 256) {
        uint32_t pk = pair_buf[i];
        int dl = pk & (BKT_NODES - 1);
        int r = atomicAdd(&hcur[dl], 1);
        col_idx[s + excl[dl] + r] = (int)(pk >> BKT_SHIFT);
    }
}

// ---- mean-aggregate from fp8 table (128 B/row): wave per node, lane = 2 feats.
//      32-bit offsets (v_lshl_add_u32 + SADDR loads) — no 64-bit addr chains. ----
__global__ void k_aggregate(const unsigned char* __restrict__ src8, bf16* __restrict__ dst,
                            const int* __restrict__ row_ptr, const int* __restrict__ col_idx,
                            const float* __restrict__ inv_deg, int n) {
    int node = blockIdx.x * 4 + (threadIdx.x >> 6);
    int lane = threadIdx.x & 63;
    if (node >= n) return;
    int e0 = row_ptr[node], e1 = row_ptr[node + 1];
    float inv = inv_deg[node];
    const uint32_t l2 = (uint32_t)(lane << 1);
    float f0 = 0.f, f1 = 0.f;
    int e = e0;
    // align to 4
    for (; e < e1 && (e & 3); ++e) {
        uint32_t u = *(const uint16_t*)(src8 + (((uint32_t)col_idx[e] << 7) + l2));
        f32x2 p = __builtin_amdgcn_cvt_pk_f32_fp8(u, false);
        f0 += p[0]; f1 += p[1];
    }
    for (; e + 7 < e1; e += 8) {
        int4 i0 = *(const int4*)(col_idx + e);
        int4 i1 = *(const int4*)(col_idx + e + 4);
        uint32_t u0 = *(const uint16_t*)(src8 + (((uint32_t)i0.x << 7) + l2));
        uint32_t u1 = *(const uint16_t*)(src8 + (((uint32_t)i0.y << 7) + l2));
        uint32_t u2 = *(const uint16_t*)(src8 + (((uint32_t)i0.z << 7) + l2));
        uint32_t u3 = *(const uint16_t*)(src8 + (((uint32_t)i0.w << 7) + l2));
        uint32_t u4 = *(const uint16_t*)(src8 + (((uint32_t)i1.x << 7) + l2));
        uint32_t u5 = *(const uint16_t*)(src8 + (((uint32_t)i1.y << 7) + l2));
        uint32_t u6 = *(const uint16_t*)(src8 + (((uint32_t)i1.z << 7) + l2));
        uint32_t u7 = *(const uint16_t*)(src8 + (((uint32_t)i1.w << 7) + l2));
        f32x2 p0 = __builtin_amdgcn_cvt_pk_f32_fp8(u0, false);
        f32x2 p1 = __builtin_amdgcn_cvt_pk_f32_fp8(u1, false);
        f32x2 p2 = __builtin_amdgcn_cvt_pk_f32_fp8(u2, false);
        f32x2 p3 = __builtin_amdgcn_cvt_pk_f32_fp8(u3, false);
        f32x2 p4 = __builtin_amdgcn_cvt_pk_f32_fp8(u4, false);
        f32x2 p5 = __builtin_amdgcn_cvt_pk_f32_fp8(u5, false);
        f32x2 p6 = __builtin_amdgcn_cvt_pk_f32_fp8(u6, false);
        f32x2 p7 = __builtin_amdgcn_cvt_pk_f32_fp8(u7, false);
        f0 += ((p0[0] + p1[0]) + (p2[0] + p3[0])) + ((p4[0] + p5[0]) + (p6[0] + p7[0]));
        f1 += ((p0[1] + p1[1]) + (p2[1] + p3[1])) + ((p4[1] + p5[1]) + (p6[1] + p7[1]));
    }
    if (e + 3 < e1) {
        int4 i0 = *(const int4*)(col_idx + e);
        uint32_t u0 = *(const uint16_t*)(src8 + (((uint32_t)i0.x << 7) + l2));
        uint32_t u1 = *(const uint16_t*)(src8 + (((uint32_t)i0.y << 7) + l2));
        uint32_t u2 = *(const uint16_t*)(src8 + (((uint32_t)i0.z << 7) + l2));
        uint32_t u3 = *(const uint16_t*)(src8 + (((uint32_t)i0.w << 7) + l2));
        f32x2 p0 = __builtin_amdgcn_cvt_pk_f32_fp8(u0, false);
        f32x2 p1 = __builtin_amdgcn_cvt_pk_f32_fp8(u1, false);
        f32x2 p2 = __builtin_amdgcn_cvt_pk_f32_fp8(u2, false);
        f32x2 p3 = __builtin_amdgcn_cvt_pk_f32_fp8(u3, false);
        f0 += (p0[0] + p1[0]) + (p2[0] + p3[0]);
        f1 += (p0[1] + p1[1]) + (p2[1] + p3[1]);
        e += 4;
    }
    for (; e < e1; ++e) {
        uint32_t u = *(const uint16_t*)(src8 + (((uint32_t)col_idx[e] << 7) + l2));
        f32x2 p = __builtin_amdgcn_cvt_pk_f32_fp8(u, false);
        f0 += p[0]; f1 += p[1];
    }
    bf16x2 o; o[0] = (bf16)(f0 * inv); o[1] = (bf16)(f1 * inv);
    *(bf16x2*)(dst + (size_t)node * 128 + (lane << 1)) = o;
}

// ---- MFMA GEMM, 2-phase pipeline with bf16 h output + striped stats.
//      NT = number of 16-col output tiles (8 = 128 cols; 6 = 96 cols for the
//      47+47-col layer-2 projection: 25% less MFMA + B-staging). ----
template<int CH, bool STATS, int NT>
__global__ __launch_bounds__(256) void k_gemm6(
    const bf16* __restrict__ A1, const bf16* __restrict__ A2, const bf16* __restrict__ Bt,
    const float* __restrict__ bias, bf16* __restrict__ outH,
    fp8* __restrict__ yl8, bf16* __restrict__ yrbf, float* __restrict__ stats, int M) {
    __shared__ __attribute__((aligned(16))) bf16 sA[2][4096];
    __shared__ __attribute__((aligned(16))) bf16 sB[2][4096];
    __shared__ float scol[128], scol2[128];
    constexpr int LDB = CH * 32;             // Bt leading dim (elements)
    const int tid = threadIdx.x;
    const int w = tid >> 6, l = tid & 63;
    const int q = l >> 4, r = l & 15;
    const int r0 = blockIdx.x * 128;
    if (STATS && tid < 128) { scol[tid] = 0.f; scol2[tid] = 0.f; }

    auto stage = [&](int buf, int c) {
        const bf16* As = (c < 4) ? A1 : A2;
        const int ka = (c & 3) * 32;
        #pragma unroll
        for (int i = 0; i < 2; ++i) {
            const int T = w * 2 + i;
            const bf16* ga = As + (size_t)(r0 + T * 16 + r) * 128 + ka + q * 8;
            __builtin_amdgcn_global_load_lds((AS1 uint32_t*)(uintptr_t)ga,
                (AS3 uint32_t*)(uint32_t)(uintptr_t)(&sA[buf][T * 512]), 16, 0, 0);
            if (T < NT) {
                const bf16* gb = Bt + (T * 16 + r) * LDB + c * 32 + q * 8;
                __builtin_amdgcn_global_load_lds((AS1 uint32_t*)(uintptr_t)gb,
                    (AS3 uint32_t*)(uint32_t)(uintptr_t)(&sB[buf][T * 512]), 16, 0, 0);
            }
        }
    };

    f32x4 acc[2][NT];
    #pragma unroll
    for (int i = 0; i < 2; ++i)
        #pragma unroll
        for (int j = 0; j < NT; ++j) { acc[i][j][0] = 0.f; acc[i][j][1] = 0.f; acc[i][j][2] = 0.f; acc[i][j][3] = 0.f; }

    stage(0, 0);
    __syncthreads();                 // drains vmcnt(0): buf0 fully landed

    #pragma unroll
    for (int c = 0; c < CH; ++c) {
        const int cur = c & 1;
        if (c + 1 < CH) stage(cur ^ 1, c + 1);   // issue next loads; fly under compute
        bf16x8 af0 = *(const bf16x8*)&sA[cur][(w * 2 + 0) * 512 + q * 128 + r * 8];
        bf16x8 af1 = *(const bf16x8*)&sA[cur][(w * 2 + 1) * 512 + q * 128 + r * 8];
        #pragma unroll
        for (int ct = 0; ct < NT; ++ct) {
            bf16x8 bv = *(const bf16x8*)&sB[cur][ct * 512 + q * 128 + r * 8];
            acc[0][ct] = __builtin_amdgcn_mfma_f32_16x16x32_bf16(af0, bv, acc[0][ct], 0, 0, 0);
            acc[1][ct] = __builtin_amdgcn_mfma_f32_16x16x32_bf16(af1, bv, acc[1][ct], 0, 0, 0);
        }
        __syncthreads();             // drain: next buf landed; all reads of cur done
    }

    if (STATS) {
        #pragma unroll
        for (int ct = 0; ct < NT; ++ct) {
            int col = ct * 16 + r;
            float bv = bias ? bias[col] : 0.f;
            float s_c = 0.f, q_c = 0.f;
            #pragma unroll
            for (int rt = 0; rt < 2; ++rt) {
                #pragma unroll
                for (int j = 0; j < 4; ++j) {
                    int row = r0 + w * 32 + rt * 16 + q * 4 + j;
                    if (row < M) {
                        float v = acc[rt][ct][j] + bv;
                        outH[(size_t)row * 128 + col] = (bf16)v;
                        s_c += v; q_c += v * v;
                    }
                }
            }
            atomicAdd(&scol[col], s_c);
            atomicAdd(&scol2[col], q_c);
        }
        __syncthreads();
        float* sbase = stats + ((blockIdx.x & (NCOPY - 1)) << 8);
        if (tid < 128) {
            atomicAdd(&sbase[tid], scol[tid]);
            atomicAdd(&sbase[128 + tid], scol2[tid]);
        }
    } else {
        #pragma unroll
        for (int rt = 0; rt < 2; ++rt) {
            #pragma unroll
            for (int ct = 0; ct < NT; ++ct) {
                int col = ct * 16 + r;
                #pragma unroll
                for (int j = 0; j < 4; ++j) {
                    int row = r0 + w * 32 + rt * 16 + q * 4 + j;
                    if (row >= M) continue;
                    if (col < 47)      yl8[(size_t)row * 64 + col] = fp8(acc[rt][ct][j]);
                    else if (col < 94) yrbf[(size_t)row * 48 + (col - 47)] = (bf16)acc[rt][ct][j];
                }
            }
        }
    }
}

// ---- tiny BN prep: collapse NCOPY striped stats, compute scale/shift per col. ----
__global__ void k_bn_prep(const float* __restrict__ sums, const float* __restrict__ gma,
                          const float* __restrict__ bta, float* __restrict__ scsh, int n) {
    int col = threadIdx.x;               // 128 threads
    float s = 0.f, q = 0.f;
    #pragma unroll
    for (int cpy = 0; cpy < NCOPY; ++cpy) {
        s += sums[(cpy << 8) + col];
        q += sums[(cpy << 8) + 128 + col];
    }
    float invn = 1.0f / (float)n;
    float mu = s * invn;
    float var = q * invn - mu * mu;
    float sc = gma[col] * rsqrtf(var + BN_EPS);
    scsh[col] = sc;
    scsh[128 + col] = bta[col] - mu * sc;
}

// ---- BN apply + ReLU (bf16 h input, precomputed scale/shift table) ----
__global__ void k_bn_apply(const bf16* __restrict__ h, const float* __restrict__ scsh,
                           bf16* __restrict__ out, unsigned char* __restrict__ out8, int n) {
    int g = blockIdx.x * blockDim.x + threadIdx.x;
    int row = g >> 6, c2 = g & 63;
    if (row >= n) return;
    int col = c2 << 1;
    float2 sc = *(const float2*)(scsh + col);
    float2 sh = *(const float2*)(scsh + 128 + col);
    bf16x2 hv = *(const bf16x2*)(h + (size_t)row * 128 + col);
    float r0 = fmaxf((float)hv[0] * sc.x + sh.x, 0.f);
    float r1 = fmaxf((float)hv[1] * sc.y + sh.y, 0.f);
    bf16x2 o; o[0] = (bf16)r0; o[1] = (bf16)r1;
    *(bf16x2*)(out + (size_t)row * 128 + col) = o;
    uchar2 o8; o8.x = fp8(r0).__x; o8.y = fp8(r1).__x;
    *(uchar2*)(out8 + (size_t)row * 128 + col) = o8;
}

// ---- final: gather-mean of yl (fp8, 64B line/edge) + yr + bl2, log_softmax.
//      Unmasked full-batch main loop (no cmp/cndmask for deg>=16 work) + one
//      masked tail batch. yr read vectorized (one 8B bf16x4 load). ----
__global__ void k_final(const unsigned char* __restrict__ yl, const bf16* __restrict__ yr,
                        const int* __restrict__ row_ptr, const int* __restrict__ col_idx,
                        const float* __restrict__ inv_deg, const float* __restrict__ bl2,
                        float* __restrict__ out, int n) {
    int node = blockIdx.x * 4 + (threadIdx.x >> 6);
    int lane = threadIdx.x & 63;
    if (node >= n) return;
    int e0 = row_ptr[node], e1 = row_ptr[node + 1];
    float inv = inv_deg[node];
    const int sub = lane >> 4;               // edge slot within group of 4
    const int c4 = lane & 15;                // feature group: feats 4*c4 .. 4*c4+3
    const uint32_t loff = (uint32_t)(c4 << 2);
    float a0 = 0.f, a1 = 0.f, a2 = 0.f, a3 = 0.f;
    int base = e0;
    // full batches: no masking at all
    for (; base + 16 <= e1; base += 16) {
        int i0 = col_idx[base + sub];
        int i1 = col_idx[base + 4 + sub];
        int i2 = col_idx[base + 8 + sub];
        int i3 = col_idx[base + 12 + sub];
        uint32_t u0 = *(const uint32_t*)(yl + (((uint32_t)i0 << 6) + loff));
        uint32_t u1 = *(const uint32_t*)(yl + (((uint32_t)i1 << 6) + loff));
        uint32_t u2 = *(const uint32_t*)(yl + (((uint32_t)i2 << 6) + loff));
        uint32_t u3 = *(const uint32_t*)(yl + (((uint32_t)i3 << 6) + loff));
        f32x2 p0l = __builtin_amdgcn_cvt_pk_f32_fp8(u0, false);
        f32x2 p0h = __builtin_amdgcn_cvt_pk_f32_fp8(u0, true);
        f32x2 p1l = __builtin_amdgcn_cvt_pk_f32_fp8(u1, false);
        f32x2 p1h = __builtin_amdgcn_cvt_pk_f32_fp8(u1, true);
        f32x2 p2l = __builtin_amdgcn_cvt_pk_f32_fp8(u2, false);
        f32x2 p2h = __builtin_amdgcn_cvt_pk_f32_fp8(u2, true);
        f32x2 p3l = __builtin_amdgcn_cvt_pk_f32_fp8(u3, false);
        f32x2 p3h = __builtin_amdgcn_cvt_pk_f32_fp8(u3, true);
        a0 += (p0l[0] + p1l[0]) + (p2l[0] + p3l[0]);
        a1 += (p0l[1] + p1l[1]) + (p2l[1] + p3l[1]);
        a2 += (p0h[0] + p1h[0]) + (p2h[0] + p3h[0]);
        a3 += (p0h[1] + p1h[1]) + (p2h[1] + p3h[1]);
    }
    // single masked tail batch (< 16 edges)
    if (base < e1) {
        int ee0 = base + sub;
        int ee1 = base + 4 + sub;
        int ee2 = base + 8 + sub;
        int ee3 = base + 12 + sub;
        bool k0 = ee0 < e1, k1 = ee1 < e1, k2 = ee2 < e1, k3 = ee3 < e1;
        int i0 = col_idx[k0 ? ee0 : e0];
        int i1 = col_idx[k1 ? ee1 : e0];
        int i2 = col_idx[k2 ? ee2 : e0];
        int i3 = col_idx[k3 ? ee3 : e0];
        uint32_t u0 = *(const uint32_t*)(yl + (((uint32_t)i0 << 6) + loff));
        uint32_t u1 = *(const uint32_t*)(yl + (((uint32_t)i1 << 6) + loff));
        uint32_t u2 = *(const uint32_t*)(yl + (((uint32_t)i2 << 6) + loff));
        uint32_t u3 = *(const uint32_t*)(yl + (((uint32_t)i3 << 6) + loff));
        u0 = k0 ? u0 : 0u;
        u1 = k1 ? u1 : 0u;
        u2 = k2 ? u2 : 0u;
        u3 = k3 ? u3 : 0u;
        f32x2 p0l = __builtin_amdgcn_cvt_pk_f32_fp8(u0, false);
        f32x2 p0h = __builtin_amdgcn_cvt_pk_f32_fp8(u0, true);
        f32x2 p1l = __builtin_amdgcn_cvt_pk_f32_fp8(u1, false);
        f32x2 p1h = __builtin_amdgcn_cvt_pk_f32_fp8(u1, true);
        f32x2 p2l = __builtin_amdgcn_cvt_pk_f32_fp8(u2, false);
        f32x2 p2h = __builtin_amdgcn_cvt_pk_f32_fp8(u2, true);
        f32x2 p3l = __builtin_amdgcn_cvt_pk_f32_fp8(u3, false);
        f32x2 p3h = __builtin_amdgcn_cvt_pk_f32_fp8(u3, true);
        a0 += (p0l[0] + p1l[0]) + (p2l[0] + p3l[0]);
        a1 += (p0l[1] + p1l[1]) + (p2l[1] + p3l[1]);
        a2 += (p0h[0] + p1h[0]) + (p2h[0] + p3h[0]);
        a3 += (p0h[1] + p1h[1]) + (p2h[1] + p3h[1]);
    }
    // sum the 4 edge subgroups (lanes differing in bits 4,5 share c4)
    a0 += __shfl_xor(a0, 16, 64); a1 += __shfl_xor(a1, 16, 64);
    a2 += __shfl_xor(a2, 16, 64); a3 += __shfl_xor(a3, 16, 64);
    a0 += __shfl_xor(a0, 32, 64); a1 += __shfl_xor(a1, 32, 64);
    a2 += __shfl_xor(a2, 32, 64); a3 += __shfl_xor(a3, 32, 64);
    const int f0 = c4 << 2;
    // yr: one 8-byte load (node*96 + 8*c4 is 8B-aligned)
    bf16x4v yv4 = *(const bf16x4v*)(yr + (size_t)node * 48 + f0);
    float v0 = (f0 + 0 < 47) ? fmaf(a0, inv, (float)yv4[0] + bl2[f0 + 0]) : -__builtin_inff();
    float v1 = (f0 + 1 < 47) ? fmaf(a1, inv, (float)yv4[1] + bl2[f0 + 1]) : -__builtin_inff();
    float v2 = (f0 + 2 < 47) ? fmaf(a2, inv, (float)yv4[2] + bl2[f0 + 2]) : -__builtin_inff();
    float v3 = (f0 + 3 < 47) ? fmaf(a3, inv, (float)yv4[3] + bl2[f0 + 3]) : -__builtin_inff();
    float m = fmaxf(fmaxf(v0, v1), fmaxf(v2, v3));
    #pragma unroll
    for (int o = 1; o < 16; o <<= 1) m = fmaxf(m, __shfl_xor(m, o, 64));
    float ex0 = (f0 + 0 < 47) ? __expf(v0 - m) : 0.f;
    float ex1 = (f0 + 1 < 47) ? __expf(v1 - m) : 0.f;
    float ex2 = (f0 + 2 < 47) ? __expf(v2 - m) : 0.f;
    float ex3 = (f0 + 3 < 47) ? __expf(v3 - m) : 0.f;
    float s = (ex0 + ex1) + (ex2 + ex3);
    #pragma unroll
    for (int o = 1; o < 16; o <<= 1) s += __shfl_xor(s, o, 64);
    float ls = __logf(s);
    if (lane < 16) {
        float* op = out + (size_t)node * 47 + f0;
        if (f0 + 0 < 47) op[0] = v0 - m - ls;
        if (f0 + 1 < 47) op[1] = v1 - m - ls;
        if (f0 + 2 < 47) op[2] = v2 - m - ls;
        if (f0 + 3 < 47) op[3] = v3 - m - ls;
    }
}

extern "C" void kernel_launch(void* const* d_in, const int* in_sizes, int n_in,
                              void* d_out, int out_size, void* d_ws, size_t ws_size,
                              hipStream_t stream) {
    const float* x   = (const float*)d_in[0];
    const int*   ei  = (const int*)d_in[1];
    const float* Wl0 = (const float*)d_in[2];
    const float* bl0 = (const float*)d_in[3];
    const float* Wr0 = (const float*)d_in[4];
    const float* g0  = (const float*)d_in[5];
    const float* be0 = (const float*)d_in[6];
    const float* Wl1 = (const float*)d_in[7];
    const float* bl1 = (const float*)d_in[8];
    const float* Wr1 = (const float*)d_in[9];
    const float* g1  = (const float*)d_in[10];
    const float* be1 = (const float*)d_in[11];
    const float* Wl2 = (const float*)d_in[12];
    const float* bl2 = (const float*)d_in[13];
    const float* Wr2 = (const float*)d_in[14];
    float* out = (float*)d_out;

    const int N  = in_sizes[0] / 128;
    const int E  = in_sizes[1] / 2;
    const int NP = ((N + 127) / 128) * 128;
    const int NBKT = (N + BKT_NODES - 1) / BKT_NODES;

    char* p = (char*)d_ws;
    size_t off = 0;
    auto alloc = [&](size_t b) { char* r = p + off; off += (b + 255) & ~(size_t)255; return r; };
    // zero-init region (one memset): bfill, bnsum (2 layers x NCOPY x 256), btot
    int*   bfill   = (int*)alloc(1024 * 4);
    float* bnsum   = (float*)alloc(2 * NCOPY * 256 * 4);
    int*   btot    = (int*)alloc(512 * 4);
    size_t zero_span = off;
    float* scsh    = (float*)alloc(2 * 256 * 4);   // per-layer scale/shift tables
    int*   row_ptr = (int*)alloc((size_t)(N + 1) * 4);
    float* invd    = (float*)alloc((size_t)N * 4);
    int*   col_idx = (int*)alloc((size_t)E * 4);
    uint32_t* pair_buf = (uint32_t*)alloc((size_t)E * 4);
    bf16*  x_bf    = (bf16*)alloc((size_t)NP * 128 * 2);
    bf16*  aggbf   = (bf16*)alloc((size_t)NP * 128 * 2);
    bf16*  hbf     = (bf16*)alloc((size_t)NP * 128 * 2);
    unsigned char* h8 = (unsigned char*)alloc((size_t)NP * 128);
    float* bufF    = (float*)alloc((size_t)NP * 128 * 4 + 256);
    bf16*  Bt0     = (bf16*)alloc(128 * 256 * 2);
    bf16*  Bt1     = (bf16*)alloc(128 * 256 * 2);
    bf16*  Bt2     = (bf16*)alloc(128 * 128 * 2);
    // aliases into bufF (sequentially dead/live): x8 (pre-GEMM0), hraw (bf16 h,
    // GEMM->bn_apply), yl8/yrbf (post-BN1)
    unsigned char* x8 = (unsigned char*)bufF;
    bf16*  hraw = (bf16*)bufF;
    fp8*   yl8  = (fp8*)bufF;
    bf16*  yrbf = (bf16*)((char*)bufF + (size_t)NP * 64);

    hipMemsetAsync(bfill, 0, zero_span, stream);

    int n4 = N * 128 / 4;
    k_setup<<<(n4 + 255) / 256, 256, 0, stream>>>(x, x_bf, x8, n4, ei, btot, E, NBKT,
                                                  Wl0, Wr0, Wl1, Wr1, Wl2, Wr2, Bt0, Bt1, Bt2);
    k_bin<<<(E + TILE_E - 1) / TILE_E, 256, 0, stream>>>(ei, btot, bfill, pair_buf, E, NBKT);
    k_fill2<<<NBKT, 256, 0, stream>>>(pair_buf, btot, row_ptr, invd, col_idx, N, E, NBKT);

    int aggBlocks  = (N + 3) / 4;
    int gemmBlocks = NP / 128;
    int bnBlocks   = (N * 64 + 255) / 256;

    // Layer 0
    k_aggregate<<<aggBlocks, 256, 0, stream>>>(x8, aggbf, row_ptr, col_idx, invd, N);
    k_gemm6<8, true, 8><<<gemmBlocks, 256, 0, stream>>>(aggbf, x_bf, Bt0, bl0, hraw, nullptr, nullptr, bnsum, N);
    k_bn_prep<<<1, 128, 0, stream>>>(bnsum, g0, be0, scsh, N);
    k_bn_apply<<<bnBlocks, 256, 0, stream>>>(hraw, scsh, hbf, h8, N);
    // Layer 1
    k_aggregate<<<aggBlocks, 256, 0, stream>>>(h8, aggbf, row_ptr, col_idx, invd, N);
    k_gemm6<8, true, 8><<<gemmBlocks, 256, 0, stream>>>(aggbf, hbf, Bt1, bl1, hraw, nullptr, nullptr, bnsum + NCOPY * 256, N);
    k_bn_prep<<<1, 128, 0, stream>>>(bnsum + NCOPY * 256, g1, be1, scsh + 256, N);
    k_bn_apply<<<bnBlocks, 256, 0, stream>>>(hraw, scsh + 256, hbf, h8, N);
    // Layer 2: project to yl (fp8, stride 64) / yr (bf16), then gather + log_softmax
    k_gemm6<4, false, 6><<<gemmBlocks, 256, 0, stream>>>(hbf, hbf, Bt2, nullptr, nullptr, yl8, yrbf, nullptr, N);
    k_final<<<aggBlocks, 256, 0, stream>>>((const unsigned char*)yl8, yrbf, row_ptr, col_idx, invd, bl2, out, N);
}

// Round 10
// 453.288 us; speedup vs baseline: 1.4550x; 1.0874x over previous
//
#include <hip/hip_runtime.h>
#include <hip/hip_fp8.h>
#include <stdint.h>

#define AS1 __attribute__((address_space(1)))
#define AS3 __attribute__((address_space(3)))

typedef __bf16 bf16;
typedef __bf16 bf16x2 __attribute__((ext_vector_type(2)));
typedef __bf16 bf16x4v __attribute__((ext_vector_type(4)));
typedef __bf16 bf16x8 __attribute__((ext_vector_type(8)));
typedef float f32x4 __attribute__((ext_vector_type(4)));
typedef float f32x2 __attribute__((ext_vector_type(2)));
typedef __hip_fp8_e4m3 fp8;

#define BN_EPS 1e-5f
#define BKT_SHIFT 8              // 256 nodes per bucket
#define BKT_NODES 256
#define TILE_E 2048              // edges per binning block
#define NCOPY 16                 // striped stats copies (atomic de-contention)

// ---- fused setup: weight cvt+transpose, x fp32 -> bf16 + fp8, bucket count ----
__global__ void k_setup(const float* __restrict__ x, bf16* __restrict__ x_bf,
                        unsigned char* __restrict__ x8, int n4,
                        const int* __restrict__ ei, int* __restrict__ btot, int E, int nbkt,
                        const float* __restrict__ Wl0, const float* __restrict__ Wr0,
                        const float* __restrict__ Wl1, const float* __restrict__ Wr1,
                        const float* __restrict__ Wl2, const float* __restrict__ Wr2,
                        bf16* __restrict__ Bt0, bf16* __restrict__ Bt1, bf16* __restrict__ Bt2) {
    __shared__ int hist[512];
    const int tid = threadIdx.x;
    int g = blockIdx.x * 256 + tid;
    if (g < n4) {
        float4 v = ((const float4*)x)[g];
        bf16x4v o; o[0] = (bf16)v.x; o[1] = (bf16)v.y; o[2] = (bf16)v.z; o[3] = (bf16)v.w;
        ((bf16x4v*)x_bf)[g] = o;
        uchar4 o8;
        o8.x = fp8(v.x).__x; o8.y = fp8(v.y).__x; o8.z = fp8(v.z).__x; o8.w = fp8(v.w).__x;
        ((uchar4*)x8)[g] = o8;
    }
    if (blockIdx.x < 128) {
        int idx = g;                 // 32768 threads: c in [0,128), k in [0,256)
        int c = idx >> 8, k = idx & 255;
        float v0 = (k < 128) ? Wl0[k * 128 + c] : Wr0[(k - 128) * 128 + c];
        Bt0[c * 256 + k] = (bf16)v0;
        float v1 = (k < 128) ? Wl1[k * 128 + c] : Wr1[(k - 128) * 128 + c];
        Bt1[c * 256 + k] = (bf16)v1;
        if (k < 128) {
            float v2 = 0.f;
            if (c < 47)      v2 = Wl2[k * 47 + c];
            else if (c < 94) v2 = Wr2[k * 47 + (c - 47)];
            Bt2[c * 128 + k] = (bf16)v2;
        }
    }
    // bucket histogram for blocks [0, ceil(E/4096))
    int nbinb = (E + 4095) / 4096;
    if (blockIdx.x < nbinb) {
        hist[tid] = 0; hist[tid + 256] = 0;
        __syncthreads();
        const int e0 = blockIdx.x * 4096;
        #pragma unroll
        for (int k = 0; k < 4; ++k) {
            int i4 = (e0 >> 2) + k * 256 + tid;
            if (i4 * 4 + 3 < E) {
                int4 d4 = ((const int4*)(ei + E))[i4];
                atomicAdd(&hist[d4.x >> BKT_SHIFT], 1);
                atomicAdd(&hist[d4.y >> BKT_SHIFT], 1);
                atomicAdd(&hist[d4.z >> BKT_SHIFT], 1);
                atomicAdd(&hist[d4.w >> BKT_SHIFT], 1);
            } else {
                for (int e = i4 * 4; e < min(E, i4 * 4 + 4); ++e)
                    atomicAdd(&hist[ei[E + e] >> BKT_SHIFT], 1);
            }
        }
        __syncthreads();
        for (int b = tid; b < nbkt; b += 256)
            if (hist[b]) atomicAdd(&btot[b], hist[b]);
    }
}

// In-block exclusive scan of btot[0..512) into sb[0..512], sb[512]=total.
__device__ __forceinline__ void scan_btot(const int* __restrict__ btot, int nbkt,
                                          int* sb, int* wsum) {
    const int tid = threadIdx.x, lane = tid & 63, wid = tid >> 6;
    int a = (tid < nbkt) ? btot[tid] : 0;
    int b2 = (tid + 256 < nbkt) ? btot[tid + 256] : 0;
    int ia = a, ib = b2;
    #pragma unroll
    for (int d = 1; d < 64; d <<= 1) {
        int t1 = __shfl_up(ia, d, 64);
        int t2 = __shfl_up(ib, d, 64);
        if (lane >= d) { ia += t1; ib += t2; }
    }
    if (lane == 63) { wsum[wid] = ia; wsum[4 + wid] = ib; }
    __syncthreads();
    if (tid == 0) {
        int c = 0;
        #pragma unroll
        for (int i = 0; i < 8; ++i) { int t = wsum[i]; wsum[i] = c; c += t; }
    }
    __syncthreads();
    sb[tid] = ia - a + wsum[wid];
    sb[tid + 256] = ib - b2 + wsum[4 + wid];
    if (tid == 255) sb[512] = ib + wsum[7];
    __syncthreads();
}

// ---- binning pass: in-block bbase scan -> histogram -> claim -> ranked write ----
__global__ __launch_bounds__(256) void k_bin(const int* __restrict__ ei,
                                             const int* __restrict__ btot,
                                             int* __restrict__ bfill,
                                             uint32_t* __restrict__ pair_buf,
                                             int E, int nbkt) {
    __shared__ int hist[512], gbase[512], hcur[512];
    __shared__ int sb[513], wsum[8];
    const int tid = threadIdx.x;
    const int e0 = blockIdx.x * TILE_E;
    hist[tid] = 0; hist[tid + 256] = 0;
    scan_btot(btot, nbkt, sb, wsum);   // includes syncs; hist zeroed before first sync

    int dreg[TILE_E / 256];
    #pragma unroll
    for (int k = 0; k < TILE_E / 256; ++k) {
        int e = e0 + k * 256 + tid;
        int d = (e < E) ? ei[E + e] : -1;
        dreg[k] = d;
        if (d >= 0) atomicAdd(&hist[d >> BKT_SHIFT], 1);
    }
    __syncthreads();

    for (int b = tid; b < nbkt; b += 256) {
        int h = hist[b];
        int g = (h > 0) ? atomicAdd(&bfill[b], h) : 0;
        gbase[b] = sb[b] + g;
        hcur[b] = 0;
    }
    __syncthreads();

    #pragma unroll
    for (int k = 0; k < TILE_E / 256; ++k) {
        int d = dreg[k];
        if (d >= 0) {
            int e = e0 + k * 256 + tid;
            int s = ei[e];
            int b = d >> BKT_SHIFT;
            int r = atomicAdd(&hcur[b], 1);
            pair_buf[(size_t)gbase[b] + r] =
                ((uint32_t)s << BKT_SHIFT) | (uint32_t)(d & (BKT_NODES - 1));
        }
    }
}

// ---- fill: one block per bucket ----
__global__ __launch_bounds__(256) void k_fill2(const uint32_t* __restrict__ pair_buf,
                                               const int* __restrict__ btot,
                                               int* __restrict__ row_ptr,
                                               float* __restrict__ inv_deg,
                                               int* __restrict__ col_idx,
                                               int n, int E, int nbkt) {
    __shared__ int hist[256], excl[256], hcur[256], wsum4[4];
    __shared__ int sb[513], wsum[8];
    const int b = blockIdx.x;
    const int tid = threadIdx.x, lane = tid & 63, wid = tid >> 6;
    const int n0 = b << BKT_SHIFT;
    hist[tid] = 0; hcur[tid] = 0;
    scan_btot(btot, nbkt, sb, wsum);
    const int s = sb[b], e = sb[b + 1];
    for (int i = s + tid; i < e; i += 256)
        atomicAdd(&hist[pair_buf[i] & (BKT_NODES - 1)], 1);
    __syncthreads();
    int v = hist[tid];
    int incl = v;
    #pragma unroll
    for (int d = 1; d < 64; d <<= 1) {
        int t = __shfl_up(incl, d, 64);
        if (lane >= d) incl += t;
    }
    if (lane == 63) wsum4[wid] = incl;
    __syncthreads();
    if (tid == 0) {
        int c = 0;
        #pragma unroll
        for (int i = 0; i < 4; ++i) { int t = wsum4[i]; wsum4[i] = c; c += t; }
    }
    __syncthreads();
    int ex = incl - v + wsum4[wid];
    excl[tid] = ex;
    int node = n0 + tid;
    if (node < n) {
        row_ptr[node] = s + ex;
        inv_deg[node] = 1.0f / (float)(v > 1 ? v : 1);
    }
    if (b == (int)gridDim.x - 1 && tid == 0) row_ptr[n] = E;
    __syncthreads();
    for (int i = s + tid; i < e; i += 256) {
        uint32_t pk = pair_buf[i];
        int dl = pk & (BKT_NODES - 1);
        int r = atomicAdd(&hcur[dl], 1);
        col_idx[s + excl[dl] + r] = (int)(pk >> BKT_SHIFT);
    }
}

// ---- mean-aggregate from fp8 table (128 B/row).
//      TWO nodes per wave: half = 32 lanes, lane = 4 feats (uint32 gather
//      covers the whole 128-B row with one half). Every gather instruction
//      serves one edge of node A AND one edge of node B -> VMEM issue per
//      edge halved vs 1-node/wave uint16 version. 16-edge batches (16
//      independent gathers in flight). Accumulation is lane-local.
//      Tail: index-clamped masked batch (overread of col_idx stays inside
//      workspace padding; clamped idx 0 keeps gathers in-bounds). ----
#define ACC4(u) { f32x2 pl_ = __builtin_amdgcn_cvt_pk_f32_fp8(u, false); \
                  f32x2 ph_ = __builtin_amdgcn_cvt_pk_f32_fp8(u, true);  \
                  a0 += pl_[0]; a1 += pl_[1]; a2 += ph_[0]; a3 += ph_[1]; }
__global__ void k_aggregate(const unsigned char* __restrict__ src8, bf16* __restrict__ dst,
                            const int* __restrict__ row_ptr, const int* __restrict__ col_idx,
                            const float* __restrict__ inv_deg, int n) {
    const int lane = threadIdx.x & 63;
    const int half = lane >> 5;
    const int sl = lane & 31;
    const int node = blockIdx.x * 8 + ((threadIdx.x >> 6) << 1) + half;
    const bool valid = node < n;
    const int nn = valid ? node : 0;
    const int re0 = row_ptr[nn];
    const int re1 = valid ? row_ptr[nn + 1] : re0;
    const float inv = inv_deg[nn];
    const uint32_t l4 = (uint32_t)(sl << 2);
    float a0 = 0.f, a1 = 0.f, a2 = 0.f, a3 = 0.f;
    int e = re0;
    // align to 4 for int4 idx loads (<=3 scalar edges)
    for (; e < re1 && (e & 3); ++e) {
        uint32_t u = *(const uint32_t*)(src8 + (((uint32_t)col_idx[e] << 7) + l4));
        ACC4(u)
    }
    // full 16-edge batches: 4 idx loads + 16 independent gathers in flight
    for (; e + 16 <= re1; e += 16) {
        int4 i0 = *(const int4*)(col_idx + e);
        int4 i1 = *(const int4*)(col_idx + e + 4);
        int4 i2 = *(const int4*)(col_idx + e + 8);
        int4 i3 = *(const int4*)(col_idx + e + 12);
        uint32_t u0  = *(const uint32_t*)(src8 + (((uint32_t)i0.x << 7) + l4));
        uint32_t u1  = *(const uint32_t*)(src8 + (((uint32_t)i0.y << 7) + l4));
        uint32_t u2  = *(const uint32_t*)(src8 + (((uint32_t)i0.z << 7) + l4));
        uint32_t u3  = *(const uint32_t*)(src8 + (((uint32_t)i0.w << 7) + l4));
        uint32_t u4  = *(const uint32_t*)(src8 + (((uint32_t)i1.x << 7) + l4));
        uint32_t u5  = *(const uint32_t*)(src8 + (((uint32_t)i1.y << 7) + l4));
        uint32_t u6  = *(const uint32_t*)(src8 + (((uint32_t)i1.z << 7) + l4));
        uint32_t u7  = *(const uint32_t*)(src8 + (((uint32_t)i1.w << 7) + l4));
        uint32_t u8  = *(const uint32_t*)(src8 + (((uint32_t)i2.x << 7) + l4));
        uint32_t u9  = *(const uint32_t*)(src8 + (((uint32_t)i2.y << 7) + l4));
        uint32_t u10 = *(const uint32_t*)(src8 + (((uint32_t)i2.z << 7) + l4));
        uint32_t u11 = *(const uint32_t*)(src8 + (((uint32_t)i2.w << 7) + l4));
        uint32_t u12 = *(const uint32_t*)(src8 + (((uint32_t)i3.x << 7) + l4));
        uint32_t u13 = *(const uint32_t*)(src8 + (((uint32_t)i3.y << 7) + l4));
        uint32_t u14 = *(const uint32_t*)(src8 + (((uint32_t)i3.z << 7) + l4));
        uint32_t u15 = *(const uint32_t*)(src8 + (((uint32_t)i3.w << 7) + l4));
        ACC4(u0) ACC4(u1) ACC4(u2) ACC4(u3) ACC4(u4) ACC4(u5) ACC4(u6) ACC4(u7)
        ACC4(u8) ACC4(u9) ACC4(u10) ACC4(u11) ACC4(u12) ACC4(u13) ACC4(u14) ACC4(u15)
    }
    // masked tail (<16 edges), aligned idx loads with clamped indices
    if (e < re1) {
        int4 i0 = *(const int4*)(col_idx + e);
        int4 i1 = *(const int4*)(col_idx + e + 4);
        int4 i2 = *(const int4*)(col_idx + e + 8);
        int4 i3 = *(const int4*)(col_idx + e + 12);
        bool k0  = e + 0  < re1, k1  = e + 1  < re1, k2  = e + 2  < re1, k3  = e + 3  < re1;
        bool k4  = e + 4  < re1, k5  = e + 5  < re1, k6  = e + 6  < re1, k7  = e + 7  < re1;
        bool k8  = e + 8  < re1, k9  = e + 9  < re1, k10 = e + 10 < re1, k11 = e + 11 < re1;
        bool k12 = e + 12 < re1, k13 = e + 13 < re1, k14 = e + 14 < re1, k15 = e + 15 < re1;
        int r0  = k0  ? i0.x : 0, r1  = k1  ? i0.y : 0, r2  = k2  ? i0.z : 0, r3  = k3  ? i0.w : 0;
        int r4  = k4  ? i1.x : 0, r5  = k5  ? i1.y : 0, r6  = k6  ? i1.z : 0, r7  = k7  ? i1.w : 0;
        int r8  = k8  ? i2.x : 0, r9  = k9  ? i2.y : 0, r10 = k10 ? i2.z : 0, r11 = k11 ? i2.w : 0;
        int r12 = k12 ? i3.x : 0, r13 = k13 ? i3.y : 0, r14 = k14 ? i3.z : 0, r15 = k15 ? i3.w : 0;
        uint32_t u0  = *(const uint32_t*)(src8 + (((uint32_t)r0  << 7) + l4));
        uint32_t u1  = *(const uint32_t*)(src8 + (((uint32_t)r1  << 7) + l4));
        uint32_t u2  = *(const uint32_t*)(src8 + (((uint32_t)r2  << 7) + l4));
        uint32_t u3  = *(const uint32_t*)(src8 + (((uint32_t)r3  << 7) + l4));
        uint32_t u4  = *(const uint32_t*)(src8 + (((uint32_t)r4  << 7) + l4));
        uint32_t u5  = *(const uint32_t*)(src8 + (((uint32_t)r5  << 7) + l4));
        uint32_t u6  = *(const uint32_t*)(src8 + (((uint32_t)r6  << 7) + l4));
        uint32_t u7  = *(const uint32_t*)(src8 + (((uint32_t)r7  << 7) + l4));
        uint32_t u8  = *(const uint32_t*)(src8 + (((uint32_t)r8  << 7) + l4));
        uint32_t u9  = *(const uint32_t*)(src8 + (((uint32_t)r9  << 7) + l4));
        uint32_t u10 = *(const uint32_t*)(src8 + (((uint32_t)r10 << 7) + l4));
        uint32_t u11 = *(const uint32_t*)(src8 + (((uint32_t)r11 << 7) + l4));
        uint32_t u12 = *(const uint32_t*)(src8 + (((uint32_t)r12 << 7) + l4));
        uint32_t u13 = *(const uint32_t*)(src8 + (((uint32_t)r13 << 7) + l4));
        uint32_t u14 = *(const uint32_t*)(src8 + (((uint32_t)r14 << 7) + l4));
        uint32_t u15 = *(const uint32_t*)(src8 + (((uint32_t)r15 << 7) + l4));
        u0  = k0  ? u0  : 0u; u1  = k1  ? u1  : 0u; u2  = k2  ? u2  : 0u; u3  = k3  ? u3  : 0u;
        u4  = k4  ? u4  : 0u; u5  = k5  ? u5  : 0u; u6  = k6  ? u6  : 0u; u7  = k7  ? u7  : 0u;
        u8  = k8  ? u8  : 0u; u9  = k9  ? u9  : 0u; u10 = k10 ? u10 : 0u; u11 = k11 ? u11 : 0u;
        u12 = k12 ? u12 : 0u; u13 = k13 ? u13 : 0u; u14 = k14 ? u14 : 0u; u15 = k15 ? u15 : 0u;
        ACC4(u0) ACC4(u1) ACC4(u2) ACC4(u3) ACC4(u4) ACC4(u5) ACC4(u6) ACC4(u7)
        ACC4(u8) ACC4(u9) ACC4(u10) ACC4(u11) ACC4(u12) ACC4(u13) ACC4(u14) ACC4(u15)
    }
    if (valid) {
        bf16x4v o;
        o[0] = (bf16)(a0 * inv); o[1] = (bf16)(a1 * inv);
        o[2] = (bf16)(a2 * inv); o[3] = (bf16)(a3 * inv);
        *(bf16x4v*)(dst + (size_t)node * 128 + (sl << 2)) = o;
    }
}
#undef ACC4

// ---- MFMA GEMM, 2-phase pipeline with bf16 h output + striped stats.
//      NT = number of 16-col output tiles (8 = 128 cols; 6 = 96 cols for the
//      47+47-col layer-2 projection: 25% less MFMA + B-staging). ----
template<int CH, bool STATS, int NT>
__global__ __launch_bounds__(256) void k_gemm6(
    const bf16* __restrict__ A1, const bf16* __restrict__ A2, const bf16* __restrict__ Bt,
    const float* __restrict__ bias, bf16* __restrict__ outH,
    fp8* __restrict__ yl8, bf16* __restrict__ yrbf, float* __restrict__ stats, int M) {
    __shared__ __attribute__((aligned(16))) bf16 sA[2][4096];
    __shared__ __attribute__((aligned(16))) bf16 sB[2][4096];
    __shared__ float scol[128], scol2[128];
    constexpr int LDB = CH * 32;             // Bt leading dim (elements)
    const int tid = threadIdx.x;
    const int w = tid >> 6, l = tid & 63;
    const int q = l >> 4, r = l & 15;
    const int r0 = blockIdx.x * 128;
    if (STATS && tid < 128) { scol[tid] = 0.f; scol2[tid] = 0.f; }

    auto stage = [&](int buf, int c) {
        const bf16* As = (c < 4) ? A1 : A2;
        const int ka = (c & 3) * 32;
        #pragma unroll
        for (int i = 0; i < 2; ++i) {
            const int T = w * 2 + i;
            const bf16* ga = As + (size_t)(r0 + T * 16 + r) * 128 + ka + q * 8;
            __builtin_amdgcn_global_load_lds((AS1 uint32_t*)(uintptr_t)ga,
                (AS3 uint32_t*)(uint32_t)(uintptr_t)(&sA[buf][T * 512]), 16, 0, 0);
            if (T < NT) {
                const bf16* gb = Bt + (T * 16 + r) * LDB + c * 32 + q * 8;
                __builtin_amdgcn_global_load_lds((AS1 uint32_t*)(uintptr_t)gb,
                    (AS3 uint32_t*)(uint32_t)(uintptr_t)(&sB[buf][T * 512]), 16, 0, 0);
            }
        }
    };

    f32x4 acc[2][NT];
    #pragma unroll
    for (int i = 0; i < 2; ++i)
        #pragma unroll
        for (int j = 0; j < NT; ++j) { acc[i][j][0] = 0.f; acc[i][j][1] = 0.f; acc[i][j][2] = 0.f; acc[i][j][3] = 0.f; }

    stage(0, 0);
    __syncthreads();                 // drains vmcnt(0): buf0 fully landed

    #pragma unroll
    for (int c = 0; c < CH; ++c) {
        const int cur = c & 1;
        if (c + 1 < CH) stage(cur ^ 1, c + 1);   // issue next loads; fly under compute
        bf16x8 af0 = *(const bf16x8*)&sA[cur][(w * 2 + 0) * 512 + q * 128 + r * 8];
        bf16x8 af1 = *(const bf16x8*)&sA[cur][(w * 2 + 1) * 512 + q * 128 + r * 8];
        #pragma unroll
        for (int ct = 0; ct < NT; ++ct) {
            bf16x8 bv = *(const bf16x8*)&sB[cur][ct * 512 + q * 128 + r * 8];
            acc[0][ct] = __builtin_amdgcn_mfma_f32_16x16x32_bf16(af0, bv, acc[0][ct], 0, 0, 0);
            acc[1][ct] = __builtin_amdgcn_mfma_f32_16x16x32_bf16(af1, bv, acc[1][ct], 0, 0, 0);
        }
        __syncthreads();             // drain: next buf landed; all reads of cur done
    }

    if (STATS) {
        #pragma unroll
        for (int ct = 0; ct < NT; ++ct) {
            int col = ct * 16 + r;
            float bv = bias ? bias[col] : 0.f;
            float s_c = 0.f, q_c = 0.f;
            #pragma unroll
            for (int rt = 0; rt < 2; ++rt) {
                #pragma unroll
                for (int j = 0; j < 4; ++j) {
                    int row = r0 + w * 32 + rt * 16 + q * 4 + j;
                    if (row < M) {
                        float v = acc[rt][ct][j] + bv;
                        outH[(size_t)row * 128 + col] = (bf16)v;
                        s_c += v; q_c += v * v;
                    }
                }
            }
            atomicAdd(&scol[col], s_c);
            atomicAdd(&scol2[col], q_c);
        }
        __syncthreads();
        float* sbase = stats + ((blockIdx.x & (NCOPY - 1)) << 8);
        if (tid < 128) {
            atomicAdd(&sbase[tid], scol[tid]);
            atomicAdd(&sbase[128 + tid], scol2[tid]);
        }
    } else {
        #pragma unroll
        for (int rt = 0; rt < 2; ++rt) {
            #pragma unroll
            for (int ct = 0; ct < NT; ++ct) {
                int col = ct * 16 + r;
                #pragma unroll
                for (int j = 0; j < 4; ++j) {
                    int row = r0 + w * 32 + rt * 16 + q * 4 + j;
                    if (row >= M) continue;
                    if (col < 47)      yl8[(size_t)row * 64 + col] = fp8(acc[rt][ct][j]);
                    else if (col < 94) yrbf[(size_t)row * 48 + (col - 47)] = (bf16)acc[rt][ct][j];
                }
            }
        }
    }
}

// ---- tiny BN prep: collapse NCOPY striped stats, compute scale/shift per col. ----
__global__ void k_bn_prep(const float* __restrict__ sums, const float* __restrict__ gma,
                          const float* __restrict__ bta, float* __restrict__ scsh, int n) {
    int col = threadIdx.x;               // 128 threads
    float s = 0.f, q = 0.f;
    #pragma unroll
    for (int cpy = 0; cpy < NCOPY; ++cpy) {
        s += sums[(cpy << 8) + col];
        q += sums[(cpy << 8) + 128 + col];
    }
    float invn = 1.0f / (float)n;
    float mu = s * invn;
    float var = q * invn - mu * mu;
    float sc = gma[col] * rsqrtf(var + BN_EPS);
    scsh[col] = sc;
    scsh[128 + col] = bta[col] - mu * sc;
}

// ---- BN apply + ReLU (bf16 h input, precomputed scale/shift table) ----
__global__ void k_bn_apply(const bf16* __restrict__ h, const float* __restrict__ scsh,
                           bf16* __restrict__ out, unsigned char* __restrict__ out8, int n) {
    int g = blockIdx.x * blockDim.x + threadIdx.x;
    int row = g >> 6, c2 = g & 63;
    if (row >= n) return;
    int col = c2 << 1;
    float2 sc = *(const float2*)(scsh + col);
    float2 sh = *(const float2*)(scsh + 128 + col);
    bf16x2 hv = *(const bf16x2*)(h + (size_t)row * 128 + col);
    float r0 = fmaxf((float)hv[0] * sc.x + sh.x, 0.f);
    float r1 = fmaxf((float)hv[1] * sc.y + sh.y, 0.f);
    bf16x2 o; o[0] = (bf16)r0; o[1] = (bf16)r1;
    *(bf16x2*)(out + (size_t)row * 128 + col) = o;
    uchar2 o8; o8.x = fp8(r0).__x; o8.y = fp8(r1).__x;
    *(uchar2*)(out8 + (size_t)row * 128 + col) = o8;
}

// ---- final: gather-mean of yl (fp8, 64B line/edge) + yr + bl2, log_softmax.
//      Unmasked full-batch main loop + one masked tail batch; vectorized yr. ----
__global__ void k_final(const unsigned char* __restrict__ yl, const bf16* __restrict__ yr,
                        const int* __restrict__ row_ptr, const int* __restrict__ col_idx,
                        const float* __restrict__ inv_deg, const float* __restrict__ bl2,
                        float* __restrict__ out, int n) {
    int node = blockIdx.x * 4 + (threadIdx.x >> 6);
    int lane = threadIdx.x & 63;
    if (node >= n) return;
    int e0 = row_ptr[node], e1 = row_ptr[node + 1];
    float inv = inv_deg[node];
    const int sub = lane >> 4;               // edge slot within group of 4
    const int c4 = lane & 15;                // feature group: feats 4*c4 .. 4*c4+3
    const uint32_t loff = (uint32_t)(c4 << 2);
    float a0 = 0.f, a1 = 0.f, a2 = 0.f, a3 = 0.f;
    int base = e0;
    // full batches: no masking at all
    for (; base + 16 <= e1; base += 16) {
        int i0 = col_idx[base + sub];
        int i1 = col_idx[base + 4 + sub];
        int i2 = col_idx[base + 8 + sub];
        int i3 = col_idx[base + 12 + sub];
        uint32_t u0 = *(const uint32_t*)(yl + (((uint32_t)i0 << 6) + loff));
        uint32_t u1 = *(const uint32_t*)(yl + (((uint32_t)i1 << 6) + loff));
        uint32_t u2 = *(const uint32_t*)(yl + (((uint32_t)i2 << 6) + loff));
        uint32_t u3 = *(const uint32_t*)(yl + (((uint32_t)i3 << 6) + loff));
        f32x2 p0l = __builtin_amdgcn_cvt_pk_f32_fp8(u0, false);
        f32x2 p0h = __builtin_amdgcn_cvt_pk_f32_fp8(u0, true);
        f32x2 p1l = __builtin_amdgcn_cvt_pk_f32_fp8(u1, false);
        f32x2 p1h = __builtin_amdgcn_cvt_pk_f32_fp8(u1, true);
        f32x2 p2l = __builtin_amdgcn_cvt_pk_f32_fp8(u2, false);
        f32x2 p2h = __builtin_amdgcn_cvt_pk_f32_fp8(u2, true);
        f32x2 p3l = __builtin_amdgcn_cvt_pk_f32_fp8(u3, false);
        f32x2 p3h = __builtin_amdgcn_cvt_pk_f32_fp8(u3, true);
        a0 += (p0l[0] + p1l[0]) + (p2l[0] + p3l[0]);
        a1 += (p0l[1] + p1l[1]) + (p2l[1] + p3l[1]);
        a2 += (p0h[0] + p1h[0]) + (p2h[0] + p3h[0]);
        a3 += (p0h[1] + p1h[1]) + (p2h[1] + p3h[1]);
    }
    // single masked tail batch (< 16 edges)
    if (base < e1) {
        int ee0 = base + sub;
        int ee1 = base + 4 + sub;
        int ee2 = base + 8 + sub;
        int ee3 = base + 12 + sub;
        bool k0 = ee0 < e1, k1 = ee1 < e1, k2 = ee2 < e1, k3 = ee3 < e1;
        int i0 = col_idx[k0 ? ee0 : e0];
        int i1 = col_idx[k1 ? ee1 : e0];
        int i2 = col_idx[k2 ? ee2 : e0];
        int i3 = col_idx[k3 ? ee3 : e0];
        uint32_t u0 = *(const uint32_t*)(yl + (((uint32_t)i0 << 6) + loff));
        uint32_t u1 = *(const uint32_t*)(yl + (((uint32_t)i1 << 6) + loff));
        uint32_t u2 = *(const uint32_t*)(yl + (((uint32_t)i2 << 6) + loff));
        uint32_t u3 = *(const uint32_t*)(yl + (((uint32_t)i3 << 6) + loff));
        u0 = k0 ? u0 : 0u;
        u1 = k1 ? u1 : 0u;
        u2 = k2 ? u2 : 0u;
        u3 = k3 ? u3 : 0u;
        f32x2 p0l = __builtin_amdgcn_cvt_pk_f32_fp8(u0, false);
        f32x2 p0h = __builtin_amdgcn_cvt_pk_f32_fp8(u0, true);
        f32x2 p1l = __builtin_amdgcn_cvt_pk_f32_fp8(u1, false);
        f32x2 p1h = __builtin_amdgcn_cvt_pk_f32_fp8(u1, true);
        f32x2 p2l = __builtin_amdgcn_cvt_pk_f32_fp8(u2, false);
        f32x2 p2h = __builtin_amdgcn_cvt_pk_f32_fp8(u2, true);
        f32x2 p3l = __builtin_amdgcn_cvt_pk_f32_fp8(u3, false);
        f32x2 p3h = __builtin_amdgcn_cvt_pk_f32_fp8(u3, true);
        a0 += (p0l[0] + p1l[0]) + (p2l[0] + p3l[0]);
        a1 += (p0l[1] + p1l[1]) + (p2l[1] + p3l[1]);
        a2 += (p0h[0] + p1h[0]) + (p2h[0] + p3h[0]);
        a3 += (p0h[1] + p1h[1]) + (p2h[1] + p3h[1]);
    }
    // sum the 4 edge subgroups (lanes differing in bits 4,5 share c4)
    a0 += __shfl_xor(a0, 16, 64); a1 += __shfl_xor(a1, 16, 64);
    a2 += __shfl_xor(a2, 16, 64); a3 += __shfl_xor(a3, 16, 64);
    a0 += __shfl_xor(a0, 32, 64); a1 += __shfl_xor(a1, 32, 64);
    a2 += __shfl_xor(a2, 32, 64); a3 += __shfl_xor(a3, 32, 64);
    const int f0 = c4 << 2;
    // yr: one 8-byte load (node*96 + 8*c4 is 8B-aligned)
    bf16x4v yv4 = *(const bf16x4v*)(yr + (size_t)node * 48 + f0);
    float v0 = (f0 + 0 < 47) ? fmaf(a0, inv, (float)yv4[0] + bl2[f0 + 0]) : -__builtin_inff();
    float v1 = (f0 + 1 < 47) ? fmaf(a1, inv, (float)yv4[1] + bl2[f0 + 1]) : -__builtin_inff();
    float v2 = (f0 + 2 < 47) ? fmaf(a2, inv, (float)yv4[2] + bl2[f0 + 2]) : -__builtin_inff();
    float v3 = (f0 + 3 < 47) ? fmaf(a3, inv, (float)yv4[3] + bl2[f0 + 3]) : -__builtin_inff();
    float m = fmaxf(fmaxf(v0, v1), fmaxf(v2, v3));
    #pragma unroll
    for (int o = 1; o < 16; o <<= 1) m = fmaxf(m, __shfl_xor(m, o, 64));
    float ex0 = (f0 + 0 < 47) ? __expf(v0 - m) : 0.f;
    float ex1 = (f0 + 1 < 47) ? __expf(v1 - m) : 0.f;
    float ex2 = (f0 + 2 < 47) ? __expf(v2 - m) : 0.f;
    float ex3 = (f0 + 3 < 47) ? __expf(v3 - m) : 0.f;
    float s = (ex0 + ex1) + (ex2 + ex3);
    #pragma unroll
    for (int o = 1; o < 16; o <<= 1) s += __shfl_xor(s, o, 64);
    float ls = __logf(s);
    if (lane < 16) {
        float* op = out + (size_t)node * 47 + f0;
        if (f0 + 0 < 47) op[0] = v0 - m - ls;
        if (f0 + 1 < 47) op[1] = v1 - m - ls;
        if (f0 + 2 < 47) op[2] = v2 - m - ls;
        if (f0 + 3 < 47) op[3] = v3 - m - ls;
    }
}

extern "C" void kernel_launch(void* const* d_in, const int* in_sizes, int n_in,
                              void* d_out, int out_size, void* d_ws, size_t ws_size,
                              hipStream_t stream) {
    const float* x   = (const float*)d_in[0];
    const int*   ei  = (const int*)d_in[1];
    const float* Wl0 = (const float*)d_in[2];
    const float* bl0 = (const float*)d_in[3];
    const float* Wr0 = (const float*)d_in[4];
    const float* g0  = (const float*)d_in[5];
    const float* be0 = (const float*)d_in[6];
    const float* Wl1 = (const float*)d_in[7];
    const float* bl1 = (const float*)d_in[8];
    const float* Wr1 = (const float*)d_in[9];
    const float* g1  = (const float*)d_in[10];
    const float* be1 = (const float*)d_in[11];
    const float* Wl2 = (const float*)d_in[12];
    const float* bl2 = (const float*)d_in[13];
    const float* Wr2 = (const float*)d_in[14];
    float* out = (float*)d_out;

    const int N  = in_sizes[0] / 128;
    const int E  = in_sizes[1] / 2;
    const int NP = ((N + 127) / 128) * 128;
    const int NBKT = (N + BKT_NODES - 1) / BKT_NODES;

    char* p = (char*)d_ws;
    size_t off = 0;
    auto alloc = [&](size_t b) { char* r = p + off; off += (b + 255) & ~(size_t)255; return r; };
    // zero-init region (one memset): bfill, bnsum (2 layers x NCOPY x 256), btot
    int*   bfill   = (int*)alloc(1024 * 4);
    float* bnsum   = (float*)alloc(2 * NCOPY * 256 * 4);
    int*   btot    = (int*)alloc(512 * 4);
    size_t zero_span = off;
    float* scsh    = (float*)alloc(2 * 256 * 4);   // per-layer scale/shift tables
    int*   row_ptr = (int*)alloc((size_t)(N + 1) * 4);
    float* invd    = (float*)alloc((size_t)N * 4);
    int*   col_idx = (int*)alloc((size_t)E * 4);
    uint32_t* pair_buf = (uint32_t*)alloc((size_t)E * 4);
    bf16*  x_bf    = (bf16*)alloc((size_t)NP * 128 * 2);
    bf16*  aggbf   = (bf16*)alloc((size_t)NP * 128 * 2);
    bf16*  hbf     = (bf16*)alloc((size_t)NP * 128 * 2);
    unsigned char* h8 = (unsigned char*)alloc((size_t)NP * 128);
    float* bufF    = (float*)alloc((size_t)NP * 128 * 4 + 256);
    bf16*  Bt0     = (bf16*)alloc(128 * 256 * 2);
    bf16*  Bt1     = (bf16*)alloc(128 * 256 * 2);
    bf16*  Bt2     = (bf16*)alloc(128 * 128 * 2);
    // aliases into bufF (sequentially dead/live): x8 (pre-GEMM0), hraw (bf16 h,
    // GEMM->bn_apply), yl8/yrbf (post-BN1)
    unsigned char* x8 = (unsigned char*)bufF;
    bf16*  hraw = (bf16*)bufF;
    fp8*   yl8  = (fp8*)bufF;
    bf16*  yrbf = (bf16*)((char*)bufF + (size_t)NP * 64);

    hipMemsetAsync(bfill, 0, zero_span, stream);

    int n4 = N * 128 / 4;
    k_setup<<<(n4 + 255) / 256, 256, 0, stream>>>(x, x_bf, x8, n4, ei, btot, E, NBKT,
                                                  Wl0, Wr0, Wl1, Wr1, Wl2, Wr2, Bt0, Bt1, Bt2);
    k_bin<<<(E + TILE_E - 1) / TILE_E, 256, 0, stream>>>(ei, btot, bfill, pair_buf, E, NBKT);
    k_fill2<<<NBKT, 256, 0, stream>>>(pair_buf, btot, row_ptr, invd, col_idx, N, E, NBKT);

    int aggBlocks  = (N + 7) / 8;     // 2 nodes per wave, 4 waves per block
    int gemmBlocks = NP / 128;
    int bnBlocks   = (N * 64 + 255) / 256;
    int finBlocks  = (N + 3) / 4;

    // Layer 0
    k_aggregate<<<aggBlocks, 256, 0, stream>>>(x8, aggbf, row_ptr, col_idx, invd, N);
    k_gemm6<8, true, 8><<<gemmBlocks, 256, 0, stream>>>(aggbf, x_bf, Bt0, bl0, hraw, nullptr, nullptr, bnsum, N);
    k_bn_prep<<<1, 128, 0, stream>>>(bnsum, g0, be0, scsh, N);
    k_bn_apply<<<bnBlocks, 256, 0, stream>>>(hraw, scsh, hbf, h8, N);
    // Layer 1
    k_aggregate<<<aggBlocks, 256, 0, stream>>>(h8, aggbf, row_ptr, col_idx, invd, N);
    k_gemm6<8, true, 8><<<gemmBlocks, 256, 0, stream>>>(aggbf, hbf, Bt1, bl1, hraw, nullptr, nullptr, bnsum + NCOPY * 256, N);
    k_bn_prep<<<1, 128, 0, stream>>>(bnsum + NCOPY * 256, g1, be1, scsh + 256, N);
    k_bn_apply<<<bnBlocks, 256, 0, stream>>>(hraw, scsh + 256, hbf, h8, N);
    // Layer 2: project to yl (fp8, stride 64) / yr (bf16), then gather + log_softmax
    k_gemm6<4, false, 6><<<gemmBlocks, 256, 0, stream>>>(hbf, hbf, Bt2, nullptr, nullptr, yl8, yrbf, nullptr, N);
    k_final<<<finBlocks, 256, 0, stream>>>((const unsigned char*)yl8, yrbf, row_ptr, col_idx, invd, bl2, out, N);
}

// Round 11
// 444.275 us; speedup vs baseline: 1.4845x; 1.0203x over previous
//
#include <hip/hip_runtime.h>
#include <hip/hip_fp8.h>
#include <stdint.h>

#define AS1 __attribute__((address_space(1)))
#define AS3 __attribute__((address_space(3)))

typedef __bf16 bf16;
typedef __bf16 bf16x2 __attribute__((ext_vector_type(2)));
typedef __bf16 bf16x4v __attribute__((ext_vector_type(4)));
typedef __bf16 bf16x8 __attribute__((ext_vector_type(8)));
typedef float f32x4 __attribute__((ext_vector_type(4)));
typedef float f32x2 __attribute__((ext_vector_type(2)));
typedef __hip_fp8_e4m3 fp8;

#define BN_EPS 1e-5f
#define BKT_SHIFT 8              // 256 nodes per bucket
#define BKT_NODES 256
#define TILE_E 2048              // edges per binning block
#define NCOPY 16                 // striped stats copies (atomic de-contention)

// ---- fused setup: weight cvt+transpose, x fp32 -> bf16 + fp8, bucket count ----
__global__ void k_setup(const float* __restrict__ x, bf16* __restrict__ x_bf,
                        unsigned char* __restrict__ x8, int n4,
                        const int* __restrict__ ei, int* __restrict__ btot, int E, int nbkt,
                        const float* __restrict__ Wl0, const float* __restrict__ Wr0,
                        const float* __restrict__ Wl1, const float* __restrict__ Wr1,
                        const float* __restrict__ Wl2, const float* __restrict__ Wr2,
                        bf16* __restrict__ Bt0, bf16* __restrict__ Bt1, bf16* __restrict__ Bt2) {
    __shared__ int hist[512];
    const int tid = threadIdx.x;
    int g = blockIdx.x * 256 + tid;
    if (g < n4) {
        float4 v = ((const float4*)x)[g];
        bf16x4v o; o[0] = (bf16)v.x; o[1] = (bf16)v.y; o[2] = (bf16)v.z; o[3] = (bf16)v.w;
        ((bf16x4v*)x_bf)[g] = o;
        uchar4 o8;
        o8.x = fp8(v.x).__x; o8.y = fp8(v.y).__x; o8.z = fp8(v.z).__x; o8.w = fp8(v.w).__x;
        ((uchar4*)x8)[g] = o8;
    }
    if (blockIdx.x < 128) {
        int idx = g;                 // 32768 threads: c in [0,128), k in [0,256)
        int c = idx >> 8, k = idx & 255;
        float v0 = (k < 128) ? Wl0[k * 128 + c] : Wr0[(k - 128) * 128 + c];
        Bt0[c * 256 + k] = (bf16)v0;
        float v1 = (k < 128) ? Wl1[k * 128 + c] : Wr1[(k - 128) * 128 + c];
        Bt1[c * 256 + k] = (bf16)v1;
        if (k < 128) {
            float v2 = 0.f;
            if (c < 47)      v2 = Wl2[k * 47 + c];
            else if (c < 94) v2 = Wr2[k * 47 + (c - 47)];
            Bt2[c * 128 + k] = (bf16)v2;
        }
    }
    // bucket histogram for blocks [0, ceil(E/4096))
    int nbinb = (E + 4095) / 4096;
    if (blockIdx.x < nbinb) {
        hist[tid] = 0; hist[tid + 256] = 0;
        __syncthreads();
        const int e0 = blockIdx.x * 4096;
        #pragma unroll
        for (int k = 0; k < 4; ++k) {
            int i4 = (e0 >> 2) + k * 256 + tid;
            if (i4 * 4 + 3 < E) {
                int4 d4 = ((const int4*)(ei + E))[i4];
                atomicAdd(&hist[d4.x >> BKT_SHIFT], 1);
                atomicAdd(&hist[d4.y >> BKT_SHIFT], 1);
                atomicAdd(&hist[d4.z >> BKT_SHIFT], 1);
                atomicAdd(&hist[d4.w >> BKT_SHIFT], 1);
            } else {
                for (int e = i4 * 4; e < min(E, i4 * 4 + 4); ++e)
                    atomicAdd(&hist[ei[E + e] >> BKT_SHIFT], 1);
            }
        }
        __syncthreads();
        for (int b = tid; b < nbkt; b += 256)
            if (hist[b]) atomicAdd(&btot[b], hist[b]);
    }
}

// In-block exclusive scan of btot[0..512) into sb[0..512], sb[512]=total.
__device__ __forceinline__ void scan_btot(const int* __restrict__ btot, int nbkt,
                                          int* sb, int* wsum) {
    const int tid = threadIdx.x, lane = tid & 63, wid = tid >> 6;
    int a = (tid < nbkt) ? btot[tid] : 0;
    int b2 = (tid + 256 < nbkt) ? btot[tid + 256] : 0;
    int ia = a, ib = b2;
    #pragma unroll
    for (int d = 1; d < 64; d <<= 1) {
        int t1 = __shfl_up(ia, d, 64);
        int t2 = __shfl_up(ib, d, 64);
        if (lane >= d) { ia += t1; ib += t2; }
    }
    if (lane == 63) { wsum[wid] = ia; wsum[4 + wid] = ib; }
    __syncthreads();
    if (tid == 0) {
        int c = 0;
        #pragma unroll
        for (int i = 0; i < 8; ++i) { int t = wsum[i]; wsum[i] = c; c += t; }
    }
    __syncthreads();
    sb[tid] = ia - a + wsum[wid];
    sb[tid + 256] = ib - b2 + wsum[4 + wid];
    if (tid == 255) sb[512] = ib + wsum[7];
    __syncthreads();
}

// ---- binning pass: in-block bbase scan -> histogram -> claim -> ranked write ----
__global__ __launch_bounds__(256) void k_bin(const int* __restrict__ ei,
                                             const int* __restrict__ btot,
                                             int* __restrict__ bfill,
                                             uint32_t* __restrict__ pair_buf,
                                             int E, int nbkt) {
    __shared__ int hist[512], gbase[512], hcur[512];
    __shared__ int sb[513], wsum[8];
    const int tid = threadIdx.x;
    const int e0 = blockIdx.x * TILE_E;
    hist[tid] = 0; hist[tid + 256] = 0;
    scan_btot(btot, nbkt, sb, wsum);   // includes syncs; hist zeroed before first sync

    int dreg[TILE_E / 256];
    #pragma unroll
    for (int k = 0; k < TILE_E / 256; ++k) {
        int e = e0 + k * 256 + tid;
        int d = (e < E) ? ei[E + e] : -1;
        dreg[k] = d;
        if (d >= 0) atomicAdd(&hist[d >> BKT_SHIFT], 1);
    }
    __syncthreads();

    for (int b = tid; b < nbkt; b += 256) {
        int h = hist[b];
        int g = (h > 0) ? atomicAdd(&bfill[b], h) : 0;
        gbase[b] = sb[b] + g;
        hcur[b] = 0;
    }
    __syncthreads();

    #pragma unroll
    for (int k = 0; k < TILE_E / 256; ++k) {
        int d = dreg[k];
        if (d >= 0) {
            int e = e0 + k * 256 + tid;
            int s = ei[e];
            int b = d >> BKT_SHIFT;
            int r = atomicAdd(&hcur[b], 1);
            pair_buf[(size_t)gbase[b] + r] =
                ((uint32_t)s << BKT_SHIFT) | (uint32_t)(d & (BKT_NODES - 1));
        }
    }
}

// ---- fill: one block per bucket ----
__global__ __launch_bounds__(256) void k_fill2(const uint32_t* __restrict__ pair_buf,
                                               const int* __restrict__ btot,
                                               int* __restrict__ row_ptr,
                                               float* __restrict__ inv_deg,
                                               int* __restrict__ col_idx,
                                               int n, int E, int nbkt) {
    __shared__ int hist[256], excl[256], hcur[256], wsum4[4];
    __shared__ int sb[513], wsum[8];
    const int b = blockIdx.x;
    const int tid = threadIdx.x, lane = tid & 63, wid = tid >> 6;
    const int n0 = b << BKT_SHIFT;
    hist[tid] = 0; hcur[tid] = 0;
    scan_btot(btot, nbkt, sb, wsum);
    const int s = sb[b], e = sb[b + 1];
    for (int i = s + tid; i < e; i += 256)
        atomicAdd(&hist[pair_buf[i] & (BKT_NODES - 1)], 1);
    __syncthreads();
    int v = hist[tid];
    int incl = v;
    #pragma unroll
    for (int d = 1; d < 64; d <<= 1) {
        int t = __shfl_up(incl, d, 64);
        if (lane >= d) incl += t;
    }
    if (lane == 63) wsum4[wid] = incl;
    __syncthreads();
    if (tid == 0) {
        int c = 0;
        #pragma unroll
        for (int i = 0; i < 4; ++i) { int t = wsum4[i]; wsum4[i] = c; c += t; }
    }
    __syncthreads();
    int ex = incl - v + wsum4[wid];
    excl[tid] = ex;
    int node = n0 + tid;
    if (node < n) {
        row_ptr[node] = s + ex;
        inv_deg[node] = 1.0f / (float)(v > 1 ? v : 1);
    }
    if (b == (int)gridDim.x - 1 && tid == 0) row_ptr[n] = E;
    __syncthreads();
    for (int i = s + tid; i < e; i += 256) {
        uint32_t pk = pair_buf[i];
        int dl = pk & (BKT_NODES - 1);
        int r = atomicAdd(&hcur[dl], 1);
        col_idx[s + excl[dl] + r] = (int)(pk >> BKT_SHIFT);
    }
}

// ---- mean-aggregate from fp8 table (128 B/row), two nodes per wave. ----
#define ACC4(u) { f32x2 pl_ = __builtin_amdgcn_cvt_pk_f32_fp8(u, false); \
                  f32x2 ph_ = __builtin_amdgcn_cvt_pk_f32_fp8(u, true);  \
                  a0 += pl_[0]; a1 += pl_[1]; a2 += ph_[0]; a3 += ph_[1]; }
__global__ void k_aggregate(const unsigned char* __restrict__ src8, bf16* __restrict__ dst,
                            const int* __restrict__ row_ptr, const int* __restrict__ col_idx,
                            const float* __restrict__ inv_deg, int n) {
    const int lane = threadIdx.x & 63;
    const int half = lane >> 5;
    const int sl = lane & 31;
    const int node = blockIdx.x * 8 + ((threadIdx.x >> 6) << 1) + half;
    const bool valid = node < n;
    const int nn = valid ? node : 0;
    const int re0 = row_ptr[nn];
    const int re1 = valid ? row_ptr[nn + 1] : re0;
    const float inv = inv_deg[nn];
    const uint32_t l4 = (uint32_t)(sl << 2);
    float a0 = 0.f, a1 = 0.f, a2 = 0.f, a3 = 0.f;
    int e = re0;
    // align to 4 for int4 idx loads (<=3 scalar edges)
    for (; e < re1 && (e & 3); ++e) {
        uint32_t u = *(const uint32_t*)(src8 + (((uint32_t)col_idx[e] << 7) + l4));
        ACC4(u)
    }
    // full 16-edge batches: 4 idx loads + 16 independent gathers in flight
    for (; e + 16 <= re1; e += 16) {
        int4 i0 = *(const int4*)(col_idx + e);
        int4 i1 = *(const int4*)(col_idx + e + 4);
        int4 i2 = *(const int4*)(col_idx + e + 8);
        int4 i3 = *(const int4*)(col_idx + e + 12);
        uint32_t u0  = *(const uint32_t*)(src8 + (((uint32_t)i0.x << 7) + l4));
        uint32_t u1  = *(const uint32_t*)(src8 + (((uint32_t)i0.y << 7) + l4));
        uint32_t u2  = *(const uint32_t*)(src8 + (((uint32_t)i0.z << 7) + l4));
        uint32_t u3  = *(const uint32_t*)(src8 + (((uint32_t)i0.w << 7) + l4));
        uint32_t u4  = *(const uint32_t*)(src8 + (((uint32_t)i1.x << 7) + l4));
        uint32_t u5  = *(const uint32_t*)(src8 + (((uint32_t)i1.y << 7) + l4));
        uint32_t u6  = *(const uint32_t*)(src8 + (((uint32_t)i1.z << 7) + l4));
        uint32_t u7  = *(const uint32_t*)(src8 + (((uint32_t)i1.w << 7) + l4));
        uint32_t u8  = *(const uint32_t*)(src8 + (((uint32_t)i2.x << 7) + l4));
        uint32_t u9  = *(const uint32_t*)(src8 + (((uint32_t)i2.y << 7) + l4));
        uint32_t u10 = *(const uint32_t*)(src8 + (((uint32_t)i2.z << 7) + l4));
        uint32_t u11 = *(const uint32_t*)(src8 + (((uint32_t)i2.w << 7) + l4));
        uint32_t u12 = *(const uint32_t*)(src8 + (((uint32_t)i3.x << 7) + l4));
        uint32_t u13 = *(const uint32_t*)(src8 + (((uint32_t)i3.y << 7) + l4));
        uint32_t u14 = *(const uint32_t*)(src8 + (((uint32_t)i3.z << 7) + l4));
        uint32_t u15 = *(const uint32_t*)(src8 + (((uint32_t)i3.w << 7) + l4));
        ACC4(u0) ACC4(u1) ACC4(u2) ACC4(u3) ACC4(u4) ACC4(u5) ACC4(u6) ACC4(u7)
        ACC4(u8) ACC4(u9) ACC4(u10) ACC4(u11) ACC4(u12) ACC4(u13) ACC4(u14) ACC4(u15)
    }
    // masked tail (<16 edges), aligned idx loads with clamped indices
    if (e < re1) {
        int4 i0 = *(const int4*)(col_idx + e);
        int4 i1 = *(const int4*)(col_idx + e + 4);
        int4 i2 = *(const int4*)(col_idx + e + 8);
        int4 i3 = *(const int4*)(col_idx + e + 12);
        bool k0  = e + 0  < re1, k1  = e + 1  < re1, k2  = e + 2  < re1, k3  = e + 3  < re1;
        bool k4  = e + 4  < re1, k5  = e + 5  < re1, k6  = e + 6  < re1, k7  = e + 7  < re1;
        bool k8  = e + 8  < re1, k9  = e + 9  < re1, k10 = e + 10 < re1, k11 = e + 11 < re1;
        bool k12 = e + 12 < re1, k13 = e + 13 < re1, k14 = e + 14 < re1, k15 = e + 15 < re1;
        int r0  = k0  ? i0.x : 0, r1  = k1  ? i0.y : 0, r2  = k2  ? i0.z : 0, r3  = k3  ? i0.w : 0;
        int r4  = k4  ? i1.x : 0, r5  = k5  ? i1.y : 0, r6  = k6  ? i1.z : 0, r7  = k7  ? i1.w : 0;
        int r8  = k8  ? i2.x : 0, r9  = k9  ? i2.y : 0, r10 = k10 ? i2.z : 0, r11 = k11 ? i2.w : 0;
        int r12 = k12 ? i3.x : 0, r13 = k13 ? i3.y : 0, r14 = k14 ? i3.z : 0, r15 = k15 ? i3.w : 0;
        uint32_t u0  = *(const uint32_t*)(src8 + (((uint32_t)r0  << 7) + l4));
        uint32_t u1  = *(const uint32_t*)(src8 + (((uint32_t)r1  << 7) + l4));
        uint32_t u2  = *(const uint32_t*)(src8 + (((uint32_t)r2  << 7) + l4));
        uint32_t u3  = *(const uint32_t*)(src8 + (((uint32_t)r3  << 7) + l4));
        uint32_t u4  = *(const uint32_t*)(src8 + (((uint32_t)r4  << 7) + l4));
        uint32_t u5  = *(const uint32_t*)(src8 + (((uint32_t)r5  << 7) + l4));
        uint32_t u6  = *(const uint32_t*)(src8 + (((uint32_t)r6  << 7) + l4));
        uint32_t u7  = *(const uint32_t*)(src8 + (((uint32_t)r7  << 7) + l4));
        uint32_t u8  = *(const uint32_t*)(src8 + (((uint32_t)r8  << 7) + l4));
        uint32_t u9  = *(const uint32_t*)(src8 + (((uint32_t)r9  << 7) + l4));
        uint32_t u10 = *(const uint32_t*)(src8 + (((uint32_t)r10 << 7) + l4));
        uint32_t u11 = *(const uint32_t*)(src8 + (((uint32_t)r11 << 7) + l4));
        uint32_t u12 = *(const uint32_t*)(src8 + (((uint32_t)r12 << 7) + l4));
        uint32_t u13 = *(const uint32_t*)(src8 + (((uint32_t)r13 << 7) + l4));
        uint32_t u14 = *(const uint32_t*)(src8 + (((uint32_t)r14 << 7) + l4));
        uint32_t u15 = *(const uint32_t*)(src8 + (((uint32_t)r15 << 7) + l4));
        u0  = k0  ? u0  : 0u; u1  = k1  ? u1  : 0u; u2  = k2  ? u2  : 0u; u3  = k3  ? u3  : 0u;
        u4  = k4  ? u4  : 0u; u5  = k5  ? u5  : 0u; u6  = k6  ? u6  : 0u; u7  = k7  ? u7  : 0u;
        u8  = k8  ? u8  : 0u; u9  = k9  ? u9  : 0u; u10 = k10 ? u10 : 0u; u11 = k11 ? u11 : 0u;
        u12 = k12 ? u12 : 0u; u13 = k13 ? u13 : 0u; u14 = k14 ? u14 : 0u; u15 = k15 ? u15 : 0u;
        ACC4(u0) ACC4(u1) ACC4(u2) ACC4(u3) ACC4(u4) ACC4(u5) ACC4(u6) ACC4(u7)
        ACC4(u8) ACC4(u9) ACC4(u10) ACC4(u11) ACC4(u12) ACC4(u13) ACC4(u14) ACC4(u15)
    }
    if (valid) {
        bf16x4v o;
        o[0] = (bf16)(a0 * inv); o[1] = (bf16)(a1 * inv);
        o[2] = (bf16)(a2 * inv); o[3] = (bf16)(a3 * inv);
        *(bf16x4v*)(dst + (size_t)node * 128 + (sl << 2)) = o;
    }
}
#undef ACC4

// ---- MFMA GEMM v7: B staged to LDS ONCE (64 KB, single barrier, never
//      recycled -> race-free by construction); A fragments stream directly
//      global->VGPR (per-lane fragment address == staging address, proven R3).
//      ZERO barriers in the K-loop: the 2*CH independent A-loads hoist into
//      flight and latency hides in-wave, instead of 8 per-chunk vmcnt(0)
//      drains synchronizing all waves. ----
template<int CH, bool STATS, int NT>
__global__ __launch_bounds__(256) void k_gemm7(
    const bf16* __restrict__ A1, const bf16* __restrict__ A2, const bf16* __restrict__ Bt,
    const float* __restrict__ bias, bf16* __restrict__ outH,
    fp8* __restrict__ yl8, bf16* __restrict__ yrbf, float* __restrict__ stats, int M) {
    __shared__ __attribute__((aligned(16))) bf16 sB[CH * NT * 512];
    __shared__ float scol[128], scol2[128];
    constexpr int LDB = CH * 32;             // Bt leading dim (elements)
    const int tid = threadIdx.x;
    const int w = tid >> 6, l = tid & 63;
    const int q = l >> 4, r = l & 15;
    const int r0 = blockIdx.x * 128;
    if (STATS && tid < 128) { scol[tid] = 0.f; scol2[tid] = 0.f; }

    // stage ALL of B once: CH chunks x NT col-tiles, tile layout = fragment order
    #pragma unroll
    for (int c = 0; c < CH; ++c) {
        #pragma unroll
        for (int i = 0; i < 2; ++i) {
            const int T = w * 2 + i;
            if (T < NT) {
                const bf16* gb = Bt + (T * 16 + r) * LDB + c * 32 + q * 8;
                __builtin_amdgcn_global_load_lds((AS1 uint32_t*)(uintptr_t)gb,
                    (AS3 uint32_t*)(uint32_t)(uintptr_t)(&sB[(c * NT + T) * 512]), 16, 0, 0);
            }
        }
    }

    const uint32_t aoff = ((uint32_t)(r0 + w * 32 + r) << 7) + (uint32_t)(q << 3);
    const bf16* pa0_1 = A1 + aoff;                 // row-tile w*2
    const bf16* pa1_1 = A1 + aoff + 16 * 128;      // row-tile w*2+1
    const bf16* pa0_2 = A2 + aoff;
    const bf16* pa1_2 = A2 + aoff + 16 * 128;

    f32x4 acc[2][NT];
    #pragma unroll
    for (int i = 0; i < 2; ++i)
        #pragma unroll
        for (int j = 0; j < NT; ++j) { acc[i][j][0] = 0.f; acc[i][j][1] = 0.f; acc[i][j][2] = 0.f; acc[i][j][3] = 0.f; }

    __syncthreads();                 // one drain: all of B landed; read-only after

    #pragma unroll
    for (int c = 0; c < CH; ++c) {
        const bf16* p0 = (c < 4) ? pa0_1 : pa0_2;
        const bf16* p1 = (c < 4) ? pa1_1 : pa1_2;
        const int ka = (c & 3) * 32;
        bf16x8 af0 = *(const bf16x8*)(p0 + ka);    // direct global->VGPR fragment
        bf16x8 af1 = *(const bf16x8*)(p1 + ka);
        #pragma unroll
        for (int ct = 0; ct < NT; ++ct) {
            bf16x8 bv = *(const bf16x8*)&sB[(c * NT + ct) * 512 + q * 128 + r * 8];
            acc[0][ct] = __builtin_amdgcn_mfma_f32_16x16x32_bf16(af0, bv, acc[0][ct], 0, 0, 0);
            acc[1][ct] = __builtin_amdgcn_mfma_f32_16x16x32_bf16(af1, bv, acc[1][ct], 0, 0, 0);
        }
    }

    if (STATS) {
        #pragma unroll
        for (int ct = 0; ct < NT; ++ct) {
            int col = ct * 16 + r;
            float bv = bias ? bias[col] : 0.f;
            float s_c = 0.f, q_c = 0.f;
            #pragma unroll
            for (int rt = 0; rt < 2; ++rt) {
                #pragma unroll
                for (int j = 0; j < 4; ++j) {
                    int row = r0 + w * 32 + rt * 16 + q * 4 + j;
                    if (row < M) {
                        float v = acc[rt][ct][j] + bv;
                        outH[(size_t)row * 128 + col] = (bf16)v;
                        s_c += v; q_c += v * v;
                    }
                }
            }
            atomicAdd(&scol[col], s_c);
            atomicAdd(&scol2[col], q_c);
        }
        __syncthreads();
        float* sbase = stats + ((blockIdx.x & (NCOPY - 1)) << 8);
        if (tid < 128) {
            atomicAdd(&sbase[tid], scol[tid]);
            atomicAdd(&sbase[128 + tid], scol2[tid]);
        }
    } else {
        #pragma unroll
        for (int rt = 0; rt < 2; ++rt) {
            #pragma unroll
            for (int ct = 0; ct < NT; ++ct) {
                int col = ct * 16 + r;
                #pragma unroll
                for (int j = 0; j < 4; ++j) {
                    int row = r0 + w * 32 + rt * 16 + q * 4 + j;
                    if (row >= M) continue;
                    if (col < 47)      yl8[(size_t)row * 64 + col] = fp8(acc[rt][ct][j]);
                    else if (col < 94) yrbf[(size_t)row * 48 + (col - 47)] = (bf16)acc[rt][ct][j];
                }
            }
        }
    }
}

// ---- tiny BN prep: collapse NCOPY striped stats, compute scale/shift per col. ----
__global__ void k_bn_prep(const float* __restrict__ sums, const float* __restrict__ gma,
                          const float* __restrict__ bta, float* __restrict__ scsh, int n) {
    int col = threadIdx.x;               // 128 threads
    float s = 0.f, q = 0.f;
    #pragma unroll
    for (int cpy = 0; cpy < NCOPY; ++cpy) {
        s += sums[(cpy << 8) + col];
        q += sums[(cpy << 8) + 128 + col];
    }
    float invn = 1.0f / (float)n;
    float mu = s * invn;
    float var = q * invn - mu * mu;
    float sc = gma[col] * rsqrtf(var + BN_EPS);
    scsh[col] = sc;
    scsh[128 + col] = bta[col] - mu * sc;
}

// ---- BN apply + ReLU (bf16 h input, precomputed scale/shift table) ----
__global__ void k_bn_apply(const bf16* __restrict__ h, const float* __restrict__ scsh,
                           bf16* __restrict__ out, unsigned char* __restrict__ out8, int n) {
    int g = blockIdx.x * blockDim.x + threadIdx.x;
    int row = g >> 6, c2 = g & 63;
    if (row >= n) return;
    int col = c2 << 1;
    float2 sc = *(const float2*)(scsh + col);
    float2 sh = *(const float2*)(scsh + 128 + col);
    bf16x2 hv = *(const bf16x2*)(h + (size_t)row * 128 + col);
    float r0 = fmaxf((float)hv[0] * sc.x + sh.x, 0.f);
    float r1 = fmaxf((float)hv[1] * sc.y + sh.y, 0.f);
    bf16x2 o; o[0] = (bf16)r0; o[1] = (bf16)r1;
    *(bf16x2*)(out + (size_t)row * 128 + col) = o;
    uchar2 o8; o8.x = fp8(r0).__x; o8.y = fp8(r1).__x;
    *(uchar2*)(out8 + (size_t)row * 128 + col) = o8;
}

// ---- final: gather-mean of yl (fp8, 64B line/edge) + yr + bl2, log_softmax. ----
__global__ void k_final(const unsigned char* __restrict__ yl, const bf16* __restrict__ yr,
                        const int* __restrict__ row_ptr, const int* __restrict__ col_idx,
                        const float* __restrict__ inv_deg, const float* __restrict__ bl2,
                        float* __restrict__ out, int n) {
    int node = blockIdx.x * 4 + (threadIdx.x >> 6);
    int lane = threadIdx.x & 63;
    if (node >= n) return;
    int e0 = row_ptr[node], e1 = row_ptr[node + 1];
    float inv = inv_deg[node];
    const int sub = lane >> 4;               // edge slot within group of 4
    const int c4 = lane & 15;                // feature group: feats 4*c4 .. 4*c4+3
    const uint32_t loff = (uint32_t)(c4 << 2);
    float a0 = 0.f, a1 = 0.f, a2 = 0.f, a3 = 0.f;
    int base = e0;
    // full batches: no masking at all
    for (; base + 16 <= e1; base += 16) {
        int i0 = col_idx[base + sub];
        int i1 = col_idx[base + 4 + sub];
        int i2 = col_idx[base + 8 + sub];
        int i3 = col_idx[base + 12 + sub];
        uint32_t u0 = *(const uint32_t*)(yl + (((uint32_t)i0 << 6) + loff));
        uint32_t u1 = *(const uint32_t*)(yl + (((uint32_t)i1 << 6) + loff));
        uint32_t u2 = *(const uint32_t*)(yl + (((uint32_t)i2 << 6) + loff));
        uint32_t u3 = *(const uint32_t*)(yl + (((uint32_t)i3 << 6) + loff));
        f32x2 p0l = __builtin_amdgcn_cvt_pk_f32_fp8(u0, false);
        f32x2 p0h = __builtin_amdgcn_cvt_pk_f32_fp8(u0, true);
        f32x2 p1l = __builtin_amdgcn_cvt_pk_f32_fp8(u1, false);
        f32x2 p1h = __builtin_amdgcn_cvt_pk_f32_fp8(u1, true);
        f32x2 p2l = __builtin_amdgcn_cvt_pk_f32_fp8(u2, false);
        f32x2 p2h = __builtin_amdgcn_cvt_pk_f32_fp8(u2, true);
        f32x2 p3l = __builtin_amdgcn_cvt_pk_f32_fp8(u3, false);
        f32x2 p3h = __builtin_amdgcn_cvt_pk_f32_fp8(u3, true);
        a0 += (p0l[0] + p1l[0]) + (p2l[0] + p3l[0]);
        a1 += (p0l[1] + p1l[1]) + (p2l[1] + p3l[1]);
        a2 += (p0h[0] + p1h[0]) + (p2h[0] + p3h[0]);
        a3 += (p0h[1] + p1h[1]) + (p2h[1] + p3h[1]);
    }
    // single masked tail batch (< 16 edges)
    if (base < e1) {
        int ee0 = base + sub;
        int ee1 = base + 4 + sub;
        int ee2 = base + 8 + sub;
        int ee3 = base + 12 + sub;
        bool k0 = ee0 < e1, k1 = ee1 < e1, k2 = ee2 < e1, k3 = ee3 < e1;
        int i0 = col_idx[k0 ? ee0 : e0];
        int i1 = col_idx[k1 ? ee1 : e0];
        int i2 = col_idx[k2 ? ee2 : e0];
        int i3 = col_idx[k3 ? ee3 : e0];
        uint32_t u0 = *(const uint32_t*)(yl + (((uint32_t)i0 << 6) + loff));
        uint32_t u1 = *(const uint32_t*)(yl + (((uint32_t)i1 << 6) + loff));
        uint32_t u2 = *(const uint32_t*)(yl + (((uint32_t)i2 << 6) + loff));
        uint32_t u3 = *(const uint32_t*)(yl + (((uint32_t)i3 << 6) + loff));
        u0 = k0 ? u0 : 0u;
        u1 = k1 ? u1 : 0u;
        u2 = k2 ? u2 : 0u;
        u3 = k3 ? u3 : 0u;
        f32x2 p0l = __builtin_amdgcn_cvt_pk_f32_fp8(u0, false);
        f32x2 p0h = __builtin_amdgcn_cvt_pk_f32_fp8(u0, true);
        f32x2 p1l = __builtin_amdgcn_cvt_pk_f32_fp8(u1, false);
        f32x2 p1h = __builtin_amdgcn_cvt_pk_f32_fp8(u1, true);
        f32x2 p2l = __builtin_amdgcn_cvt_pk_f32_fp8(u2, false);
        f32x2 p2h = __builtin_amdgcn_cvt_pk_f32_fp8(u2, true);
        f32x2 p3l = __builtin_amdgcn_cvt_pk_f32_fp8(u3, false);
        f32x2 p3h = __builtin_amdgcn_cvt_pk_f32_fp8(u3, true);
        a0 += (p0l[0] + p1l[0]) + (p2l[0] + p3l[0]);
        a1 += (p0l[1] + p1l[1]) + (p2l[1] + p3l[1]);
        a2 += (p0h[0] + p1h[0]) + (p2h[0] + p3h[0]);
        a3 += (p0h[1] + p1h[1]) + (p2h[1] + p3h[1]);
    }
    // sum the 4 edge subgroups (lanes differing in bits 4,5 share c4)
    a0 += __shfl_xor(a0, 16, 64); a1 += __shfl_xor(a1, 16, 64);
    a2 += __shfl_xor(a2, 16, 64); a3 += __shfl_xor(a3, 16, 64);
    a0 += __shfl_xor(a0, 32, 64); a1 += __shfl_xor(a1, 32, 64);
    a2 += __shfl_xor(a2, 32, 64); a3 += __shfl_xor(a3, 32, 64);
    const int f0 = c4 << 2;
    // yr: one 8-byte load (node*96 + 8*c4 is 8B-aligned)
    bf16x4v yv4 = *(const bf16x4v*)(yr + (size_t)node * 48 + f0);
    float v0 = (f0 + 0 < 47) ? fmaf(a0, inv, (float)yv4[0] + bl2[f0 + 0]) : -__builtin_inff();
    float v1 = (f0 + 1 < 47) ? fmaf(a1, inv, (float)yv4[1] + bl2[f0 + 1]) : -__builtin_inff();
    float v2 = (f0 + 2 < 47) ? fmaf(a2, inv, (float)yv4[2] + bl2[f0 + 2]) : -__builtin_inff();
    float v3 = (f0 + 3 < 47) ? fmaf(a3, inv, (float)yv4[3] + bl2[f0 + 3]) : -__builtin_inff();
    float m = fmaxf(fmaxf(v0, v1), fmaxf(v2, v3));
    #pragma unroll
    for (int o = 1; o < 16; o <<= 1) m = fmaxf(m, __shfl_xor(m, o, 64));
    float ex0 = (f0 + 0 < 47) ? __expf(v0 - m) : 0.f;
    float ex1 = (f0 + 1 < 47) ? __expf(v1 - m) : 0.f;
    float ex2 = (f0 + 2 < 47) ? __expf(v2 - m) : 0.f;
    float ex3 = (f0 + 3 < 47) ? __expf(v3 - m) : 0.f;
    float s = (ex0 + ex1) + (ex2 + ex3);
    #pragma unroll
    for (int o = 1; o < 16; o <<= 1) s += __shfl_xor(s, o, 64);
    float ls = __logf(s);
    if (lane < 16) {
        float* op = out + (size_t)node * 47 + f0;
        if (f0 + 0 < 47) op[0] = v0 - m - ls;
        if (f0 + 1 < 47) op[1] = v1 - m - ls;
        if (f0 + 2 < 47) op[2] = v2 - m - ls;
        if (f0 + 3 < 47) op[3] = v3 - m - ls;
    }
}

extern "C" void kernel_launch(void* const* d_in, const int* in_sizes, int n_in,
                              void* d_out, int out_size, void* d_ws, size_t ws_size,
                              hipStream_t stream) {
    const float* x   = (const float*)d_in[0];
    const int*   ei  = (const int*)d_in[1];
    const float* Wl0 = (const float*)d_in[2];
    const float* bl0 = (const float*)d_in[3];
    const float* Wr0 = (const float*)d_in[4];
    const float* g0  = (const float*)d_in[5];
    const float* be0 = (const float*)d_in[6];
    const float* Wl1 = (const float*)d_in[7];
    const float* bl1 = (const float*)d_in[8];
    const float* Wr1 = (const float*)d_in[9];
    const float* g1  = (const float*)d_in[10];
    const float* be1 = (const float*)d_in[11];
    const float* Wl2 = (const float*)d_in[12];
    const float* bl2 = (const float*)d_in[13];
    const float* Wr2 = (const float*)d_in[14];
    float* out = (float*)d_out;

    const int N  = in_sizes[0] / 128;
    const int E  = in_sizes[1] / 2;
    const int NP = ((N + 127) / 128) * 128;
    const int NBKT = (N + BKT_NODES - 1) / BKT_NODES;

    char* p = (char*)d_ws;
    size_t off = 0;
    auto alloc = [&](size_t b) { char* r = p + off; off += (b + 255) & ~(size_t)255; return r; };
    // zero-init region (one memset): bfill, bnsum (2 layers x NCOPY x 256), btot
    int*   bfill   = (int*)alloc(1024 * 4);
    float* bnsum   = (float*)alloc(2 * NCOPY * 256 * 4);
    int*   btot    = (int*)alloc(512 * 4);
    size_t zero_span = off;
    float* scsh    = (float*)alloc(2 * 256 * 4);   // per-layer scale/shift tables
    int*   row_ptr = (int*)alloc((size_t)(N + 1) * 4);
    float* invd    = (float*)alloc((size_t)N * 4);
    int*   col_idx = (int*)alloc((size_t)E * 4);
    uint32_t* pair_buf = (uint32_t*)alloc((size_t)E * 4);
    bf16*  x_bf    = (bf16*)alloc((size_t)NP * 128 * 2);
    bf16*  aggbf   = (bf16*)alloc((size_t)NP * 128 * 2);
    bf16*  hbf     = (bf16*)alloc((size_t)NP * 128 * 2);
    unsigned char* h8 = (unsigned char*)alloc((size_t)NP * 128);
    float* bufF    = (float*)alloc((size_t)NP * 128 * 4 + 256);
    bf16*  Bt0     = (bf16*)alloc(128 * 256 * 2);
    bf16*  Bt1     = (bf16*)alloc(128 * 256 * 2);
    bf16*  Bt2     = (bf16*)alloc(128 * 128 * 2);
    // aliases into bufF (sequentially dead/live): x8 (pre-GEMM0), hraw (bf16 h,
    // GEMM->bn_apply), yl8/yrbf (post-BN1)
    unsigned char* x8 = (unsigned char*)bufF;
    bf16*  hraw = (bf16*)bufF;
    fp8*   yl8  = (fp8*)bufF;
    bf16*  yrbf = (bf16*)((char*)bufF + (size_t)NP * 64);

    hipMemsetAsync(bfill, 0, zero_span, stream);

    int n4 = N * 128 / 4;
    k_setup<<<(n4 + 255) / 256, 256, 0, stream>>>(x, x_bf, x8, n4, ei, btot, E, NBKT,
                                                  Wl0, Wr0, Wl1, Wr1, Wl2, Wr2, Bt0, Bt1, Bt2);
    k_bin<<<(E + TILE_E - 1) / TILE_E, 256, 0, stream>>>(ei, btot, bfill, pair_buf, E, NBKT);
    k_fill2<<<NBKT, 256, 0, stream>>>(pair_buf, btot, row_ptr, invd, col_idx, N, E, NBKT);

    int aggBlocks  = (N + 7) / 8;     // 2 nodes per wave, 4 waves per block
    int gemmBlocks = NP / 128;
    int bnBlocks   = (N * 64 + 255) / 256;
    int finBlocks  = (N + 3) / 4;

    // Layer 0
    k_aggregate<<<aggBlocks, 256, 0, stream>>>(x8, aggbf, row_ptr, col_idx, invd, N);
    k_gemm7<8, true, 8><<<gemmBlocks, 256, 0, stream>>>(aggbf, x_bf, Bt0, bl0, hraw, nullptr, nullptr, bnsum, N);
    k_bn_prep<<<1, 128, 0, stream>>>(bnsum, g0, be0, scsh, N);
    k_bn_apply<<<bnBlocks, 256, 0, stream>>>(hraw, scsh, hbf, h8, N);
    // Layer 1
    k_aggregate<<<aggBlocks, 256, 0, stream>>>(h8, aggbf, row_ptr, col_idx, invd, N);
    k_gemm7<8, true, 8><<<gemmBlocks, 256, 0, stream>>>(aggbf, hbf, Bt1, bl1, hraw, nullptr, nullptr, bnsum + NCOPY * 256, N);
    k_bn_prep<<<1, 128, 0, stream>>>(bnsum + NCOPY * 256, g1, be1, scsh + 256, N);
    k_bn_apply<<<bnBlocks, 256, 0, stream>>>(hraw, scsh + 256, hbf, h8, N);
    // Layer 2: project to yl (fp8, stride 64) / yr (bf16), then gather + log_softmax
    k_gemm7<4, false, 6><<<gemmBlocks, 256, 0, stream>>>(hbf, hbf, Bt2, nullptr, nullptr, yl8, yrbf, nullptr, N);
    k_final<<<finBlocks, 256, 0, stream>>>((const unsigned char*)yl8, yrbf, row_ptr, col_idx, invd, bl2, out, N);
}

// Round 12
// 423.850 us; speedup vs baseline: 1.5561x; 1.0482x over previous
//
#include <hip/hip_runtime.h>
#include <hip/hip_fp8.h>
#include <stdint.h>

#define AS1 __attribute__((address_space(1)))
#define AS3 __attribute__((address_space(3)))

typedef __bf16 bf16;
typedef __bf16 bf16x2 __attribute__((ext_vector_type(2)));
typedef __bf16 bf16x4v __attribute__((ext_vector_type(4)));
typedef __bf16 bf16x8 __attribute__((ext_vector_type(8)));
typedef float f32x4 __attribute__((ext_vector_type(4)));
typedef float f32x2 __attribute__((ext_vector_type(2)));
typedef __hip_fp8_e4m3 fp8;

#define BN_EPS 1e-5f
#define BKT_SHIFT 8              // 256 nodes per bucket
#define BKT_NODES 256
#define TILE_E 2048              // edges per binning block
#define NCOPY 16                 // striped stats copies (atomic de-contention)

// ---- fused setup: weight cvt+transpose, x fp32 -> bf16 + fp8, bucket count ----
__global__ void k_setup(const float* __restrict__ x, bf16* __restrict__ x_bf,
                        unsigned char* __restrict__ x8, int n4,
                        const int* __restrict__ ei, int* __restrict__ btot, int E, int nbkt,
                        const float* __restrict__ Wl0, const float* __restrict__ Wr0,
                        const float* __restrict__ Wl1, const float* __restrict__ Wr1,
                        const float* __restrict__ Wl2, const float* __restrict__ Wr2,
                        bf16* __restrict__ Bt0, bf16* __restrict__ Bt1, bf16* __restrict__ Bt2) {
    __shared__ int hist[512];
    const int tid = threadIdx.x;
    int g = blockIdx.x * 256 + tid;
    if (g < n4) {
        float4 v = ((const float4*)x)[g];
        bf16x4v o; o[0] = (bf16)v.x; o[1] = (bf16)v.y; o[2] = (bf16)v.z; o[3] = (bf16)v.w;
        ((bf16x4v*)x_bf)[g] = o;
        uchar4 o8;
        o8.x = fp8(v.x).__x; o8.y = fp8(v.y).__x; o8.z = fp8(v.z).__x; o8.w = fp8(v.w).__x;
        ((uchar4*)x8)[g] = o8;
    }
    if (blockIdx.x < 128) {
        int idx = g;                 // 32768 threads: c in [0,128), k in [0,256)
        int c = idx >> 8, k = idx & 255;
        float v0 = (k < 128) ? Wl0[k * 128 + c] : Wr0[(k - 128) * 128 + c];
        Bt0[c * 256 + k] = (bf16)v0;
        float v1 = (k < 128) ? Wl1[k * 128 + c] : Wr1[(k - 128) * 128 + c];
        Bt1[c * 256 + k] = (bf16)v1;
        if (k < 128) {
            float v2 = 0.f;
            if (c < 47)      v2 = Wl2[k * 47 + c];
            else if (c < 94) v2 = Wr2[k * 47 + (c - 47)];
            Bt2[c * 128 + k] = (bf16)v2;
        }
    }
    // bucket histogram for blocks [0, ceil(E/4096))
    int nbinb = (E + 4095) / 4096;
    if (blockIdx.x < nbinb) {
        hist[tid] = 0; hist[tid + 256] = 0;
        __syncthreads();
        const int e0 = blockIdx.x * 4096;
        #pragma unroll
        for (int k = 0; k < 4; ++k) {
            int i4 = (e0 >> 2) + k * 256 + tid;
            if (i4 * 4 + 3 < E) {
                int4 d4 = ((const int4*)(ei + E))[i4];
                atomicAdd(&hist[d4.x >> BKT_SHIFT], 1);
                atomicAdd(&hist[d4.y >> BKT_SHIFT], 1);
                atomicAdd(&hist[d4.z >> BKT_SHIFT], 1);
                atomicAdd(&hist[d4.w >> BKT_SHIFT], 1);
            } else {
                for (int e = i4 * 4; e < min(E, i4 * 4 + 4); ++e)
                    atomicAdd(&hist[ei[E + e] >> BKT_SHIFT], 1);
            }
        }
        __syncthreads();
        for (int b = tid; b < nbkt; b += 256)
            if (hist[b]) atomicAdd(&btot[b], hist[b]);
    }
}

// In-block exclusive scan of btot[0..512) into sb[0..512], sb[512]=total.
__device__ __forceinline__ void scan_btot(const int* __restrict__ btot, int nbkt,
                                          int* sb, int* wsum) {
    const int tid = threadIdx.x, lane = tid & 63, wid = tid >> 6;
    int a = (tid < nbkt) ? btot[tid] : 0;
    int b2 = (tid + 256 < nbkt) ? btot[tid + 256] : 0;
    int ia = a, ib = b2;
    #pragma unroll
    for (int d = 1; d < 64; d <<= 1) {
        int t1 = __shfl_up(ia, d, 64);
        int t2 = __shfl_up(ib, d, 64);
        if (lane >= d) { ia += t1; ib += t2; }
    }
    if (lane == 63) { wsum[wid] = ia; wsum[4 + wid] = ib; }
    __syncthreads();
    if (tid == 0) {
        int c = 0;
        #pragma unroll
        for (int i = 0; i < 8; ++i) { int t = wsum[i]; wsum[i] = c; c += t; }
    }
    __syncthreads();
    sb[tid] = ia - a + wsum[wid];
    sb[tid + 256] = ib - b2 + wsum[4 + wid];
    if (tid == 255) sb[512] = ib + wsum[7];
    __syncthreads();
}

// ---- binning pass: in-block bbase scan -> histogram -> claim -> ranked write ----
__global__ __launch_bounds__(256) void k_bin(const int* __restrict__ ei,
                                             const int* __restrict__ btot,
                                             int* __restrict__ bfill,
                                             uint32_t* __restrict__ pair_buf,
                                             int E, int nbkt) {
    __shared__ int hist[512], gbase[512], hcur[512];
    __shared__ int sb[513], wsum[8];
    const int tid = threadIdx.x;
    const int e0 = blockIdx.x * TILE_E;
    hist[tid] = 0; hist[tid + 256] = 0;
    scan_btot(btot, nbkt, sb, wsum);   // includes syncs; hist zeroed before first sync

    int dreg[TILE_E / 256];
    #pragma unroll
    for (int k = 0; k < TILE_E / 256; ++k) {
        int e = e0 + k * 256 + tid;
        int d = (e < E) ? ei[E + e] : -1;
        dreg[k] = d;
        if (d >= 0) atomicAdd(&hist[d >> BKT_SHIFT], 1);
    }
    __syncthreads();

    for (int b = tid; b < nbkt; b += 256) {
        int h = hist[b];
        int g = (h > 0) ? atomicAdd(&bfill[b], h) : 0;
        gbase[b] = sb[b] + g;
        hcur[b] = 0;
    }
    __syncthreads();

    #pragma unroll
    for (int k = 0; k < TILE_E / 256; ++k) {
        int d = dreg[k];
        if (d >= 0) {
            int e = e0 + k * 256 + tid;
            int s = ei[e];
            int b = d >> BKT_SHIFT;
            int r = atomicAdd(&hcur[b], 1);
            pair_buf[(size_t)gbase[b] + r] =
                ((uint32_t)s << BKT_SHIFT) | (uint32_t)(d & (BKT_NODES - 1));
        }
    }
}

// ---- fill: one block per bucket ----
__global__ __launch_bounds__(256) void k_fill2(const uint32_t* __restrict__ pair_buf,
                                               const int* __restrict__ btot,
                                               int* __restrict__ row_ptr,
                                               float* __restrict__ inv_deg,
                                               int* __restrict__ col_idx,
                                               int n, int E, int nbkt) {
    __shared__ int hist[256], excl[256], hcur[256], wsum4[4];
    __shared__ int sb[513], wsum[8];
    const int b = blockIdx.x;
    const int tid = threadIdx.x, lane = tid & 63, wid = tid >> 6;
    const int n0 = b << BKT_SHIFT;
    hist[tid] = 0; hcur[tid] = 0;
    scan_btot(btot, nbkt, sb, wsum);
    const int s = sb[b], e = sb[b + 1];
    for (int i = s + tid; i < e; i += 256)
        atomicAdd(&hist[pair_buf[i] & (BKT_NODES - 1)], 1);
    __syncthreads();
    int v = hist[tid];
    int incl = v;
    #pragma unroll
    for (int d = 1; d < 64; d <<= 1) {
        int t = __shfl_up(incl, d, 64);
        if (lane >= d) incl += t;
    }
    if (lane == 63) wsum4[wid] = incl;
    __syncthreads();
    if (tid == 0) {
        int c = 0;
        #pragma unroll
        for (int i = 0; i < 4; ++i) { int t = wsum4[i]; wsum4[i] = c; c += t; }
    }
    __syncthreads();
    int ex = incl - v + wsum4[wid];
    excl[tid] = ex;
    int node = n0 + tid;
    if (node < n) {
        row_ptr[node] = s + ex;
        inv_deg[node] = 1.0f / (float)(v > 1 ? v : 1);
    }
    if (b == (int)gridDim.x - 1 && tid == 0) row_ptr[n] = E;
    __syncthreads();
    for (int i = s + tid; i < e; i += 256) {
        uint32_t pk = pair_buf[i];
        int dl = pk & (BKT_NODES - 1);
        int r = atomicAdd(&hcur[dl], 1);
        col_idx[s + excl[dl] + r] = (int)(pk >> BKT_SHIFT);
    }
}

// ---- mean-aggregate from fp8 table (128 B/row), two nodes per wave. ----
#define ACC4(u) { f32x2 pl_ = __builtin_amdgcn_cvt_pk_f32_fp8(u, false); \
                  f32x2 ph_ = __builtin_amdgcn_cvt_pk_f32_fp8(u, true);  \
                  a0 += pl_[0]; a1 += pl_[1]; a2 += ph_[0]; a3 += ph_[1]; }
__global__ void k_aggregate(const unsigned char* __restrict__ src8, bf16* __restrict__ dst,
                            const int* __restrict__ row_ptr, const int* __restrict__ col_idx,
                            const float* __restrict__ inv_deg, int n) {
    const int lane = threadIdx.x & 63;
    const int half = lane >> 5;
    const int sl = lane & 31;
    const int node = blockIdx.x * 8 + ((threadIdx.x >> 6) << 1) + half;
    const bool valid = node < n;
    const int nn = valid ? node : 0;
    const int re0 = row_ptr[nn];
    const int re1 = valid ? row_ptr[nn + 1] : re0;
    const float inv = inv_deg[nn];
    const uint32_t l4 = (uint32_t)(sl << 2);
    float a0 = 0.f, a1 = 0.f, a2 = 0.f, a3 = 0.f;
    int e = re0;
    // align to 4 for int4 idx loads (<=3 scalar edges)
    for (; e < re1 && (e & 3); ++e) {
        uint32_t u = *(const uint32_t*)(src8 + (((uint32_t)col_idx[e] << 7) + l4));
        ACC4(u)
    }
    // full 16-edge batches: 4 idx loads + 16 independent gathers in flight
    for (; e + 16 <= re1; e += 16) {
        int4 i0 = *(const int4*)(col_idx + e);
        int4 i1 = *(const int4*)(col_idx + e + 4);
        int4 i2 = *(const int4*)(col_idx + e + 8);
        int4 i3 = *(const int4*)(col_idx + e + 12);
        uint32_t u0  = *(const uint32_t*)(src8 + (((uint32_t)i0.x << 7) + l4));
        uint32_t u1  = *(const uint32_t*)(src8 + (((uint32_t)i0.y << 7) + l4));
        uint32_t u2  = *(const uint32_t*)(src8 + (((uint32_t)i0.z << 7) + l4));
        uint32_t u3  = *(const uint32_t*)(src8 + (((uint32_t)i0.w << 7) + l4));
        uint32_t u4  = *(const uint32_t*)(src8 + (((uint32_t)i1.x << 7) + l4));
        uint32_t u5  = *(const uint32_t*)(src8 + (((uint32_t)i1.y << 7) + l4));
        uint32_t u6  = *(const uint32_t*)(src8 + (((uint32_t)i1.z << 7) + l4));
        uint32_t u7  = *(const uint32_t*)(src8 + (((uint32_t)i1.w << 7) + l4));
        uint32_t u8  = *(const uint32_t*)(src8 + (((uint32_t)i2.x << 7) + l4));
        uint32_t u9  = *(const uint32_t*)(src8 + (((uint32_t)i2.y << 7) + l4));
        uint32_t u10 = *(const uint32_t*)(src8 + (((uint32_t)i2.z << 7) + l4));
        uint32_t u11 = *(const uint32_t*)(src8 + (((uint32_t)i2.w << 7) + l4));
        uint32_t u12 = *(const uint32_t*)(src8 + (((uint32_t)i3.x << 7) + l4));
        uint32_t u13 = *(const uint32_t*)(src8 + (((uint32_t)i3.y << 7) + l4));
        uint32_t u14 = *(const uint32_t*)(src8 + (((uint32_t)i3.z << 7) + l4));
        uint32_t u15 = *(const uint32_t*)(src8 + (((uint32_t)i3.w << 7) + l4));
        ACC4(u0) ACC4(u1) ACC4(u2) ACC4(u3) ACC4(u4) ACC4(u5) ACC4(u6) ACC4(u7)
        ACC4(u8) ACC4(u9) ACC4(u10) ACC4(u11) ACC4(u12) ACC4(u13) ACC4(u14) ACC4(u15)
    }
    // masked tail (<16 edges), aligned idx loads with clamped indices
    if (e < re1) {
        int4 i0 = *(const int4*)(col_idx + e);
        int4 i1 = *(const int4*)(col_idx + e + 4);
        int4 i2 = *(const int4*)(col_idx + e + 8);
        int4 i3 = *(const int4*)(col_idx + e + 12);
        bool k0  = e + 0  < re1, k1  = e + 1  < re1, k2  = e + 2  < re1, k3  = e + 3  < re1;
        bool k4  = e + 4  < re1, k5  = e + 5  < re1, k6  = e + 6  < re1, k7  = e + 7  < re1;
        bool k8  = e + 8  < re1, k9  = e + 9  < re1, k10 = e + 10 < re1, k11 = e + 11 < re1;
        bool k12 = e + 12 < re1, k13 = e + 13 < re1, k14 = e + 14 < re1, k15 = e + 15 < re1;
        int r0  = k0  ? i0.x : 0, r1  = k1  ? i0.y : 0, r2  = k2  ? i0.z : 0, r3  = k3  ? i0.w : 0;
        int r4  = k4  ? i1.x : 0, r5  = k5  ? i1.y : 0, r6  = k6  ? i1.z : 0, r7  = k7  ? i1.w : 0;
        int r8  = k8  ? i2.x : 0, r9  = k9  ? i2.y : 0, r10 = k10 ? i2.z : 0, r11 = k11 ? i2.w : 0;
        int r12 = k12 ? i3.x : 0, r13 = k13 ? i3.y : 0, r14 = k14 ? i3.z : 0, r15 = k15 ? i3.w : 0;
        uint32_t u0  = *(const uint32_t*)(src8 + (((uint32_t)r0  << 7) + l4));
        uint32_t u1  = *(const uint32_t*)(src8 + (((uint32_t)r1  << 7) + l4));
        uint32_t u2  = *(const uint32_t*)(src8 + (((uint32_t)r2  << 7) + l4));
        uint32_t u3  = *(const uint32_t*)(src8 + (((uint32_t)r3  << 7) + l4));
        uint32_t u4  = *(const uint32_t*)(src8 + (((uint32_t)r4  << 7) + l4));
        uint32_t u5  = *(const uint32_t*)(src8 + (((uint32_t)r5  << 7) + l4));
        uint32_t u6  = *(const uint32_t*)(src8 + (((uint32_t)r6  << 7) + l4));
        uint32_t u7  = *(const uint32_t*)(src8 + (((uint32_t)r7  << 7) + l4));
        uint32_t u8  = *(const uint32_t*)(src8 + (((uint32_t)r8  << 7) + l4));
        uint32_t u9  = *(const uint32_t*)(src8 + (((uint32_t)r9  << 7) + l4));
        uint32_t u10 = *(const uint32_t*)(src8 + (((uint32_t)r10 << 7) + l4));
        uint32_t u11 = *(const uint32_t*)(src8 + (((uint32_t)r11 << 7) + l4));
        uint32_t u12 = *(const uint32_t*)(src8 + (((uint32_t)r12 << 7) + l4));
        uint32_t u13 = *(const uint32_t*)(src8 + (((uint32_t)r13 << 7) + l4));
        uint32_t u14 = *(const uint32_t*)(src8 + (((uint32_t)r14 << 7) + l4));
        uint32_t u15 = *(const uint32_t*)(src8 + (((uint32_t)r15 << 7) + l4));
        u0  = k0  ? u0  : 0u; u1  = k1  ? u1  : 0u; u2  = k2  ? u2  : 0u; u3  = k3  ? u3  : 0u;
        u4  = k4  ? u4  : 0u; u5  = k5  ? u5  : 0u; u6  = k6  ? u6  : 0u; u7  = k7  ? u7  : 0u;
        u8  = k8  ? u8  : 0u; u9  = k9  ? u9  : 0u; u10 = k10 ? u10 : 0u; u11 = k11 ? u11 : 0u;
        u12 = k12 ? u12 : 0u; u13 = k13 ? u13 : 0u; u14 = k14 ? u14 : 0u; u15 = k15 ? u15 : 0u;
        ACC4(u0) ACC4(u1) ACC4(u2) ACC4(u3) ACC4(u4) ACC4(u5) ACC4(u6) ACC4(u7)
        ACC4(u8) ACC4(u9) ACC4(u10) ACC4(u11) ACC4(u12) ACC4(u13) ACC4(u14) ACC4(u15)
    }
    if (valid) {
        bf16x4v o;
        o[0] = (bf16)(a0 * inv); o[1] = (bf16)(a1 * inv);
        o[2] = (bf16)(a2 * inv); o[3] = (bf16)(a3 * inv);
        *(bf16x4v*)(dst + (size_t)node * 128 + (sl << 2)) = o;
    }
}

// ---- MFMA GEMM v7: B staged to LDS ONCE; A fragments stream global->VGPR. ----
template<int CH, bool STATS, int NT>
__global__ __launch_bounds__(256) void k_gemm7(
    const bf16* __restrict__ A1, const bf16* __restrict__ A2, const bf16* __restrict__ Bt,
    const float* __restrict__ bias, bf16* __restrict__ outH,
    fp8* __restrict__ yl8, bf16* __restrict__ yrbf, float* __restrict__ stats, int M) {
    __shared__ __attribute__((aligned(16))) bf16 sB[CH * NT * 512];
    __shared__ float scol[128], scol2[128];
    constexpr int LDB = CH * 32;             // Bt leading dim (elements)
    const int tid = threadIdx.x;
    const int w = tid >> 6, l = tid & 63;
    const int q = l >> 4, r = l & 15;
    const int r0 = blockIdx.x * 128;
    if (STATS && tid < 128) { scol[tid] = 0.f; scol2[tid] = 0.f; }

    // stage ALL of B once: CH chunks x NT col-tiles, tile layout = fragment order
    #pragma unroll
    for (int c = 0; c < CH; ++c) {
        #pragma unroll
        for (int i = 0; i < 2; ++i) {
            const int T = w * 2 + i;
            if (T < NT) {
                const bf16* gb = Bt + (T * 16 + r) * LDB + c * 32 + q * 8;
                __builtin_amdgcn_global_load_lds((AS1 uint32_t*)(uintptr_t)gb,
                    (AS3 uint32_t*)(uint32_t)(uintptr_t)(&sB[(c * NT + T) * 512]), 16, 0, 0);
            }
        }
    }

    const uint32_t aoff = ((uint32_t)(r0 + w * 32 + r) << 7) + (uint32_t)(q << 3);
    const bf16* pa0_1 = A1 + aoff;                 // row-tile w*2
    const bf16* pa1_1 = A1 + aoff + 16 * 128;      // row-tile w*2+1
    const bf16* pa0_2 = A2 + aoff;
    const bf16* pa1_2 = A2 + aoff + 16 * 128;

    f32x4 acc[2][NT];
    #pragma unroll
    for (int i = 0; i < 2; ++i)
        #pragma unroll
        for (int j = 0; j < NT; ++j) { acc[i][j][0] = 0.f; acc[i][j][1] = 0.f; acc[i][j][2] = 0.f; acc[i][j][3] = 0.f; }

    __syncthreads();                 // one drain: all of B landed; read-only after

    #pragma unroll
    for (int c = 0; c < CH; ++c) {
        const bf16* p0 = (c < 4) ? pa0_1 : pa0_2;
        const bf16* p1 = (c < 4) ? pa1_1 : pa1_2;
        const int ka = (c & 3) * 32;
        bf16x8 af0 = *(const bf16x8*)(p0 + ka);    // direct global->VGPR fragment
        bf16x8 af1 = *(const bf16x8*)(p1 + ka);
        #pragma unroll
        for (int ct = 0; ct < NT; ++ct) {
            bf16x8 bv = *(const bf16x8*)&sB[(c * NT + ct) * 512 + q * 128 + r * 8];
            acc[0][ct] = __builtin_amdgcn_mfma_f32_16x16x32_bf16(af0, bv, acc[0][ct], 0, 0, 0);
            acc[1][ct] = __builtin_amdgcn_mfma_f32_16x16x32_bf16(af1, bv, acc[1][ct], 0, 0, 0);
        }
    }

    if (STATS) {
        #pragma unroll
        for (int ct = 0; ct < NT; ++ct) {
            int col = ct * 16 + r;
            float bv = bias ? bias[col] : 0.f;
            float s_c = 0.f, q_c = 0.f;
            #pragma unroll
            for (int rt = 0; rt < 2; ++rt) {
                #pragma unroll
                for (int j = 0; j < 4; ++j) {
                    int row = r0 + w * 32 + rt * 16 + q * 4 + j;
                    if (row < M) {
                        float v = acc[rt][ct][j] + bv;
                        outH[(size_t)row * 128 + col] = (bf16)v;
                        s_c += v; q_c += v * v;
                    }
                }
            }
            atomicAdd(&scol[col], s_c);
            atomicAdd(&scol2[col], q_c);
        }
        __syncthreads();
        float* sbase = stats + ((blockIdx.x & (NCOPY - 1)) << 8);
        if (tid < 128) {
            atomicAdd(&sbase[tid], scol[tid]);
            atomicAdd(&sbase[128 + tid], scol2[tid]);
        }
    } else {
        #pragma unroll
        for (int rt = 0; rt < 2; ++rt) {
            #pragma unroll
            for (int ct = 0; ct < NT; ++ct) {
                int col = ct * 16 + r;
                #pragma unroll
                for (int j = 0; j < 4; ++j) {
                    int row = r0 + w * 32 + rt * 16 + q * 4 + j;
                    if (row >= M) continue;
                    if (col < 47)      yl8[(size_t)row * 64 + col] = fp8(acc[rt][ct][j]);
                    else if (col < 94) yrbf[(size_t)row * 48 + (col - 47)] = (bf16)acc[rt][ct][j];
                }
            }
        }
    }
}

// ---- tiny BN prep: collapse NCOPY striped stats, compute scale/shift per col. ----
__global__ void k_bn_prep(const float* __restrict__ sums, const float* __restrict__ gma,
                          const float* __restrict__ bta, float* __restrict__ scsh, int n) {
    int col = threadIdx.x;               // 128 threads
    float s = 0.f, q = 0.f;
    #pragma unroll
    for (int cpy = 0; cpy < NCOPY; ++cpy) {
        s += sums[(cpy << 8) + col];
        q += sums[(cpy << 8) + 128 + col];
    }
    float invn = 1.0f / (float)n;
    float mu = s * invn;
    float var = q * invn - mu * mu;
    float sc = gma[col] * rsqrtf(var + BN_EPS);
    scsh[col] = sc;
    scsh[128 + col] = bta[col] - mu * sc;
}

// ---- BN apply + ReLU (bf16x4 8B loads — G13 vectorization; 4 cols/thread) ----
__global__ void k_bn_apply(const bf16* __restrict__ h, const float* __restrict__ scsh,
                           bf16* __restrict__ out, unsigned char* __restrict__ out8, int n) {
    int g = blockIdx.x * blockDim.x + threadIdx.x;
    int row = g >> 5, c4 = g & 31;
    if (row >= n) return;
    int col = c4 << 2;
    float4 sc = *(const float4*)(scsh + col);
    float4 sh = *(const float4*)(scsh + 128 + col);
    bf16x4v hv = *(const bf16x4v*)(h + (size_t)row * 128 + col);
    float r0 = fmaxf((float)hv[0] * sc.x + sh.x, 0.f);
    float r1 = fmaxf((float)hv[1] * sc.y + sh.y, 0.f);
    float r2 = fmaxf((float)hv[2] * sc.z + sh.z, 0.f);
    float r3 = fmaxf((float)hv[3] * sc.w + sh.w, 0.f);
    bf16x4v o; o[0] = (bf16)r0; o[1] = (bf16)r1; o[2] = (bf16)r2; o[3] = (bf16)r3;
    *(bf16x4v*)(out + (size_t)row * 128 + col) = o;
    uchar4 o8; o8.x = fp8(r0).__x; o8.y = fp8(r1).__x; o8.z = fp8(r2).__x; o8.w = fp8(r3).__x;
    *(uchar4*)(out8 + (size_t)row * 128 + col) = o8;
}

// ---- final: gather-mean of yl (fp8, 64B line/edge) + yr + bl2, log_softmax.
//      TWO nodes per wave (half = 32 lanes: sub = edge slot, c4 = feat group)
//      -> per-node fixed costs (softmax epilogue, tail masking) halve per wave.
//      Wave-uniform loop over max(degA,degB): unmasked fast path for common
//      full batches, value-clamped masked batches for the rest (R10 idiom). ----
__global__ void k_final(const unsigned char* __restrict__ yl, const bf16* __restrict__ yr,
                        const int* __restrict__ row_ptr, const int* __restrict__ col_idx,
                        const float* __restrict__ inv_deg, const float* __restrict__ bl2,
                        float* __restrict__ out, int n) {
    const int lane = threadIdx.x & 63;
    const int half = lane >> 5;
    const int sl = lane & 31;
    const int sub = sl >> 4;                 // edge slot within pair
    const int c4 = sl & 15;                  // feature group: feats 4*c4..+3
    const int node = blockIdx.x * 8 + ((threadIdx.x >> 6) << 1) + half;
    const bool valid = node < n;
    const int nn = valid ? node : 0;
    const int re0 = row_ptr[nn];
    const int re1 = valid ? row_ptr[nn + 1] : re0;
    const float inv = inv_deg[nn];
    const uint32_t loff = (uint32_t)(c4 << 2);
    int deg = re1 - re0;
    int dother = __shfl_xor(deg, 32, 64);
    int nfull = (deg < dother ? deg : dother) >> 4;       // uniform across wave
    int nb = (((deg > dother ? deg : dother) + 15) >> 4); // uniform across wave
    float a0 = 0.f, a1 = 0.f, a2 = 0.f, a3 = 0.f;
    int rbase = re0;
    int t = 0;
    // unmasked full batches (both nodes have >= 16 edges remaining)
    for (; t < nfull; ++t, rbase += 16) {
        int i0 = col_idx[rbase + 0  + sub];
        int i1 = col_idx[rbase + 2  + sub];
        int i2 = col_idx[rbase + 4  + sub];
        int i3 = col_idx[rbase + 6  + sub];
        int i4 = col_idx[rbase + 8  + sub];
        int i5 = col_idx[rbase + 10 + sub];
        int i6 = col_idx[rbase + 12 + sub];
        int i7 = col_idx[rbase + 14 + sub];
        uint32_t u0 = *(const uint32_t*)(yl + (((uint32_t)i0 << 6) + loff));
        uint32_t u1 = *(const uint32_t*)(yl + (((uint32_t)i1 << 6) + loff));
        uint32_t u2 = *(const uint32_t*)(yl + (((uint32_t)i2 << 6) + loff));
        uint32_t u3 = *(const uint32_t*)(yl + (((uint32_t)i3 << 6) + loff));
        uint32_t u4 = *(const uint32_t*)(yl + (((uint32_t)i4 << 6) + loff));
        uint32_t u5 = *(const uint32_t*)(yl + (((uint32_t)i5 << 6) + loff));
        uint32_t u6 = *(const uint32_t*)(yl + (((uint32_t)i6 << 6) + loff));
        uint32_t u7 = *(const uint32_t*)(yl + (((uint32_t)i7 << 6) + loff));
        ACC4(u0) ACC4(u1) ACC4(u2) ACC4(u3) ACC4(u4) ACC4(u5) ACC4(u6) ACC4(u7)
    }
    // masked batches (value-clamped, address stays in-bounds)
    for (; t < nb; ++t, rbase += 16) {
        int ee0 = rbase + 0  + sub, ee1 = rbase + 2  + sub;
        int ee2 = rbase + 4  + sub, ee3 = rbase + 6  + sub;
        int ee4 = rbase + 8  + sub, ee5 = rbase + 10 + sub;
        int ee6 = rbase + 12 + sub, ee7 = rbase + 14 + sub;
        bool k0 = ee0 < re1, k1 = ee1 < re1, k2 = ee2 < re1, k3 = ee3 < re1;
        bool k4 = ee4 < re1, k5 = ee5 < re1, k6 = ee6 < re1, k7 = ee7 < re1;
        int i0 = col_idx[k0 ? ee0 : re0];
        int i1 = col_idx[k1 ? ee1 : re0];
        int i2 = col_idx[k2 ? ee2 : re0];
        int i3 = col_idx[k3 ? ee3 : re0];
        int i4 = col_idx[k4 ? ee4 : re0];
        int i5 = col_idx[k5 ? ee5 : re0];
        int i6 = col_idx[k6 ? ee6 : re0];
        int i7 = col_idx[k7 ? ee7 : re0];
        uint32_t u0 = *(const uint32_t*)(yl + (((uint32_t)i0 << 6) + loff));
        uint32_t u1 = *(const uint32_t*)(yl + (((uint32_t)i1 << 6) + loff));
        uint32_t u2 = *(const uint32_t*)(yl + (((uint32_t)i2 << 6) + loff));
        uint32_t u3 = *(const uint32_t*)(yl + (((uint32_t)i3 << 6) + loff));
        uint32_t u4 = *(const uint32_t*)(yl + (((uint32_t)i4 << 6) + loff));
        uint32_t u5 = *(const uint32_t*)(yl + (((uint32_t)i5 << 6) + loff));
        uint32_t u6 = *(const uint32_t*)(yl + (((uint32_t)i6 << 6) + loff));
        uint32_t u7 = *(const uint32_t*)(yl + (((uint32_t)i7 << 6) + loff));
        u0 = k0 ? u0 : 0u; u1 = k1 ? u1 : 0u; u2 = k2 ? u2 : 0u; u3 = k3 ? u3 : 0u;
        u4 = k4 ? u4 : 0u; u5 = k5 ? u5 : 0u; u6 = k6 ? u6 : 0u; u7 = k7 ? u7 : 0u;
        ACC4(u0) ACC4(u1) ACC4(u2) ACC4(u3) ACC4(u4) ACC4(u5) ACC4(u6) ACC4(u7)
    }
    // sum the 2 edge subgroups within each half (lanes differ in bit 4)
    a0 += __shfl_xor(a0, 16, 64); a1 += __shfl_xor(a1, 16, 64);
    a2 += __shfl_xor(a2, 16, 64); a3 += __shfl_xor(a3, 16, 64);
    const int f0 = c4 << 2;
    // yr: one 8-byte load (nn*96 + 8*c4 is 8B-aligned)
    bf16x4v yv4 = *(const bf16x4v*)(yr + (size_t)nn * 48 + f0);
    float v0 = (f0 + 0 < 47) ? fmaf(a0, inv, (float)yv4[0] + bl2[f0 + 0]) : -__builtin_inff();
    float v1 = (f0 + 1 < 47) ? fmaf(a1, inv, (float)yv4[1] + bl2[f0 + 1]) : -__builtin_inff();
    float v2 = (f0 + 2 < 47) ? fmaf(a2, inv, (float)yv4[2] + bl2[f0 + 2]) : -__builtin_inff();
    float v3 = (f0 + 3 < 47) ? fmaf(a3, inv, (float)yv4[3] + bl2[f0 + 3]) : -__builtin_inff();
    float m = fmaxf(fmaxf(v0, v1), fmaxf(v2, v3));
    #pragma unroll
    for (int o = 1; o < 16; o <<= 1) m = fmaxf(m, __shfl_xor(m, o, 64));
    float ex0 = (f0 + 0 < 47) ? __expf(v0 - m) : 0.f;
    float ex1 = (f0 + 1 < 47) ? __expf(v1 - m) : 0.f;
    float ex2 = (f0 + 2 < 47) ? __expf(v2 - m) : 0.f;
    float ex3 = (f0 + 3 < 47) ? __expf(v3 - m) : 0.f;
    float s = (ex0 + ex1) + (ex2 + ex3);
    #pragma unroll
    for (int o = 1; o < 16; o <<= 1) s += __shfl_xor(s, o, 64);
    float ls = __logf(s);
    if (valid && sl < 16) {
        float* op = out + (size_t)node * 47 + f0;
        if (f0 + 0 < 47) op[0] = v0 - m - ls;
        if (f0 + 1 < 47) op[1] = v1 - m - ls;
        if (f0 + 2 < 47) op[2] = v2 - m - ls;
        if (f0 + 3 < 47) op[3] = v3 - m - ls;
    }
}
#undef ACC4

extern "C" void kernel_launch(void* const* d_in, const int* in_sizes, int n_in,
                              void* d_out, int out_size, void* d_ws, size_t ws_size,
                              hipStream_t stream) {
    const float* x   = (const float*)d_in[0];
    const int*   ei  = (const int*)d_in[1];
    const float* Wl0 = (const float*)d_in[2];
    const float* bl0 = (const float*)d_in[3];
    const float* Wr0 = (const float*)d_in[4];
    const float* g0  = (const float*)d_in[5];
    const float* be0 = (const float*)d_in[6];
    const float* Wl1 = (const float*)d_in[7];
    const float* bl1 = (const float*)d_in[8];
    const float* Wr1 = (const float*)d_in[9];
    const float* g1  = (const float*)d_in[10];
    const float* be1 = (const float*)d_in[11];
    const float* Wl2 = (const float*)d_in[12];
    const float* bl2 = (const float*)d_in[13];
    const float* Wr2 = (const float*)d_in[14];
    float* out = (float*)d_out;

    const int N  = in_sizes[0] / 128;
    const int E  = in_sizes[1] / 2;
    const int NP = ((N + 127) / 128) * 128;
    const int NBKT = (N + BKT_NODES - 1) / BKT_NODES;

    char* p = (char*)d_ws;
    size_t off = 0;
    auto alloc = [&](size_t b) { char* r = p + off; off += (b + 255) & ~(size_t)255; return r; };
    // zero-init region (one memset): bfill, bnsum (2 layers x NCOPY x 256), btot
    int*   bfill   = (int*)alloc(1024 * 4);
    float* bnsum   = (float*)alloc(2 * NCOPY * 256 * 4);
    int*   btot    = (int*)alloc(512 * 4);
    size_t zero_span = off;
    float* scsh    = (float*)alloc(2 * 256 * 4);   // per-layer scale/shift tables
    int*   row_ptr = (int*)alloc((size_t)(N + 1) * 4);
    float* invd    = (float*)alloc((size_t)N * 4);
    int*   col_idx = (int*)alloc((size_t)E * 4);
    uint32_t* pair_buf = (uint32_t*)alloc((size_t)E * 4);
    bf16*  x_bf    = (bf16*)alloc((size_t)NP * 128 * 2);
    bf16*  aggbf   = (bf16*)alloc((size_t)NP * 128 * 2);
    bf16*  hbf     = (bf16*)alloc((size_t)NP * 128 * 2);
    unsigned char* h8 = (unsigned char*)alloc((size_t)NP * 128);
    float* bufF    = (float*)alloc((size_t)NP * 128 * 4 + 256);
    bf16*  Bt0     = (bf16*)alloc(128 * 256 * 2);
    bf16*  Bt1     = (bf16*)alloc(128 * 256 * 2);
    bf16*  Bt2     = (bf16*)alloc(128 * 128 * 2);
    // aliases into bufF (sequentially dead/live): x8 (pre-GEMM0), hraw (bf16 h,
    // GEMM->bn_apply), yl8/yrbf (post-BN1)
    unsigned char* x8 = (unsigned char*)bufF;
    bf16*  hraw = (bf16*)bufF;
    fp8*   yl8  = (fp8*)bufF;
    bf16*  yrbf = (bf16*)((char*)bufF + (size_t)NP * 64);

    hipMemsetAsync(bfill, 0, zero_span, stream);

    int n4 = N * 128 / 4;
    k_setup<<<(n4 + 255) / 256, 256, 0, stream>>>(x, x_bf, x8, n4, ei, btot, E, NBKT,
                                                  Wl0, Wr0, Wl1, Wr1, Wl2, Wr2, Bt0, Bt1, Bt2);
    k_bin<<<(E + TILE_E - 1) / TILE_E, 256, 0, stream>>>(ei, btot, bfill, pair_buf, E, NBKT);
    k_fill2<<<NBKT, 256, 0, stream>>>(pair_buf, btot, row_ptr, invd, col_idx, N, E, NBKT);

    int aggBlocks  = (N + 7) / 8;     // 2 nodes per wave, 4 waves per block
    int gemmBlocks = NP / 128;
    int bnBlocks   = (N * 32 + 255) / 256;
    int finBlocks  = (N + 7) / 8;

    // Layer 0
    k_aggregate<<<aggBlocks, 256, 0, stream>>>(x8, aggbf, row_ptr, col_idx, invd, N);
    k_gemm7<8, true, 8><<<gemmBlocks, 256, 0, stream>>>(aggbf, x_bf, Bt0, bl0, hraw, nullptr, nullptr, bnsum, N);
    k_bn_prep<<<1, 128, 0, stream>>>(bnsum, g0, be0, scsh, N);
    k_bn_apply<<<bnBlocks, 256, 0, stream>>>(hraw, scsh, hbf, h8, N);
    // Layer 1
    k_aggregate<<<aggBlocks, 256, 0, stream>>>(h8, aggbf, row_ptr, col_idx, invd, N);
    k_gemm7<8, true, 8><<<gemmBlocks, 256, 0, stream>>>(aggbf, hbf, Bt1, bl1, hraw, nullptr, nullptr, bnsum + NCOPY * 256, N);
    k_bn_prep<<<1, 128, 0, stream>>>(bnsum + NCOPY * 256, g1, be1, scsh + 256, N);
    k_bn_apply<<<bnBlocks, 256, 0, stream>>>(hraw, scsh + 256, hbf, h8, N);
    // Layer 2: project to yl (fp8, stride 64) / yr (bf16), then gather + log_softmax
    k_gemm7<4, false, 6><<<gemmBlocks, 256, 0, stream>>>(hbf, hbf, Bt2, nullptr, nullptr, yl8, yrbf, nullptr, N);
    k_final<<<finBlocks, 256, 0, stream>>>((const unsigned char*)yl8, yrbf, row_ptr, col_idx, invd, bl2, out, N);
}

// Round 13
// 418.181 us; speedup vs baseline: 1.5772x; 1.0136x over previous
//
#include <hip/hip_runtime.h>
#include <hip/hip_fp8.h>
#include <stdint.h>

#define AS1 __attribute__((address_space(1)))
#define AS3 __attribute__((address_space(3)))

typedef __bf16 bf16;
typedef __bf16 bf16x2 __attribute__((ext_vector_type(2)));
typedef __bf16 bf16x4v __attribute__((ext_vector_type(4)));
typedef __bf16 bf16x8 __attribute__((ext_vector_type(8)));
typedef float f32x4 __attribute__((ext_vector_type(4)));
typedef float f32x2 __attribute__((ext_vector_type(2)));
typedef __hip_fp8_e4m3 fp8;

#define BN_EPS 1e-5f
#define BKT_SHIFT 8              // 256 nodes per bucket
#define BKT_NODES 256
#define TILE_E 8192              // edges per binning block (claim de-contention)
#define NCOPY 16                 // striped stats copies (atomic de-contention)

// ---- fused setup: weight cvt+transpose, x fp32 -> bf16 + fp8, bucket count ----
__global__ void k_setup(const float* __restrict__ x, bf16* __restrict__ x_bf,
                        unsigned char* __restrict__ x8, int n4,
                        const int* __restrict__ ei, int* __restrict__ btot, int E, int nbkt,
                        const float* __restrict__ Wl0, const float* __restrict__ Wr0,
                        const float* __restrict__ Wl1, const float* __restrict__ Wr1,
                        const float* __restrict__ Wl2, const float* __restrict__ Wr2,
                        bf16* __restrict__ Bt0, bf16* __restrict__ Bt1, bf16* __restrict__ Bt2) {
    __shared__ int hist[512];
    const int tid = threadIdx.x;
    int g = blockIdx.x * 256 + tid;
    if (g < n4) {
        float4 v = ((const float4*)x)[g];
        bf16x4v o; o[0] = (bf16)v.x; o[1] = (bf16)v.y; o[2] = (bf16)v.z; o[3] = (bf16)v.w;
        ((bf16x4v*)x_bf)[g] = o;
        uchar4 o8;
        o8.x = fp8(v.x).__x; o8.y = fp8(v.y).__x; o8.z = fp8(v.z).__x; o8.w = fp8(v.w).__x;
        ((uchar4*)x8)[g] = o8;
    }
    if (blockIdx.x < 128) {
        int idx = g;                 // 32768 threads: c in [0,128), k in [0,256)
        int c = idx >> 8, k = idx & 255;
        float v0 = (k < 128) ? Wl0[k * 128 + c] : Wr0[(k - 128) * 128 + c];
        Bt0[c * 256 + k] = (bf16)v0;
        float v1 = (k < 128) ? Wl1[k * 128 + c] : Wr1[(k - 128) * 128 + c];
        Bt1[c * 256 + k] = (bf16)v1;
        if (k < 128) {
            float v2 = 0.f;
            if (c < 47)      v2 = Wl2[k * 47 + c];
            else if (c < 94) v2 = Wr2[k * 47 + (c - 47)];
            Bt2[c * 128 + k] = (bf16)v2;
        }
    }
    // bucket histogram for blocks [0, ceil(E/4096))
    int nbinb = (E + 4095) / 4096;
    if (blockIdx.x < nbinb) {
        hist[tid] = 0; hist[tid + 256] = 0;
        __syncthreads();
        const int e0 = blockIdx.x * 4096;
        #pragma unroll
        for (int k = 0; k < 4; ++k) {
            int i4 = (e0 >> 2) + k * 256 + tid;
            if (i4 * 4 + 3 < E) {
                int4 d4 = ((const int4*)(ei + E))[i4];
                atomicAdd(&hist[d4.x >> BKT_SHIFT], 1);
                atomicAdd(&hist[d4.y >> BKT_SHIFT], 1);
                atomicAdd(&hist[d4.z >> BKT_SHIFT], 1);
                atomicAdd(&hist[d4.w >> BKT_SHIFT], 1);
            } else {
                for (int e = i4 * 4; e < min(E, i4 * 4 + 4); ++e)
                    atomicAdd(&hist[ei[E + e] >> BKT_SHIFT], 1);
            }
        }
        __syncthreads();
        for (int b = tid; b < nbkt; b += 256)
            if (hist[b]) atomicAdd(&btot[b], hist[b]);
    }
}

// In-block exclusive scan of btot[0..512) into sb[0..512], sb[512]=total.
__device__ __forceinline__ void scan_btot(const int* __restrict__ btot, int nbkt,
                                          int* sb, int* wsum) {
    const int tid = threadIdx.x, lane = tid & 63, wid = tid >> 6;
    int a = (tid < nbkt) ? btot[tid] : 0;
    int b2 = (tid + 256 < nbkt) ? btot[tid + 256] : 0;
    int ia = a, ib = b2;
    #pragma unroll
    for (int d = 1; d < 64; d <<= 1) {
        int t1 = __shfl_up(ia, d, 64);
        int t2 = __shfl_up(ib, d, 64);
        if (lane >= d) { ia += t1; ib += t2; }
    }
    if (lane == 63) { wsum[wid] = ia; wsum[4 + wid] = ib; }
    __syncthreads();
    if (tid == 0) {
        int c = 0;
        #pragma unroll
        for (int i = 0; i < 8; ++i) { int t = wsum[i]; wsum[i] = c; c += t; }
    }
    __syncthreads();
    sb[tid] = ia - a + wsum[wid];
    sb[tid + 256] = ib - b2 + wsum[4 + wid];
    if (tid == 255) sb[512] = ib + wsum[7];
    __syncthreads();
}

// ---- binning pass: in-block bbase scan -> histogram -> claim -> ranked write ----
__global__ __launch_bounds__(256) void k_bin(const int* __restrict__ ei,
                                             const int* __restrict__ btot,
                                             int* __restrict__ bfill,
                                             uint32_t* __restrict__ pair_buf,
                                             int E, int nbkt) {
    __shared__ int hist[512], gbase[512], hcur[512];
    __shared__ int sb[513], wsum[8];
    const int tid = threadIdx.x;
    const int e0 = blockIdx.x * TILE_E;
    hist[tid] = 0; hist[tid + 256] = 0;
    scan_btot(btot, nbkt, sb, wsum);   // includes syncs; hist zeroed before first sync

    int dreg[TILE_E / 256];
    #pragma unroll
    for (int k = 0; k < TILE_E / 256; ++k) {
        int e = e0 + k * 256 + tid;
        int d = (e < E) ? ei[E + e] : -1;
        dreg[k] = d;
        if (d >= 0) atomicAdd(&hist[d >> BKT_SHIFT], 1);
    }
    __syncthreads();

    for (int b = tid; b < nbkt; b += 256) {
        int h = hist[b];
        int g = (h > 0) ? atomicAdd(&bfill[b], h) : 0;
        gbase[b] = sb[b] + g;
        hcur[b] = 0;
    }
    __syncthreads();

    #pragma unroll
    for (int k = 0; k < TILE_E / 256; ++k) {
        int d = dreg[k];
        if (d >= 0) {
            int e = e0 + k * 256 + tid;
            int s = ei[e];
            int b = d >> BKT_SHIFT;
            int r = atomicAdd(&hcur[b], 1);
            pair_buf[(size_t)gbase[b] + r] =
                ((uint32_t)s << BKT_SHIFT) | (uint32_t)(d & (BKT_NODES - 1));
        }
    }
}

// ---- fill: one block per bucket ----
__global__ __launch_bounds__(256) void k_fill2(const uint32_t* __restrict__ pair_buf,
                                               const int* __restrict__ btot,
                                               int* __restrict__ row_ptr,
                                               float* __restrict__ inv_deg,
                                               int* __restrict__ col_idx,
                                               int n, int E, int nbkt) {
    __shared__ int hist[256], excl[256], hcur[256], wsum4[4];
    __shared__ int sb[513], wsum[8];
    const int b = blockIdx.x;
    const int tid = threadIdx.x, lane = tid & 63, wid = tid >> 6;
    const int n0 = b << BKT_SHIFT;
    hist[tid] = 0; hcur[tid] = 0;
    scan_btot(btot, nbkt, sb, wsum);
    const int s = sb[b], e = sb[b + 1];
    for (int i = s + tid; i < e; i += 256)
        atomicAdd(&hist[pair_buf[i] & (BKT_NODES - 1)], 1);
    __syncthreads();
    int v = hist[tid];
    int incl = v;
    #pragma unroll
    for (int d = 1; d < 64; d <<= 1) {
        int t = __shfl_up(incl, d, 64);
        if (lane >= d) incl += t;
    }
    if (lane == 63) wsum4[wid] = incl;
    __syncthreads();
    if (tid == 0) {
        int c = 0;
        #pragma unroll
        for (int i = 0; i < 4; ++i) { int t = wsum4[i]; wsum4[i] = c; c += t; }
    }
    __syncthreads();
    int ex = incl - v + wsum4[wid];
    excl[tid] = ex;
    int node = n0 + tid;
    if (node < n) {
        row_ptr[node] = s + ex;
        inv_deg[node] = 1.0f / (float)(v > 1 ? v : 1);
    }
    if (b == (int)gridDim.x - 1 && tid == 0) row_ptr[n] = E;
    __syncthreads();
    for (int i = s + tid; i < e; i += 256) {
        uint32_t pk = pair_buf[i];
        int dl = pk & (BKT_NODES - 1);
        int r = atomicAdd(&hcur[dl], 1);
        col_idx[s + excl[dl] + r] = (int)(pk >> BKT_SHIFT);
    }
}

// ---- mean-aggregate from fp8 table (128 B/row), two nodes per wave. ----
#define ACC4(u) { f32x2 pl_ = __builtin_amdgcn_cvt_pk_f32_fp8(u, false); \
                  f32x2 ph_ = __builtin_amdgcn_cvt_pk_f32_fp8(u, true);  \
                  a0 += pl_[0]; a1 += pl_[1]; a2 += ph_[0]; a3 += ph_[1]; }
__global__ void k_aggregate(const unsigned char* __restrict__ src8, bf16* __restrict__ dst,
                            const int* __restrict__ row_ptr, const int* __restrict__ col_idx,
                            const float* __restrict__ inv_deg, int n) {
    const int lane = threadIdx.x & 63;
    const int half = lane >> 5;
    const int sl = lane & 31;
    const int node = blockIdx.x * 8 + ((threadIdx.x >> 6) << 1) + half;
    const bool valid = node < n;
    const int nn = valid ? node : 0;
    const int re0 = row_ptr[nn];
    const int re1 = valid ? row_ptr[nn + 1] : re0;
    const float inv = inv_deg[nn];
    const uint32_t l4 = (uint32_t)(sl << 2);
    float a0 = 0.f, a1 = 0.f, a2 = 0.f, a3 = 0.f;
    int e = re0;
    // align to 4 for int4 idx loads (<=3 scalar edges)
    for (; e < re1 && (e & 3); ++e) {
        uint32_t u = *(const uint32_t*)(src8 + (((uint32_t)col_idx[e] << 7) + l4));
        ACC4(u)
    }
    // full 16-edge batches: 4 idx loads + 16 independent gathers in flight
    for (; e + 16 <= re1; e += 16) {
        int4 i0 = *(const int4*)(col_idx + e);
        int4 i1 = *(const int4*)(col_idx + e + 4);
        int4 i2 = *(const int4*)(col_idx + e + 8);
        int4 i3 = *(const int4*)(col_idx + e + 12);
        uint32_t u0  = *(const uint32_t*)(src8 + (((uint32_t)i0.x << 7) + l4));
        uint32_t u1  = *(const uint32_t*)(src8 + (((uint32_t)i0.y << 7) + l4));
        uint32_t u2  = *(const uint32_t*)(src8 + (((uint32_t)i0.z << 7) + l4));
        uint32_t u3  = *(const uint32_t*)(src8 + (((uint32_t)i0.w << 7) + l4));
        uint32_t u4  = *(const uint32_t*)(src8 + (((uint32_t)i1.x << 7) + l4));
        uint32_t u5  = *(const uint32_t*)(src8 + (((uint32_t)i1.y << 7) + l4));
        uint32_t u6  = *(const uint32_t*)(src8 + (((uint32_t)i1.z << 7) + l4));
        uint32_t u7  = *(const uint32_t*)(src8 + (((uint32_t)i1.w << 7) + l4));
        uint32_t u8  = *(const uint32_t*)(src8 + (((uint32_t)i2.x << 7) + l4));
        uint32_t u9  = *(const uint32_t*)(src8 + (((uint32_t)i2.y << 7) + l4));
        uint32_t u10 = *(const uint32_t*)(src8 + (((uint32_t)i2.z << 7) + l4));
        uint32_t u11 = *(const uint32_t*)(src8 + (((uint32_t)i2.w << 7) + l4));
        uint32_t u12 = *(const uint32_t*)(src8 + (((uint32_t)i3.x << 7) + l4));
        uint32_t u13 = *(const uint32_t*)(src8 + (((uint32_t)i3.y << 7) + l4));
        uint32_t u14 = *(const uint32_t*)(src8 + (((uint32_t)i3.z << 7) + l4));
        uint32_t u15 = *(const uint32_t*)(src8 + (((uint32_t)i3.w << 7) + l4));
        ACC4(u0) ACC4(u1) ACC4(u2) ACC4(u3) ACC4(u4) ACC4(u5) ACC4(u6) ACC4(u7)
        ACC4(u8) ACC4(u9) ACC4(u10) ACC4(u11) ACC4(u12) ACC4(u13) ACC4(u14) ACC4(u15)
    }
    // masked tail (<16 edges), aligned idx loads with clamped indices
    if (e < re1) {
        int4 i0 = *(const int4*)(col_idx + e);
        int4 i1 = *(const int4*)(col_idx + e + 4);
        int4 i2 = *(const int4*)(col_idx + e + 8);
        int4 i3 = *(const int4*)(col_idx + e + 12);
        bool k0  = e + 0  < re1, k1  = e + 1  < re1, k2  = e + 2  < re1, k3  = e + 3  < re1;
        bool k4  = e + 4  < re1, k5  = e + 5  < re1, k6  = e + 6  < re1, k7  = e + 7  < re1;
        bool k8  = e + 8  < re1, k9  = e + 9  < re1, k10 = e + 10 < re1, k11 = e + 11 < re1;
        bool k12 = e + 12 < re1, k13 = e + 13 < re1, k14 = e + 14 < re1, k15 = e + 15 < re1;
        int r0  = k0  ? i0.x : 0, r1  = k1  ? i0.y : 0, r2  = k2  ? i0.z : 0, r3  = k3  ? i0.w : 0;
        int r4  = k4  ? i1.x : 0, r5  = k5  ? i1.y : 0, r6  = k6  ? i1.z : 0, r7  = k7  ? i1.w : 0;
        int r8  = k8  ? i2.x : 0, r9  = k9  ? i2.y : 0, r10 = k10 ? i2.z : 0, r11 = k11 ? i2.w : 0;
        int r12 = k12 ? i3.x : 0, r13 = k13 ? i3.y : 0, r14 = k14 ? i3.z : 0, r15 = k15 ? i3.w : 0;
        uint32_t u0  = *(const uint32_t*)(src8 + (((uint32_t)r0  << 7) + l4));
        uint32_t u1  = *(const uint32_t*)(src8 + (((uint32_t)r1  << 7) + l4));
        uint32_t u2  = *(const uint32_t*)(src8 + (((uint32_t)r2  << 7) + l4));
        uint32_t u3  = *(const uint32_t*)(src8 + (((uint32_t)r3  << 7) + l4));
        uint32_t u4  = *(const uint32_t*)(src8 + (((uint32_t)r4  << 7) + l4));
        uint32_t u5  = *(const uint32_t*)(src8 + (((uint32_t)r5  << 7) + l4));
        uint32_t u6  = *(const uint32_t*)(src8 + (((uint32_t)r6  << 7) + l4));
        uint32_t u7  = *(const uint32_t*)(src8 + (((uint32_t)r7  << 7) + l4));
        uint32_t u8  = *(const uint32_t*)(src8 + (((uint32_t)r8  << 7) + l4));
        uint32_t u9  = *(const uint32_t*)(src8 + (((uint32_t)r9  << 7) + l4));
        uint32_t u10 = *(const uint32_t*)(src8 + (((uint32_t)r10 << 7) + l4));
        uint32_t u11 = *(const uint32_t*)(src8 + (((uint32_t)r11 << 7) + l4));
        uint32_t u12 = *(const uint32_t*)(src8 + (((uint32_t)r12 << 7) + l4));
        uint32_t u13 = *(const uint32_t*)(src8 + (((uint32_t)r13 << 7) + l4));
        uint32_t u14 = *(const uint32_t*)(src8 + (((uint32_t)r14 << 7) + l4));
        uint32_t u15 = *(const uint32_t*)(src8 + (((uint32_t)r15 << 7) + l4));
        u0  = k0  ? u0  : 0u; u1  = k1  ? u1  : 0u; u2  = k2  ? u2  : 0u; u3  = k3  ? u3  : 0u;
        u4  = k4  ? u4  : 0u; u5  = k5  ? u5  : 0u; u6  = k6  ? u6  : 0u; u7  = k7  ? u7  : 0u;
        u8  = k8  ? u8  : 0u; u9  = k9  ? u9  : 0u; u10 = k10 ? u10 : 0u; u11 = k11 ? u11 : 0u;
        u12 = k12 ? u12 : 0u; u13 = k13 ? u13 : 0u; u14 = k14 ? u14 : 0u; u15 = k15 ? u15 : 0u;
        ACC4(u0) ACC4(u1) ACC4(u2) ACC4(u3) ACC4(u4) ACC4(u5) ACC4(u6) ACC4(u7)
        ACC4(u8) ACC4(u9) ACC4(u10) ACC4(u11) ACC4(u12) ACC4(u13) ACC4(u14) ACC4(u15)
    }
    if (valid) {
        bf16x4v o;
        o[0] = (bf16)(a0 * inv); o[1] = (bf16)(a1 * inv);
        o[2] = (bf16)(a2 * inv); o[3] = (bf16)(a3 * inv);
        *(bf16x4v*)(dst + (size_t)node * 128 + (sl << 2)) = o;
    }
}

// ---- MFMA GEMM v8: B staged to LDS ONCE; ALL A fragments preloaded into a
//      fully-unrolled register array (2*CH independent dwordx4 loads in
//      flight before the first MFMA — forces deep memory pipelining that the
//      compiler declined at 88 VGPRs). Zero barriers in the K-loop. ----
template<int CH, bool STATS, int NT>
__global__ __launch_bounds__(256) void k_gemm8(
    const bf16* __restrict__ A1, const bf16* __restrict__ A2, const bf16* __restrict__ Bt,
    const float* __restrict__ bias, bf16* __restrict__ outH,
    fp8* __restrict__ yl8, bf16* __restrict__ yrbf, float* __restrict__ stats, int M) {
    __shared__ __attribute__((aligned(16))) bf16 sB[CH * NT * 512];
    __shared__ float scol[128], scol2[128];
    constexpr int LDB = CH * 32;             // Bt leading dim (elements)
    const int tid = threadIdx.x;
    const int w = tid >> 6, l = tid & 63;
    const int q = l >> 4, r = l & 15;
    const int r0 = blockIdx.x * 128;
    if (STATS && tid < 128) { scol[tid] = 0.f; scol2[tid] = 0.f; }

    // stage ALL of B once: CH chunks x NT col-tiles, tile layout = fragment order
    #pragma unroll
    for (int c = 0; c < CH; ++c) {
        #pragma unroll
        for (int i = 0; i < 2; ++i) {
            const int T = w * 2 + i;
            if (T < NT) {
                const bf16* gb = Bt + (T * 16 + r) * LDB + c * 32 + q * 8;
                __builtin_amdgcn_global_load_lds((AS1 uint32_t*)(uintptr_t)gb,
                    (AS3 uint32_t*)(uint32_t)(uintptr_t)(&sB[(c * NT + T) * 512]), 16, 0, 0);
            }
        }
    }

    const uint32_t aoff = ((uint32_t)(r0 + w * 32 + r) << 7) + (uint32_t)(q << 3);
    const bf16* pa0_1 = A1 + aoff;                 // row-tile w*2
    const bf16* pa1_1 = A1 + aoff + 16 * 128;      // row-tile w*2+1
    const bf16* pa0_2 = A2 + aoff;
    const bf16* pa1_2 = A2 + aoff + 16 * 128;

    // preload ALL A fragments (static indexing -> registers, rule #20)
    bf16x8 afr0[CH], afr1[CH];
    #pragma unroll
    for (int c = 0; c < CH; ++c) {
        const bf16* p0 = (c < 4) ? pa0_1 : pa0_2;
        const bf16* p1 = (c < 4) ? pa1_1 : pa1_2;
        const int ka = (c & 3) * 32;
        afr0[c] = *(const bf16x8*)(p0 + ka);
        afr1[c] = *(const bf16x8*)(p1 + ka);
    }

    f32x4 acc[2][NT];
    #pragma unroll
    for (int i = 0; i < 2; ++i)
        #pragma unroll
        for (int j = 0; j < NT; ++j) { acc[i][j][0] = 0.f; acc[i][j][1] = 0.f; acc[i][j][2] = 0.f; acc[i][j][3] = 0.f; }

    __syncthreads();                 // one drain: all of B landed; read-only after

    #pragma unroll
    for (int c = 0; c < CH; ++c) {
        #pragma unroll
        for (int ct = 0; ct < NT; ++ct) {
            bf16x8 bv = *(const bf16x8*)&sB[(c * NT + ct) * 512 + q * 128 + r * 8];
            acc[0][ct] = __builtin_amdgcn_mfma_f32_16x16x32_bf16(afr0[c], bv, acc[0][ct], 0, 0, 0);
            acc[1][ct] = __builtin_amdgcn_mfma_f32_16x16x32_bf16(afr1[c], bv, acc[1][ct], 0, 0, 0);
        }
    }

    if (STATS) {
        #pragma unroll
        for (int ct = 0; ct < NT; ++ct) {
            int col = ct * 16 + r;
            float bv = bias ? bias[col] : 0.f;
            float s_c = 0.f, q_c = 0.f;
            #pragma unroll
            for (int rt = 0; rt < 2; ++rt) {
                #pragma unroll
                for (int j = 0; j < 4; ++j) {
                    int row = r0 + w * 32 + rt * 16 + q * 4 + j;
                    if (row < M) {
                        float v = acc[rt][ct][j] + bv;
                        outH[(size_t)row * 128 + col] = (bf16)v;
                        s_c += v; q_c += v * v;
                    }
                }
            }
            atomicAdd(&scol[col], s_c);
            atomicAdd(&scol2[col], q_c);
        }
        __syncthreads();
        float* sbase = stats + ((blockIdx.x & (NCOPY - 1)) << 8);
        if (tid < 128) {
            atomicAdd(&sbase[tid], scol[tid]);
            atomicAdd(&sbase[128 + tid], scol2[tid]);
        }
    } else {
        #pragma unroll
        for (int rt = 0; rt < 2; ++rt) {
            #pragma unroll
            for (int ct = 0; ct < NT; ++ct) {
                int col = ct * 16 + r;
                #pragma unroll
                for (int j = 0; j < 4; ++j) {
                    int row = r0 + w * 32 + rt * 16 + q * 4 + j;
                    if (row >= M) continue;
                    if (col < 47)      yl8[(size_t)row * 64 + col] = fp8(acc[rt][ct][j]);
                    else if (col < 94) yrbf[(size_t)row * 48 + (col - 47)] = (bf16)acc[rt][ct][j];
                }
            }
        }
    }
}

// ---- tiny BN prep: collapse NCOPY striped stats, compute scale/shift per col. ----
__global__ void k_bn_prep(const float* __restrict__ sums, const float* __restrict__ gma,
                          const float* __restrict__ bta, float* __restrict__ scsh, int n) {
    int col = threadIdx.x;               // 128 threads
    float s = 0.f, q = 0.f;
    #pragma unroll
    for (int cpy = 0; cpy < NCOPY; ++cpy) {
        s += sums[(cpy << 8) + col];
        q += sums[(cpy << 8) + 128 + col];
    }
    float invn = 1.0f / (float)n;
    float mu = s * invn;
    float var = q * invn - mu * mu;
    float sc = gma[col] * rsqrtf(var + BN_EPS);
    scsh[col] = sc;
    scsh[128 + col] = bta[col] - mu * sc;
}

// ---- BN apply + ReLU (bf16x4 8B loads — G13 vectorization; 4 cols/thread) ----
__global__ void k_bn_apply(const bf16* __restrict__ h, const float* __restrict__ scsh,
                           bf16* __restrict__ out, unsigned char* __restrict__ out8, int n) {
    int g = blockIdx.x * blockDim.x + threadIdx.x;
    int row = g >> 5, c4 = g & 31;
    if (row >= n) return;
    int col = c4 << 2;
    float4 sc = *(const float4*)(scsh + col);
    float4 sh = *(const float4*)(scsh + 128 + col);
    bf16x4v hv = *(const bf16x4v*)(h + (size_t)row * 128 + col);
    float r0 = fmaxf((float)hv[0] * sc.x + sh.x, 0.f);
    float r1 = fmaxf((float)hv[1] * sc.y + sh.y, 0.f);
    float r2 = fmaxf((float)hv[2] * sc.z + sh.z, 0.f);
    float r3 = fmaxf((float)hv[3] * sc.w + sh.w, 0.f);
    bf16x4v o; o[0] = (bf16)r0; o[1] = (bf16)r1; o[2] = (bf16)r2; o[3] = (bf16)r3;
    *(bf16x4v*)(out + (size_t)row * 128 + col) = o;
    uchar4 o8; o8.x = fp8(r0).__x; o8.y = fp8(r1).__x; o8.z = fp8(r2).__x; o8.w = fp8(r3).__x;
    *(uchar4*)(out8 + (size_t)row * 128 + col) = o8;
}

// ---- final: gather-mean of yl (fp8, 64B line/edge) + yr + bl2, log_softmax.
//      TWO nodes per wave; wave-uniform loop; unmasked fast path. ----
__global__ void k_final(const unsigned char* __restrict__ yl, const bf16* __restrict__ yr,
                        const int* __restrict__ row_ptr, const int* __restrict__ col_idx,
                        const float* __restrict__ inv_deg, const float* __restrict__ bl2,
                        float* __restrict__ out, int n) {
    const int lane = threadIdx.x & 63;
    const int half = lane >> 5;
    const int sl = lane & 31;
    const int sub = sl >> 4;                 // edge slot within pair
    const int c4 = sl & 15;                  // feature group: feats 4*c4..+3
    const int node = blockIdx.x * 8 + ((threadIdx.x >> 6) << 1) + half;
    const bool valid = node < n;
    const int nn = valid ? node : 0;
    const int re0 = row_ptr[nn];
    const int re1 = valid ? row_ptr[nn + 1] : re0;
    const float inv = inv_deg[nn];
    const uint32_t loff = (uint32_t)(c4 << 2);
    int deg = re1 - re0;
    int dother = __shfl_xor(deg, 32, 64);
    int nfull = (deg < dother ? deg : dother) >> 4;       // uniform across wave
    int nb = (((deg > dother ? deg : dother) + 15) >> 4); // uniform across wave
    float a0 = 0.f, a1 = 0.f, a2 = 0.f, a3 = 0.f;
    int rbase = re0;
    int t = 0;
    // unmasked full batches (both nodes have >= 16 edges remaining)
    for (; t < nfull; ++t, rbase += 16) {
        int i0 = col_idx[rbase + 0  + sub];
        int i1 = col_idx[rbase + 2  + sub];
        int i2 = col_idx[rbase + 4  + sub];
        int i3 = col_idx[rbase + 6  + sub];
        int i4 = col_idx[rbase + 8  + sub];
        int i5 = col_idx[rbase + 10 + sub];
        int i6 = col_idx[rbase + 12 + sub];
        int i7 = col_idx[rbase + 14 + sub];
        uint32_t u0 = *(const uint32_t*)(yl + (((uint32_t)i0 << 6) + loff));
        uint32_t u1 = *(const uint32_t*)(yl + (((uint32_t)i1 << 6) + loff));
        uint32_t u2 = *(const uint32_t*)(yl + (((uint32_t)i2 << 6) + loff));
        uint32_t u3 = *(const uint32_t*)(yl + (((uint32_t)i3 << 6) + loff));
        uint32_t u4 = *(const uint32_t*)(yl + (((uint32_t)i4 << 6) + loff));
        uint32_t u5 = *(const uint32_t*)(yl + (((uint32_t)i5 << 6) + loff));
        uint32_t u6 = *(const uint32_t*)(yl + (((uint32_t)i6 << 6) + loff));
        uint32_t u7 = *(const uint32_t*)(yl + (((uint32_t)i7 << 6) + loff));
        ACC4(u0) ACC4(u1) ACC4(u2) ACC4(u3) ACC4(u4) ACC4(u5) ACC4(u6) ACC4(u7)
    }
    // masked batches (value-clamped, address stays in-bounds)
    for (; t < nb; ++t, rbase += 16) {
        int ee0 = rbase + 0  + sub, ee1 = rbase + 2  + sub;
        int ee2 = rbase + 4  + sub, ee3 = rbase + 6  + sub;
        int ee4 = rbase + 8  + sub, ee5 = rbase + 10 + sub;
        int ee6 = rbase + 12 + sub, ee7 = rbase + 14 + sub;
        bool k0 = ee0 < re1, k1 = ee1 < re1, k2 = ee2 < re1, k3 = ee3 < re1;
        bool k4 = ee4 < re1, k5 = ee5 < re1, k6 = ee6 < re1, k7 = ee7 < re1;
        int i0 = col_idx[k0 ? ee0 : re0];
        int i1 = col_idx[k1 ? ee1 : re0];
        int i2 = col_idx[k2 ? ee2 : re0];
        int i3 = col_idx[k3 ? ee3 : re0];
        int i4 = col_idx[k4 ? ee4 : re0];
        int i5 = col_idx[k5 ? ee5 : re0];
        int i6 = col_idx[k6 ? ee6 : re0];
        int i7 = col_idx[k7 ? ee7 : re0];
        uint32_t u0 = *(const uint32_t*)(yl + (((uint32_t)i0 << 6) + loff));
        uint32_t u1 = *(const uint32_t*)(yl + (((uint32_t)i1 << 6) + loff));
        uint32_t u2 = *(const uint32_t*)(yl + (((uint32_t)i2 << 6) + loff));
        uint32_t u3 = *(const uint32_t*)(yl + (((uint32_t)i3 << 6) + loff));
        uint32_t u4 = *(const uint32_t*)(yl + (((uint32_t)i4 << 6) + loff));
        uint32_t u5 = *(const uint32_t*)(yl + (((uint32_t)i5 << 6) + loff));
        uint32_t u6 = *(const uint32_t*)(yl + (((uint32_t)i6 << 6) + loff));
        uint32_t u7 = *(const uint32_t*)(yl + (((uint32_t)i7 << 6) + loff));
        u0 = k0 ? u0 : 0u; u1 = k1 ? u1 : 0u; u2 = k2 ? u2 : 0u; u3 = k3 ? u3 : 0u;
        u4 = k4 ? u4 : 0u; u5 = k5 ? u5 : 0u; u6 = k6 ? u6 : 0u; u7 = k7 ? u7 : 0u;
        ACC4(u0) ACC4(u1) ACC4(u2) ACC4(u3) ACC4(u4) ACC4(u5) ACC4(u6) ACC4(u7)
    }
    // sum the 2 edge subgroups within each half (lanes differ in bit 4)
    a0 += __shfl_xor(a0, 16, 64); a1 += __shfl_xor(a1, 16, 64);
    a2 += __shfl_xor(a2, 16, 64); a3 += __shfl_xor(a3, 16, 64);
    const int f0 = c4 << 2;
    // yr: one 8-byte load (nn*96 + 8*c4 is 8B-aligned)
    bf16x4v yv4 = *(const bf16x4v*)(yr + (size_t)nn * 48 + f0);
    float v0 = (f0 + 0 < 47) ? fmaf(a0, inv, (float)yv4[0] + bl2[f0 + 0]) : -__builtin_inff();
    float v1 = (f0 + 1 < 47) ? fmaf(a1, inv, (float)yv4[1] + bl2[f0 + 1]) : -__builtin_inff();
    float v2 = (f0 + 2 < 47) ? fmaf(a2, inv, (float)yv4[2] + bl2[f0 + 2]) : -__builtin_inff();
    float v3 = (f0 + 3 < 47) ? fmaf(a3, inv, (float)yv4[3] + bl2[f0 + 3]) : -__builtin_inff();
    float m = fmaxf(fmaxf(v0, v1), fmaxf(v2, v3));
    #pragma unroll
    for (int o = 1; o < 16; o <<= 1) m = fmaxf(m, __shfl_xor(m, o, 64));
    float ex0 = (f0 + 0 < 47) ? __expf(v0 - m) : 0.f;
    float ex1 = (f0 + 1 < 47) ? __expf(v1 - m) : 0.f;
    float ex2 = (f0 + 2 < 47) ? __expf(v2 - m) : 0.f;
    float ex3 = (f0 + 3 < 47) ? __expf(v3 - m) : 0.f;
    float s = (ex0 + ex1) + (ex2 + ex3);
    #pragma unroll
    for (int o = 1; o < 16; o <<= 1) s += __shfl_xor(s, o, 64);
    float ls = __logf(s);
    if (valid && sl < 16) {
        float* op = out + (size_t)node * 47 + f0;
        if (f0 + 0 < 47) op[0] = v0 - m - ls;
        if (f0 + 1 < 47) op[1] = v1 - m - ls;
        if (f0 + 2 < 47) op[2] = v2 - m - ls;
        if (f0 + 3 < 47) op[3] = v3 - m - ls;
    }
}
#undef ACC4

extern "C" void kernel_launch(void* const* d_in, const int* in_sizes, int n_in,
                              void* d_out, int out_size, void* d_ws, size_t ws_size,
                              hipStream_t stream) {
    const float* x   = (const float*)d_in[0];
    const int*   ei  = (const int*)d_in[1];
    const float* Wl0 = (const float*)d_in[2];
    const float* bl0 = (const float*)d_in[3];
    const float* Wr0 = (const float*)d_in[4];
    const float* g0  = (const float*)d_in[5];
    const float* be0 = (const float*)d_in[6];
    const float* Wl1 = (const float*)d_in[7];
    const float* bl1 = (const float*)d_in[8];
    const float* Wr1 = (const float*)d_in[9];
    const float* g1  = (const float*)d_in[10];
    const float* be1 = (const float*)d_in[11];
    const float* Wl2 = (const float*)d_in[12];
    const float* bl2 = (const float*)d_in[13];
    const float* Wr2 = (const float*)d_in[14];
    float* out = (float*)d_out;

    const int N  = in_sizes[0] / 128;
    const int E  = in_sizes[1] / 2;
    const int NP = ((N + 127) / 128) * 128;
    const int NBKT = (N + BKT_NODES - 1) / BKT_NODES;

    char* p = (char*)d_ws;
    size_t off = 0;
    auto alloc = [&](size_t b) { char* r = p + off; off += (b + 255) & ~(size_t)255; return r; };
    // zero-init region (one memset): bfill, bnsum (2 layers x NCOPY x 256), btot
    int*   bfill   = (int*)alloc(1024 * 4);
    float* bnsum   = (float*)alloc(2 * NCOPY * 256 * 4);
    int*   btot    = (int*)alloc(512 * 4);
    size_t zero_span = off;
    float* scsh    = (float*)alloc(2 * 256 * 4);   // per-layer scale/shift tables
    int*   row_ptr = (int*)alloc((size_t)(N + 1) * 4);
    float* invd    = (float*)alloc((size_t)N * 4);
    int*   col_idx = (int*)alloc((size_t)E * 4);
    uint32_t* pair_buf = (uint32_t*)alloc((size_t)E * 4);
    bf16*  x_bf    = (bf16*)alloc((size_t)NP * 128 * 2);
    bf16*  aggbf   = (bf16*)alloc((size_t)NP * 128 * 2);
    bf16*  hbf     = (bf16*)alloc((size_t)NP * 128 * 2);
    unsigned char* h8 = (unsigned char*)alloc((size_t)NP * 128);
    float* bufF    = (float*)alloc((size_t)NP * 128 * 4 + 256);
    bf16*  Bt0     = (bf16*)alloc(128 * 256 * 2);
    bf16*  Bt1     = (bf16*)alloc(128 * 256 * 2);
    bf16*  Bt2     = (bf16*)alloc(128 * 128 * 2);
    // aliases into bufF (sequentially dead/live): x8 (pre-GEMM0), hraw (bf16 h,
    // GEMM->bn_apply), yl8/yrbf (post-BN1)
    unsigned char* x8 = (unsigned char*)bufF;
    bf16*  hraw = (bf16*)bufF;
    fp8*   yl8  = (fp8*)bufF;
    bf16*  yrbf = (bf16*)((char*)bufF + (size_t)NP * 64);

    hipMemsetAsync(bfill, 0, zero_span, stream);

    int n4 = N * 128 / 4;
    k_setup<<<(n4 + 255) / 256, 256, 0, stream>>>(x, x_bf, x8, n4, ei, btot, E, NBKT,
                                                  Wl0, Wr0, Wl1, Wr1, Wl2, Wr2, Bt0, Bt1, Bt2);
    k_bin<<<(E + TILE_E - 1) / TILE_E, 256, 0, stream>>>(ei, btot, bfill, pair_buf, E, NBKT);
    k_fill2<<<NBKT, 256, 0, stream>>>(pair_buf, btot, row_ptr, invd, col_idx, N, E, NBKT);

    int aggBlocks  = (N + 7) / 8;     // 2 nodes per wave, 4 waves per block
    int gemmBlocks = NP / 128;
    int bnBlocks   = (N * 32 + 255) / 256;
    int finBlocks  = (N + 7) / 8;

    // Layer 0
    k_aggregate<<<aggBlocks, 256, 0, stream>>>(x8, aggbf, row_ptr, col_idx, invd, N);
    k_gemm8<8, true, 8><<<gemmBlocks, 256, 0, stream>>>(aggbf, x_bf, Bt0, bl0, hraw, nullptr, nullptr, bnsum, N);
    k_bn_prep<<<1, 128, 0, stream>>>(bnsum, g0, be0, scsh, N);
    k_bn_apply<<<bnBlocks, 256, 0, stream>>>(hraw, scsh, hbf, h8, N);
    // Layer 1
    k_aggregate<<<aggBlocks, 256, 0, stream>>>(h8, aggbf, row_ptr, col_idx, invd, N);
    k_gemm8<8, true, 8><<<gemmBlocks, 256, 0, stream>>>(aggbf, hbf, Bt1, bl1, hraw, nullptr, nullptr, bnsum + NCOPY * 256, N);
    k_bn_prep<<<1, 128, 0, stream>>>(bnsum + NCOPY * 256, g1, be1, scsh + 256, N);
    k_bn_apply<<<bnBlocks, 256, 0, stream>>>(hraw, scsh + 256, hbf, h8, N);
    // Layer 2: project to yl (fp8, stride 64) / yr (bf16), then gather + log_softmax
    k_gemm8<4, false, 6><<<gemmBlocks, 256, 0, stream>>>(hbf, hbf, Bt2, nullptr, nullptr, yl8, yrbf, nullptr, N);
    k_final<<<finBlocks, 256, 0, stream>>>((const unsigned char*)yl8, yrbf, row_ptr, col_idx, invd, bl2, out, N);
}